// Round 11
// baseline (220.119 us; speedup 1.0000x reference)
//
#include <hip/hip_runtime.h>
#include <cstdint>

// ---------------------------------------------------------------------------
// TenGCN fused forward. 128 graphs (2 branches x 64 batches).
// R11: kBS's 4-pass radix select (+tie ballots, ~95 block barriers) replaced
// with brute-force all-pairs ranking (LDS-broadcast reads, 1 barrier).
// 7 launches: kA (Dsc+setup) -> kPI -> kBS -> kG1 -> kG2 -> kG4 -> k5.
// ---------------------------------------------------------------------------

constexpr int B_ = 64, N_ = 1024, E_ = 32768, F_ = 128, H_ = 32;
constexpr int CF_ = 5, P_ = 50, K_ = 512, G_ = 128, PO = 25;

// workspace offsets (4-byte units)
constexpr size_t WS_SRCS  = 0;                                // G*E u16 (packed)
constexpr size_t WS_ONODE = WS_SRCS + (size_t)G_*(E_/2);      // G*512 int
constexpr size_t WS_VDEG  = WS_ONODE + (size_t)G_*K_;         // G*512 u16
constexpr size_t WS_EOFF  = WS_VDEG + (size_t)G_*(K_/2);      // G*512 int (packed ceoff)
constexpr size_t WS_DINV  = WS_EOFF + (size_t)G_*K_;          // G*512 f32 (valid dinv)
constexpr size_t WS_GA    = WS_DINV + (size_t)G_*K_;          // G*512*32 f32
constexpr size_t WS_GC    = WS_GA + (size_t)G_*K_*H_;         // G*512*32 f32
constexpr size_t WS_PM0   = WS_GC + (size_t)G_*K_*H_;         // G*2*32
constexpr size_t WS_PM1   = WS_PM0 + (size_t)G_*64;           // G*2*32
constexpr size_t WS_PPI   = WS_PM1 + (size_t)G_*64;           // G*32
constexpr size_t WS_F0V   = WS_PPI + (size_t)G_*32;           // 2 (pad 32)
constexpr size_t WS_B01   = WS_F0V + 32;                      // 32
constexpr size_t WS_C0B   = WS_B01 + 32;                      // 32
constexpr size_t WS_C1B   = WS_C0B + 32;                      // 32
constexpr size_t WS_W01   = WS_C1B + 32;                      // 1024
constexpr size_t WS_P0B   = WS_W01 + 1024;                    // 1024
constexpr size_t WS_P1B   = WS_P0B + 1024;                    // 1024

// Dsc lives in the (dead until kG2) GC region
constexpr size_t WS_DSC   = WS_GC;                            // G*N*5 f32

static __device__ __forceinline__ int swzf4(int row, int c4) {
  return row*32 + (((c4) ^ ((row >> 2) & 7)) << 2);
}

// ---------------------------------------------------------------------------
// kA: blocks [0,8G): Dsc[g][n][5] = x[n] @ Wdiff (quad-per-row, coalesced).
//     blk2 = blk-8G: 0: F0V; 1..32: W01 rows; 33: B01; 34/35: P0b/P1b.
// ---------------------------------------------------------------------------
__global__ __launch_bounds__(512, 4) void kA_pre(
    const float* __restrict__ x1, const float* __restrict__ x2,
    const float* __restrict__ Wsc,
    const float* __restrict__ F0w, const float* __restrict__ F2w,
    const float* __restrict__ H0w, const float* __restrict__ H2w,
    const float* __restrict__ Wm0b, const float* __restrict__ bm0b,
    const float* __restrict__ Wm1b, const float* __restrict__ bm1b,
    const float* __restrict__ Wg1, float* __restrict__ ws)
{
  __shared__ float SM[640];   // 2.56KB union
  int blk = blockIdx.x, t = threadIdx.x;

  if (blk < 8*G_) {
    // ---- Dsc: 8 blocks/graph, 4 threads/row, 64B-coalesced reads ----
    int g = blk >> 3, sub = blk & 7, br = g >> 6, b = g & 63;
    const float* xg = (br ? x2 : x1) + (size_t)b*N_*F_;
    float* WdL = SM;  // 640
    if (t < F_) {
      #pragma unroll
      for (int j = 0; j < 5; ++j) WdL[t*5+j] = Wsc[t*10+2*j+1] - Wsc[t*10+2*j];
    }
    __syncthreads();
    int row = sub*128 + (t >> 2), q = t & 3;
    const float4* xr = (const float4*)(xg + (size_t)row*F_);
    float acc[5] = {};
    #pragma unroll
    for (int i = 0; i < 8; ++i) {
      int k4 = q + 4*i;
      float4 v = xr[k4];
      const float* w = &WdL[k4*20];
      #pragma unroll
      for (int j = 0; j < 5; ++j)
        acc[j] += v.x*w[j] + v.y*w[5+j] + v.z*w[10+j] + v.w*w[15+j];
    }
    #pragma unroll
    for (int j = 0; j < 5; ++j) {
      acc[j] += __shfl_xor(acc[j], 1, 4);
      acc[j] += __shfl_xor(acc[j], 2, 4);
    }
    if (q == 0) {
      float* o = ws + WS_DSC + ((size_t)g*N_ + row)*5;
      #pragma unroll
      for (int j = 0; j < 5; ++j) o[j] = acc[j];
    }
    return;
  }

  int blk2 = blk - 8*G_;
  if (blk2 == 0) {
    // F0V
    float* h0mS = SM;
    if (t < 32) { float s = 0.f; for (int qq = 0; qq < 64; ++qq) s += H0w[qq*64+t]; h0mS[t] = s*(1.f/64.f); }
    __syncthreads();
    if (t < 2) { float s = 0.f; for (int p = 0; p < 32; ++p) s += F0w[p*2+t]*h0mS[p]; ws[WS_F0V+t] = s; }
  } else if (blk2 <= 32) {
    // W01 row kk: 512 thr = 32 cols x 16 k-segments of 64.
    int kk = blk2 - 1;
    int ol = t >> 4, seg = t & 15;
    const float4* ar = (const float4*)(Wm0b + (size_t)kk*1024 + seg*64);
    float s = 0.f;
    #pragma unroll
    for (int i = 0; i < 16; ++i) {
      float4 a = ar[i];
      int tt = seg*64 + i*4;
      s += a.x*Wg1[(tt+0)*32 + ol] + a.y*Wg1[(tt+1)*32 + ol]
         + a.z*Wg1[(tt+2)*32 + ol] + a.w*Wg1[(tt+3)*32 + ol];
    }
    s += __shfl_xor(s, 1, 16);
    s += __shfl_xor(s, 2, 16);
    s += __shfl_xor(s, 4, 16);
    s += __shfl_xor(s, 8, 16);
    if (seg == 0) ws[WS_W01 + kk*32 + ol] = s;
  } else if (blk2 == 33) {
    // B01: 32 cols x 16 segments of 64 + LDS reduce.
    float* red = SM;   // 512
    int j = t & 31, seg = t >> 5;
    float s = 0.f;
    #pragma unroll
    for (int i = 0; i < 64; ++i) {
      int k = seg*64 + i;
      s += bm0b[k]*Wg1[k*32 + j];
    }
    red[seg*32 + j] = s;
    __syncthreads();
    if (t < 32) {
      float a = 0.f;
      #pragma unroll
      for (int q = 0; q < 16; ++q) a += red[q*32 + t];
      ws[WS_B01 + t] = a;
    }
  } else {
    // P0b/c0b (34) and P1b/c1b (35)
    const float* Wb = (blk2 == 34) ? Wm0b : Wm1b;
    const float* bb = (blk2 == 34) ? bm0b : bm1b;
    size_t dstP = (blk2 == 34) ? WS_P0B : WS_P1B;
    size_t dstC = (blk2 == 34) ? WS_C0B : WS_C1B;
    float* h2mL = SM;        // 32
    float* f2vL = SM + 32;   // 32
    if (t < 32) { float s = 0.f; for (int r = 0; r < 32; ++r) s += H2w[r*32+t]; h2mL[t] = s*(1.f/32.f); }
    __syncthreads();
    if (t < 32) { float s = 0.f; for (int r = 0; r < 32; ++r) s += F2w[r*32+t]*h2mL[r]; f2vL[t] = s; }
    __syncthreads();
    if (t < 256) {
      #pragma unroll
      for (int q = 0; q < 4; ++q) {
        int e = t*4 + q;
        int k = e >> 5, c = e & 31;
        float s = 0.f;
        #pragma unroll
        for (int kp = 0; kp < 32; ++kp) s += Wb[k*1024 + c*32 + kp]*f2vL[kp];
        ws[dstP + e] = s;
      }
    }
    if (t < 32) {
      float s = 0.f;
      #pragma unroll
      for (int kp = 0; kp < 32; ++kp) s += bb[t*32+kp]*f2vL[kp];
      ws[dstC+t] = s;
    }
  }
}

// ---------------------------------------------------------------------------
// kPI: PI conv + relu, reduced by locally-computed g0v/g2v. Standalone.
// ---------------------------------------------------------------------------
__global__ __launch_bounds__(256, 4) void kPI(
    const float* __restrict__ PI1, const float* __restrict__ PI2,
    const float* __restrict__ Kc, const float* __restrict__ bc,
    const float* __restrict__ G0w, const float* __restrict__ G2w,
    const float* __restrict__ H0w, const float* __restrict__ H2w,
    float* __restrict__ ws)
{
  int g = blockIdx.x, br = g >> 6, b = g & 63;
  const float* pig = (br ? PI2 : PI1) + (size_t)b*CF_*P_*P_;
  __shared__ float PIt[CF_*P_*P_];   // 50KB
  __shared__ float KcL[H_*CF_*4];
  __shared__ float bcL[H_], g0L[H_], g2L[PO], h2L[H_], hhL[H_];
  int t = threadIdx.x;
  for (int i = t; i < CF_*P_*P_; i += 256) PIt[i] = pig[i];
  for (int i = t; i < H_*CF_*4; i += 256) KcL[i] = Kc[i];
  if (t < 32) {
    bcL[t] = bc[t];
    float s = 0.f;
    for (int qq = 0; qq < 64; ++qq) s += H0w[qq*64 + 32 + t];
    hhL[t] = s * (1.f/64.f);
  }
  if (t >= 64 && t < 96) {
    int r = t - 64;
    float s = 0.f;
    for (int rr = 0; rr < 32; ++rr) s += H2w[rr*32 + r];
    h2L[r] = s * (1.f/32.f);
  }
  __syncthreads();
  if (t < 32) { float s = 0.f; for (int p = 0; p < 32; ++p) s += G0w[p*32+t]*hhL[p]; g0L[t] = s; }
  if (t >= 64 && t < 64+PO) {
    int kp = t - 64;
    float s = 0.f;
    for (int r = 0; r < 32; ++r) s += G2w[r*25+kp]*h2L[r];
    g2L[kp] = s;
  }
  __syncthreads();
  int jp = t >> 3, sub = t & 7;
  float acc = 0.f;
  if (jp < PO) {
    for (int i = sub; i < H_; i += 8) {
      const float* kcp = &KcL[i*20];
      float bi = bcL[i], gi = g0L[i];
      for (int kp = 0; kp < PO; ++kp) {
        float v = bi;
        #pragma unroll
        for (int c = 0; c < CF_; ++c) {
          const float* pp = &PIt[c*2500 + (2*jp)*50 + 2*kp];
          v += pp[0]*kcp[c*4+0] + pp[1]*kcp[c*4+1] + pp[50]*kcp[c*4+2] + pp[51]*kcp[c*4+3];
        }
        acc += fmaxf(v, 0.f) * gi * g2L[kp];
      }
    }
  }
  #pragma unroll
  for (int d = 4; d > 0; d >>= 1) acc += __shfl_down(acc, d, 8);
  if (sub == 0 && jp < PO) ws[WS_PPI + (size_t)g*32 + jp] = acc;
}

// ---------------------------------------------------------------------------
// kBS: per-graph count -> scan -> scatter(LDS) -> score(LDS gather) ->
// brute-force exact rank (1 barrier) -> compact -> packed CSR out.
// ---------------------------------------------------------------------------
__global__ __launch_bounds__(1024, 4) void kBS(
    const int* __restrict__ ei1, const int* __restrict__ ei2,
    const float* __restrict__ bsc, float* __restrict__ ws)
{
  int g = blockIdx.x, br = g >> 6, b = g & 63;
  const int* ei  = (br ? ei2 : ei1) + (size_t)b*2*E_;
  const int* src = ei;
  const int* dst = ei + E_;
  int* onodeg = (int*)ws + WS_ONODE + (size_t)g*K_;
  uint16_t* vdegg = (uint16_t*)(ws + WS_VDEG) + (size_t)g*K_;
  int* ceoffg = (int*)ws + WS_EOFF + (size_t)g*K_;
  float* dinvg = ws + WS_DINV + (size_t)g*K_;
  uint16_t* csrc = (uint16_t*)(ws + WS_SRCS) + (size_t)g*E_;

  __shared__ uint16_t srcL[E_];    // 64KB
  __shared__ float DscL[N_*5];     // 20KB
  __shared__ float dinvF[N_];      // 4KB
  __shared__ float keyL[N_];       // 4KB
  __shared__ int fbL[N_];          // 4KB
  __shared__ int fillL[N_];        // 4KB
  __shared__ int nidxL[N_];        // 4KB
  __shared__ int seoffL[K_];       // 2KB
  __shared__ int vdegL[K_];        // 2KB
  __shared__ int ceoffL[K_];       // 2KB
  __shared__ int wsum[16];

  int t = threadIdx.x;
  { const float* Dg = ws + WS_DSC + (size_t)g*N_*5;
    for (int i = t; i < N_*5; i += 1024) DscL[i] = Dg[i]; }
  fillL[t] = 0;
  __syncthreads();

  // A: count
  for (int i = 0; i < E_/1024; ++i) {
    int d = dst[t + i*1024];
    atomicAdd(&fillL[d], 1);
  }
  __syncthreads();

  // B: exclusive scan of counts
  int c = fillL[t];
  int lane = t & 63, w = t >> 6;
  int x = c;
  #pragma unroll
  for (int s = 1; s < 64; s <<= 1) {
    int v = __shfl_up(x, s);
    if (lane >= s) x += v;
  }
  if (lane == 63) wsum[w] = x;
  __syncthreads();
  if (w == 0 && lane < 16) {
    int y = wsum[lane];
    #pragma unroll
    for (int s = 1; s < 16; s <<= 1) {
      int v = __shfl_up(y, s, 16);
      if (lane >= s) y += v;
    }
    wsum[lane] = y;
  }
  __syncthreads();
  int off0 = ((w == 0) ? 0 : wsum[w-1]) + x - c;
  int off1 = off0 + c;
  fbL[t] = off0;
  dinvF[t] = rsqrtf((float)c + 1.0f);
  fillL[t] = 0;
  __syncthreads();

  // C: scatter into LDS
  for (int i = 0; i < E_/1024; ++i) {
    int e = t + i*1024;
    int d = dst[e], s = src[e];
    int pos = fbL[d] + atomicAdd(&fillL[d], 1);
    srcL[pos] = (uint16_t)s;
  }
  __syncthreads();

  // D: score gather from LDS
  float scf;
  {
    float agg[5] = {};
    for (int e = off0; e < off1; ++e) {
      int s = srcL[e];
      float dvs = dinvF[s];
      const float* hr = &DscL[s*5];
      #pragma unroll
      for (int j = 0; j < 5; ++j) agg[j] += hr[j]*dvs;
    }
    float dv = dinvF[t];
    const float* hn = &DscL[t*5];
    float sc = 0.f;
    #pragma unroll
    for (int j = 0; j < 5; ++j)
      sc += fabsf(dv*(agg[j] + dv*hn[j]) + (bsc[2*j+1] - bsc[2*j]));
    scf = sc;
  }
  keyL[t] = scf;
  __syncthreads();

  // E: brute-force exact ranking under (score desc, idx asc).
  // All lanes read the same keyL address per iter -> LDS broadcast.
  int rank = 0;
  {
    float myk = scf;
    #pragma unroll 4
    for (int u = 0; u < N_; u += 4) {
      float4 k4 = *(const float4*)&keyL[u];
      rank += (k4.x > myk || (k4.x == myk && (u+0) < t)) ? 1 : 0;
      rank += (k4.y > myk || (k4.y == myk && (u+1) < t)) ? 1 : 0;
      rank += (k4.z > myk || (k4.z == myk && (u+2) < t)) ? 1 : 0;
      rank += (k4.w > myk || (k4.w == myk && (u+3) < t)) ? 1 : 0;
    }
  }
  bool sel = rank < K_;
  nidxL[t] = sel ? rank : -1;
  if (sel) onodeg[rank] = t;
  __syncthreads();

  // F: compact own segment in place (remap to ranks)
  if (sel) {
    int c2 = 0;
    for (int e = off0; e < off1; ++e) {
      int m = nidxL[srcL[e]];
      if (m >= 0) srcL[off0 + (c2++)] = (uint16_t)m;
    }
    vdegL[rank] = c2;
    seoffL[rank] = off0;
  }
  __syncthreads();

  // G: scan vdeg over 512 ranks -> packed offsets
  int vv = 0, xx = 0, w2 = t >> 6;
  if (t < K_) {
    vv = vdegL[t]; xx = vv;
    int l2 = t & 63;
    #pragma unroll
    for (int s = 1; s < 64; s <<= 1) {
      int v = __shfl_up(xx, s);
      if (l2 >= s) xx += v;
    }
    if (l2 == 63) wsum[w2] = xx;
  }
  __syncthreads();
  if (t == 0) { int run = 0; for (int q = 0; q < 8; ++q) { int tm = wsum[q]; wsum[q] = run; run += tm; } }
  __syncthreads();
  if (t < K_) {
    int ce = wsum[w2] + xx - vv;
    ceoffL[t] = ce;
    ceoffg[t] = ce;
    vdegg[t] = (uint16_t)vv;
    dinvg[t] = rsqrtf((float)vv + 1.0f);
  }
  __syncthreads();

  // H: write packed edge list
  if (t < K_) {
    int s0 = seoffL[t], n = vdegL[t], d0 = ceoffL[t];
    for (int i = 0; i < n; ++i) csrc[d0 + i] = srcL[s0 + i];
  }
}

// ---------------------------------------------------------------------------
// 256x32 @ 32x32 matmul core on swizzled LDS; W padded [32][36].
// ---------------------------------------------------------------------------
static __device__ __forceinline__ void mmA(
    const float* __restrict__ S, const float* __restrict__ Wp,
    float (&acc)[4][4], int it, int jt)
{
  const int i0 = it*4, swa = it & 7;
  #pragma unroll
  for (int kv = 0; kv < 8; ++kv) {
    float4 w0 = *(const float4*)&Wp[(kv*4+0)*36 + jt*4];
    float4 w1 = *(const float4*)&Wp[(kv*4+1)*36 + jt*4];
    float4 w2 = *(const float4*)&Wp[(kv*4+2)*36 + jt*4];
    float4 w3 = *(const float4*)&Wp[(kv*4+3)*36 + jt*4];
    #pragma unroll
    for (int d = 0; d < 4; ++d) {
      float4 a = *(const float4*)&S[(i0+d)*32 + ((kv ^ swa) << 2)];
      acc[d][0] += a.x*w0.x + a.y*w1.x + a.z*w2.x + a.w*w3.x;
      acc[d][1] += a.x*w0.y + a.y*w1.y + a.z*w2.y + a.w*w3.y;
      acc[d][2] += a.x*w0.z + a.y*w1.z + a.z*w2.z + a.w*w3.z;
      acc[d][3] += a.x*w0.w + a.y*w1.w + a.z*w2.w + a.w*w3.w;
    }
  }
}

// ---------------------------------------------------------------------------
// kG1: gA[g][dd] = dinv[dd] * (x[onode[dd]] @ Wg0).  grid (G,2) x 512.
// ---------------------------------------------------------------------------
__global__ __launch_bounds__(512, 4) void kG1(
    const float* __restrict__ x1, const float* __restrict__ x2,
    const float* __restrict__ Wg0, float* __restrict__ ws)
{
  int g = blockIdx.x, half = blockIdx.y, br = g >> 6, b = g & 63;
  const float* xg = (br ? x2 : x1) + (size_t)b*N_*F_;
  const int* onodeg = (const int*)ws + WS_ONODE + (size_t)g*K_ + half*256;
  const float* dinvg = ws + WS_DINV + (size_t)g*K_ + half*256;
  float* gAg = ws + WS_GA + (size_t)g*K_*H_ + (size_t)half*256*H_;

  __shared__ float wbuf[F_*36];
  __shared__ int   onodeL[256];
  __shared__ float dinvL[256];

  int t = threadIdx.x;
  for (int i = t; i < F_*H_; i += 512) wbuf[(i >> 5)*36 + (i & 31)] = Wg0[i];
  if (t < 256) { onodeL[t] = onodeg[t]; dinvL[t] = dinvg[t]; }
  __syncthreads();

  const int it = t >> 3, jt = t & 7;
  const int i0 = it*4;
  const float* xr0 = xg + (size_t)onodeL[i0+0]*F_;
  const float* xr1 = xg + (size_t)onodeL[i0+1]*F_;
  const float* xr2 = xg + (size_t)onodeL[i0+2]*F_;
  const float* xr3 = xg + (size_t)onodeL[i0+3]*F_;
  float acc[4][4] = {};
  for (int k4 = 0; k4 < 32; ++k4) {
    float4 w0 = *(const float4*)&wbuf[(k4*4+0)*36 + jt*4];
    float4 w1 = *(const float4*)&wbuf[(k4*4+1)*36 + jt*4];
    float4 w2 = *(const float4*)&wbuf[(k4*4+2)*36 + jt*4];
    float4 w3 = *(const float4*)&wbuf[(k4*4+3)*36 + jt*4];
    float4 a;
    a = *(const float4*)(xr0 + k4*4);
    acc[0][0]+=a.x*w0.x+a.y*w1.x+a.z*w2.x+a.w*w3.x; acc[0][1]+=a.x*w0.y+a.y*w1.y+a.z*w2.y+a.w*w3.y;
    acc[0][2]+=a.x*w0.z+a.y*w1.z+a.z*w2.z+a.w*w3.z; acc[0][3]+=a.x*w0.w+a.y*w1.w+a.z*w2.w+a.w*w3.w;
    a = *(const float4*)(xr1 + k4*4);
    acc[1][0]+=a.x*w0.x+a.y*w1.x+a.z*w2.x+a.w*w3.x; acc[1][1]+=a.x*w0.y+a.y*w1.y+a.z*w2.y+a.w*w3.y;
    acc[1][2]+=a.x*w0.z+a.y*w1.z+a.z*w2.z+a.w*w3.z; acc[1][3]+=a.x*w0.w+a.y*w1.w+a.z*w2.w+a.w*w3.w;
    a = *(const float4*)(xr2 + k4*4);
    acc[2][0]+=a.x*w0.x+a.y*w1.x+a.z*w2.x+a.w*w3.x; acc[2][1]+=a.x*w0.y+a.y*w1.y+a.z*w2.y+a.w*w3.y;
    acc[2][2]+=a.x*w0.z+a.y*w1.z+a.z*w2.z+a.w*w3.z; acc[2][3]+=a.x*w0.w+a.y*w1.w+a.z*w2.w+a.w*w3.w;
    a = *(const float4*)(xr3 + k4*4);
    acc[3][0]+=a.x*w0.x+a.y*w1.x+a.z*w2.x+a.w*w3.x; acc[3][1]+=a.x*w0.y+a.y*w1.y+a.z*w2.y+a.w*w3.y;
    acc[3][2]+=a.x*w0.z+a.y*w1.z+a.z*w2.z+a.w*w3.z; acc[3][3]+=a.x*w0.w+a.y*w1.w+a.z*w2.w+a.w*w3.w;
  }
  #pragma unroll
  for (int d = 0; d < 4; ++d) {
    int row = i0 + d;
    float rs = dinvL[row];
    float4 o; o.x=acc[d][0]*rs; o.y=acc[d][1]*rs; o.z=acc[d][2]*rs; o.w=acc[d][3]*rs;
    *(float4*)&gAg[row*32 + jt*4] = o;
  }
}

// ---------------------------------------------------------------------------
// conv gather (packed CSR) from global feature buffer into swizzled LDS.
// ---------------------------------------------------------------------------
static __device__ __forceinline__ void convG(
    const float* __restrict__ gS, float* __restrict__ cbuf,
    const float* __restrict__ bias, const float* __restrict__ dinvL,
    const int* __restrict__ eoffL, const int* __restrict__ vcntL,
    const uint16_t* __restrict__ srcS, int half, int t)
{
  int ddl = t & 255, hc = t >> 8;
  int dd = half*256 + ddl;
  int lo = eoffL[ddl], n = vcntL[ddl];
  int c0 = hc*16;
  float4 a0 = {0,0,0,0}, a1 = a0, a2 = a0, a3 = a0;
  for (int i = 0; i < n; ++i) {
    int ss = srcS[lo + i];
    const float* r = gS + ss*32 + c0;
    float4 v;
    v = *(const float4*)(r+0);  a0.x+=v.x; a0.y+=v.y; a0.z+=v.z; a0.w+=v.w;
    v = *(const float4*)(r+4);  a1.x+=v.x; a1.y+=v.y; a1.z+=v.z; a1.w+=v.w;
    v = *(const float4*)(r+8);  a2.x+=v.x; a2.y+=v.y; a2.z+=v.z; a2.w+=v.w;
    v = *(const float4*)(r+12); a3.x+=v.x; a3.y+=v.y; a3.z+=v.z; a3.w+=v.w;
  }
  { const float* r = gS + dd*32 + c0;
    float4 v;
    v = *(const float4*)(r+0);  a0.x+=v.x; a0.y+=v.y; a0.z+=v.z; a0.w+=v.w;
    v = *(const float4*)(r+4);  a1.x+=v.x; a1.y+=v.y; a1.z+=v.z; a1.w+=v.w;
    v = *(const float4*)(r+8);  a2.x+=v.x; a2.y+=v.y; a2.z+=v.z; a2.w+=v.w;
    v = *(const float4*)(r+12); a3.x+=v.x; a3.y+=v.y; a3.z+=v.z; a3.w+=v.w; }
  float dvd = dinvL[ddl];
  float4 r0, r1, r2, r3;
  r0.x = dvd*a0.x + bias[c0+0];  r0.y = dvd*a0.y + bias[c0+1];
  r0.z = dvd*a0.z + bias[c0+2];  r0.w = dvd*a0.w + bias[c0+3];
  r1.x = dvd*a1.x + bias[c0+4];  r1.y = dvd*a1.y + bias[c0+5];
  r1.z = dvd*a1.z + bias[c0+6];  r1.w = dvd*a1.w + bias[c0+7];
  r2.x = dvd*a2.x + bias[c0+8];  r2.y = dvd*a2.y + bias[c0+9];
  r2.z = dvd*a2.z + bias[c0+10]; r2.w = dvd*a2.w + bias[c0+11];
  r3.x = dvd*a3.x + bias[c0+12]; r3.y = dvd*a3.y + bias[c0+13];
  r3.z = dvd*a3.z + bias[c0+14]; r3.w = dvd*a3.w + bias[c0+15];
  int g4 = hc*4;
  *(float4*)&cbuf[swzf4(ddl, g4+0)] = r0;
  *(float4*)&cbuf[swzf4(ddl, g4+1)] = r1;
  *(float4*)&cbuf[swzf4(ddl, g4+2)] = r2;
  *(float4*)&cbuf[swzf4(ddl, g4+3)] = r3;
}

// ---------------------------------------------------------------------------
// kG2: conv0 -> r0=relu(.@Wm0a+b) -> {column partials, gC=(r0@W01+b01)*dinv}
// ---------------------------------------------------------------------------
__global__ __launch_bounds__(512, 4) void kG2(
    const float* __restrict__ bg0,
    const float* __restrict__ Wm0a, const float* __restrict__ bm0a,
    float* __restrict__ ws)
{
  int g = blockIdx.x, half = blockIdx.y;
  const float* gAg = ws + WS_GA + (size_t)g*K_*H_;
  float* gCg = ws + WS_GC + (size_t)g*K_*H_;
  const uint16_t* srcS = (const uint16_t*)(ws + WS_SRCS) + (size_t)g*E_;
  const int* eoffg = (const int*)ws + WS_EOFF + (size_t)g*K_ + half*256;
  const uint16_t* vdegg = (const uint16_t*)(ws + WS_VDEG) + (size_t)g*K_ + half*256;
  const float* dinvg = ws + WS_DINV + (size_t)g*K_ + half*256;

  __shared__ float cbufA[256*32];
  __shared__ float cbufB[256*32];
  __shared__ float wA[32*36];
  __shared__ float wB[32*36];
  __shared__ float scrP[64*33];
  __shared__ int   eoffL[256];
  __shared__ int   vcntL[256];
  __shared__ float dinvL[256];

  int t = threadIdx.x;
  for (int i = t; i < 1024; i += 512) {
    int k = i >> 5, j = i & 31;
    wA[k*36+j] = Wm0a[i];
    wB[k*36+j] = ws[WS_W01 + i];
  }
  if (t < 256) { eoffL[t] = eoffg[t]; vcntL[t] = vdegg[t]; dinvL[t] = dinvg[t]; }
  __syncthreads();

  convG(gAg, cbufA, bg0, dinvL, eoffL, vcntL, srcS, half, t);
  __syncthreads();

  const int it = t >> 3, jt = t & 7;
  float acc[4][4] = {};
  mmA(cbufA, wA, acc, it, jt);
  {
    float b0 = bm0a[jt*4+0], b1 = bm0a[jt*4+1], b2 = bm0a[jt*4+2], b3 = bm0a[jt*4+3];
    float cp0=0.f, cp1=0.f, cp2=0.f, cp3=0.f;
    #pragma unroll
    for (int d = 0; d < 4; ++d) {
      float v0=fmaxf(acc[d][0]+b0,0.f), v1=fmaxf(acc[d][1]+b1,0.f);
      float v2=fmaxf(acc[d][2]+b2,0.f), v3=fmaxf(acc[d][3]+b3,0.f);
      cp0+=v0; cp1+=v1; cp2+=v2; cp3+=v3;
      float4 o; o.x=v0; o.y=v1; o.z=v2; o.w=v3;
      *(float4*)&cbufB[swzf4(it*4+d, jt)] = o;
    }
    scrP[it*33 + jt*4+0] = cp0; scrP[it*33 + jt*4+1] = cp1;
    scrP[it*33 + jt*4+2] = cp2; scrP[it*33 + jt*4+3] = cp3;
  }
  __syncthreads();

  if (t < 32) {
    float s = 0.f;
    #pragma unroll
    for (int q = 0; q < 64; ++q) s += scrP[q*33 + t];
    ws[WS_PM0 + (size_t)g*64 + half*32 + t] = s;
  }

  float acc2[4][4] = {};
  mmA(cbufB, wB, acc2, it, jt);
  {
    float b0 = ws[WS_B01+jt*4+0], b1 = ws[WS_B01+jt*4+1];
    float b2 = ws[WS_B01+jt*4+2], b3 = ws[WS_B01+jt*4+3];
    #pragma unroll
    for (int d = 0; d < 4; ++d) {
      int row = it*4 + d;
      float rs = dinvL[row];
      float4 o;
      o.x=(acc2[d][0]+b0)*rs; o.y=(acc2[d][1]+b1)*rs;
      o.z=(acc2[d][2]+b2)*rs; o.w=(acc2[d][3]+b3)*rs;
      *(float4*)&gCg[(half*256+row)*32 + jt*4] = o;
    }
  }
}

// ---------------------------------------------------------------------------
// kG4: conv1 -> r1=relu(.@Wm1a+b) -> column partials.
// ---------------------------------------------------------------------------
__global__ __launch_bounds__(512, 4) void kG4(
    const float* __restrict__ bg1,
    const float* __restrict__ Wm1a, const float* __restrict__ bm1a,
    float* __restrict__ ws)
{
  int g = blockIdx.x, half = blockIdx.y;
  const float* gCg = ws + WS_GC + (size_t)g*K_*H_;
  const uint16_t* srcS = (const uint16_t*)(ws + WS_SRCS) + (size_t)g*E_;
  const int* eoffg = (const int*)ws + WS_EOFF + (size_t)g*K_ + half*256;
  const uint16_t* vdegg = (const uint16_t*)(ws + WS_VDEG) + (size_t)g*K_ + half*256;
  const float* dinvg = ws + WS_DINV + (size_t)g*K_ + half*256;

  __shared__ float cbufA[256*32];
  __shared__ float wA[32*36];
  __shared__ float scrP[64*33];
  __shared__ int   eoffL[256];
  __shared__ int   vcntL[256];
  __shared__ float dinvL[256];

  int t = threadIdx.x;
  for (int i = t; i < 1024; i += 512) wA[(i>>5)*36 + (i&31)] = Wm1a[i];
  if (t < 256) { eoffL[t] = eoffg[t]; vcntL[t] = vdegg[t]; dinvL[t] = dinvg[t]; }
  __syncthreads();

  convG(gCg, cbufA, bg1, dinvL, eoffL, vcntL, srcS, half, t);
  __syncthreads();

  const int it = t >> 3, jt = t & 7;
  float acc[4][4] = {};
  mmA(cbufA, wA, acc, it, jt);
  {
    float b0 = bm1a[jt*4+0], b1 = bm1a[jt*4+1], b2 = bm1a[jt*4+2], b3 = bm1a[jt*4+3];
    float cp0=0.f, cp1=0.f, cp2=0.f, cp3=0.f;
    #pragma unroll
    for (int d = 0; d < 4; ++d) {
      cp0 += fmaxf(acc[d][0]+b0,0.f); cp1 += fmaxf(acc[d][1]+b1,0.f);
      cp2 += fmaxf(acc[d][2]+b2,0.f); cp3 += fmaxf(acc[d][3]+b3,0.f);
    }
    scrP[it*33 + jt*4+0] = cp0; scrP[it*33 + jt*4+1] = cp1;
    scrP[it*33 + jt*4+2] = cp2; scrP[it*33 + jt*4+3] = cp3;
  }
  __syncthreads();

  if (t < 32) {
    float s = 0.f;
    #pragma unroll
    for (int q = 0; q < 64; ++q) s += scrP[q*33 + t];
    ws[WS_PM1 + (size_t)g*64 + half*32 + t] = s;
  }
}

// ---------------------------------------------------------------------------
// k5: per-graph tail via folded P0b/P1b. grid G x 64.
// ---------------------------------------------------------------------------
__global__ __launch_bounds__(64) void k5_final(
    const float* __restrict__ F1w, const float* __restrict__ G1w,
    const float* __restrict__ H1w, const float* __restrict__ Wo1,
    const float* __restrict__ bo1, const float* __restrict__ Wo2,
    const float* __restrict__ bo2, const float* __restrict__ ws,
    float* __restrict__ out)
{
  int g = blockIdx.x, t = threadIdx.x;
  __shared__ float mr0[32], mr1[32], AL[32], TL[32], pl[32], zl[32], ppiL[PO];
  if (t < 32) {
    mr0[t] = (ws[WS_PM0 + (size_t)g*64 + t] + ws[WS_PM0 + (size_t)g*64 + 32 + t]) * (1.f/512.f);
    mr1[t] = (ws[WS_PM1 + (size_t)g*64 + t] + ws[WS_PM1 + (size_t)g*64 + 32 + t]) * (1.f/512.f);
  }
  if (t >= 32 && t < 32+PO) ppiL[t-32] = ws[WS_PPI + (size_t)g*32 + (t-32)];
  __syncthreads();
  float f00 = ws[WS_F0V], f01 = ws[WS_F0V+1];
  if (t < 32) {
    float s0 = ws[WS_C0B + t], s1 = ws[WS_C1B + t];
    for (int k = 0; k < 32; ++k) {
      s0 += mr0[k]*ws[WS_P0B + k*32 + t];
      s1 += mr1[k]*ws[WS_P1B + k*32 + t];
    }
    AL[t] = f00*s0 + f01*s1;
  }
  __syncthreads();
  if (t < 32) {
    float s = 0.f;
    for (int jp = 0; jp < 32; ++jp) s += F1w[t*32+jp]*AL[jp];
    for (int jp = 0; jp < PO; ++jp) s += G1w[t*25+jp]*ppiL[jp];
    TL[t] = s;
  }
  __syncthreads();
  if (t < 32) {
    float s = 0.f;
    for (int j = 0; j < 32; ++j) s += H1w[t*32+j]*TL[j];
    pl[t] = s;
  }
  __syncthreads();
  if (t < 32) {
    float s = bo1[t];
    for (int j = 0; j < 32; ++j) s += pl[j]*Wo1[j*32+t];
    zl[t] = fmaxf(s, 0.f);
  }
  __syncthreads();
  if (t < 2) {
    float s = bo2[t];
    for (int q = 0; q < 32; ++q) s += zl[q]*Wo2[q*2+t];
    int br = g >> 6, b = g & 63;
    out[br*(B_*2) + b*2 + t] = s;
  }
}

// ---------------------------------------------------------------------------
extern "C" void kernel_launch(void* const* d_in, const int* in_sizes, int n_in,
                              void* d_out, int out_size, void* d_ws, size_t ws_size,
                              hipStream_t stream) {
  (void)in_sizes; (void)n_in; (void)out_size; (void)ws_size;
  const float* x1      = (const float*)d_in[0];
  const int*   ei1     = (const int*)  d_in[1];
  const float* PI1     = (const float*)d_in[2];
  const float* x2      = (const float*)d_in[3];
  const int*   ei2     = (const int*)  d_in[4];
  const float* PI2     = (const float*)d_in[5];
  const float* W_score = (const float*)d_in[6];
  const float* b_score = (const float*)d_in[7];
  const float* W_gcn0  = (const float*)d_in[8];
  const float* b_gcn0  = (const float*)d_in[9];
  const float* Wm0a    = (const float*)d_in[10];
  const float* bm0a    = (const float*)d_in[11];
  const float* Wm0b    = (const float*)d_in[12];
  const float* bm0b    = (const float*)d_in[13];
  const float* W_gcn1  = (const float*)d_in[14];
  const float* b_gcn1  = (const float*)d_in[15];
  const float* Wm1a    = (const float*)d_in[16];
  const float* bm1a    = (const float*)d_in[17];
  const float* Wm1b    = (const float*)d_in[18];
  const float* bm1b    = (const float*)d_in[19];
  const float* F0w     = (const float*)d_in[20];
  const float* F1w     = (const float*)d_in[21];
  const float* F2w     = (const float*)d_in[22];
  const float* Kc      = (const float*)d_in[23];
  const float* bc      = (const float*)d_in[24];
  const float* G0w     = (const float*)d_in[25];
  const float* G1w     = (const float*)d_in[26];
  const float* G2w     = (const float*)d_in[27];
  const float* H0w     = (const float*)d_in[28];
  const float* H1w     = (const float*)d_in[29];
  const float* H2w     = (const float*)d_in[30];
  const float* Wo1     = (const float*)d_in[31];
  const float* bo1     = (const float*)d_in[32];
  const float* Wo2     = (const float*)d_in[33];
  const float* bo2     = (const float*)d_in[34];
  float* ws  = (float*)d_ws;
  float* out = (float*)d_out;

  kA_pre<<<8*G_ + 36, 512, 0, stream>>>(x1, x2, W_score,
                                        F0w, F2w, H0w, H2w,
                                        Wm0b, bm0b, Wm1b, bm1b, W_gcn1, ws);
  kPI<<<G_, 256, 0, stream>>>(PI1, PI2, Kc, bc, G0w, G2w, H0w, H2w, ws);
  kBS<<<G_, 1024, 0, stream>>>(ei1, ei2, b_score, ws);
  kG1<<<dim3(G_, 2), 512, 0, stream>>>(x1, x2, W_gcn0, ws);
  kG2<<<dim3(G_, 2), 512, 0, stream>>>(b_gcn0, Wm0a, bm0a, ws);
  kG4<<<dim3(G_, 2), 512, 0, stream>>>(b_gcn1, Wm1a, bm1a, ws);
  k5_final<<<G_, 64, 0, stream>>>(F1w, G1w, H1w, Wo1, bo1, Wo2, bo2, ws, out);
}

// Round 12
// 174.113 us; speedup vs baseline: 1.2642x; 1.2642x over previous
//
#include <hip/hip_runtime.h>
#include <cstdint>

// ---------------------------------------------------------------------------
// TenGCN fused forward. 128 graphs (2 branches x 64 batches).
// R12: kBS radix select restored with wave0 suffix-scan (3 barriers/pass);
// kPI rewritten thread-per-(jp,kp) (register-pressure-proof, ~40 VGPR).
// 7 launches: kA (Dsc+setup) -> kPI -> kBS -> kG1 -> kG2 -> kG4 -> k5.
// ---------------------------------------------------------------------------

constexpr int B_ = 64, N_ = 1024, E_ = 32768, F_ = 128, H_ = 32;
constexpr int CF_ = 5, P_ = 50, K_ = 512, G_ = 128, PO = 25;

// workspace offsets (4-byte units)
constexpr size_t WS_SRCS  = 0;                                // G*E u16 (packed)
constexpr size_t WS_ONODE = WS_SRCS + (size_t)G_*(E_/2);      // G*512 int
constexpr size_t WS_VDEG  = WS_ONODE + (size_t)G_*K_;         // G*512 u16
constexpr size_t WS_EOFF  = WS_VDEG + (size_t)G_*(K_/2);      // G*512 int (packed ceoff)
constexpr size_t WS_DINV  = WS_EOFF + (size_t)G_*K_;          // G*512 f32 (valid dinv)
constexpr size_t WS_GA    = WS_DINV + (size_t)G_*K_;          // G*512*32 f32
constexpr size_t WS_GC    = WS_GA + (size_t)G_*K_*H_;         // G*512*32 f32
constexpr size_t WS_PM0   = WS_GC + (size_t)G_*K_*H_;         // G*2*32
constexpr size_t WS_PM1   = WS_PM0 + (size_t)G_*64;           // G*2*32
constexpr size_t WS_PPI   = WS_PM1 + (size_t)G_*64;           // G*32
constexpr size_t WS_F0V   = WS_PPI + (size_t)G_*32;           // 2 (pad 32)
constexpr size_t WS_B01   = WS_F0V + 32;                      // 32
constexpr size_t WS_C0B   = WS_B01 + 32;                      // 32
constexpr size_t WS_C1B   = WS_C0B + 32;                      // 32
constexpr size_t WS_W01   = WS_C1B + 32;                      // 1024
constexpr size_t WS_P0B   = WS_W01 + 1024;                    // 1024
constexpr size_t WS_P1B   = WS_P0B + 1024;                    // 1024

// Dsc lives in the (dead until kG2) GC region
constexpr size_t WS_DSC   = WS_GC;                            // G*N*5 f32

static __device__ __forceinline__ int swzf4(int row, int c4) {
  return row*32 + (((c4) ^ ((row >> 2) & 7)) << 2);
}

// ---------------------------------------------------------------------------
// kA: blocks [0,8G): Dsc[g][n][5] = x[n] @ Wdiff (quad-per-row, coalesced).
//     blk2 = blk-8G: 0: F0V; 1..32: W01 rows; 33: B01; 34/35: P0b/P1b.
// ---------------------------------------------------------------------------
__global__ __launch_bounds__(512, 4) void kA_pre(
    const float* __restrict__ x1, const float* __restrict__ x2,
    const float* __restrict__ Wsc,
    const float* __restrict__ F0w, const float* __restrict__ F2w,
    const float* __restrict__ H0w, const float* __restrict__ H2w,
    const float* __restrict__ Wm0b, const float* __restrict__ bm0b,
    const float* __restrict__ Wm1b, const float* __restrict__ bm1b,
    const float* __restrict__ Wg1, float* __restrict__ ws)
{
  __shared__ float SM[640];   // 2.56KB union
  int blk = blockIdx.x, t = threadIdx.x;

  if (blk < 8*G_) {
    // ---- Dsc: 8 blocks/graph, 4 threads/row, 64B-coalesced reads ----
    int g = blk >> 3, sub = blk & 7, br = g >> 6, b = g & 63;
    const float* xg = (br ? x2 : x1) + (size_t)b*N_*F_;
    float* WdL = SM;  // 640
    if (t < F_) {
      #pragma unroll
      for (int j = 0; j < 5; ++j) WdL[t*5+j] = Wsc[t*10+2*j+1] - Wsc[t*10+2*j];
    }
    __syncthreads();
    int row = sub*128 + (t >> 2), q = t & 3;
    const float4* xr = (const float4*)(xg + (size_t)row*F_);
    float acc[5] = {};
    #pragma unroll
    for (int i = 0; i < 8; ++i) {
      int k4 = q + 4*i;
      float4 v = xr[k4];
      const float* w = &WdL[k4*20];
      #pragma unroll
      for (int j = 0; j < 5; ++j)
        acc[j] += v.x*w[j] + v.y*w[5+j] + v.z*w[10+j] + v.w*w[15+j];
    }
    #pragma unroll
    for (int j = 0; j < 5; ++j) {
      acc[j] += __shfl_xor(acc[j], 1, 4);
      acc[j] += __shfl_xor(acc[j], 2, 4);
    }
    if (q == 0) {
      float* o = ws + WS_DSC + ((size_t)g*N_ + row)*5;
      #pragma unroll
      for (int j = 0; j < 5; ++j) o[j] = acc[j];
    }
    return;
  }

  int blk2 = blk - 8*G_;
  if (blk2 == 0) {
    // F0V
    float* h0mS = SM;
    if (t < 32) { float s = 0.f; for (int qq = 0; qq < 64; ++qq) s += H0w[qq*64+t]; h0mS[t] = s*(1.f/64.f); }
    __syncthreads();
    if (t < 2) { float s = 0.f; for (int p = 0; p < 32; ++p) s += F0w[p*2+t]*h0mS[p]; ws[WS_F0V+t] = s; }
  } else if (blk2 <= 32) {
    // W01 row kk: 512 thr = 32 cols x 16 k-segments of 64.
    int kk = blk2 - 1;
    int ol = t >> 4, seg = t & 15;
    const float4* ar = (const float4*)(Wm0b + (size_t)kk*1024 + seg*64);
    float s = 0.f;
    #pragma unroll
    for (int i = 0; i < 16; ++i) {
      float4 a = ar[i];
      int tt = seg*64 + i*4;
      s += a.x*Wg1[(tt+0)*32 + ol] + a.y*Wg1[(tt+1)*32 + ol]
         + a.z*Wg1[(tt+2)*32 + ol] + a.w*Wg1[(tt+3)*32 + ol];
    }
    s += __shfl_xor(s, 1, 16);
    s += __shfl_xor(s, 2, 16);
    s += __shfl_xor(s, 4, 16);
    s += __shfl_xor(s, 8, 16);
    if (seg == 0) ws[WS_W01 + kk*32 + ol] = s;
  } else if (blk2 == 33) {
    // B01: 32 cols x 16 segments of 64 + LDS reduce.
    float* red = SM;   // 512
    int j = t & 31, seg = t >> 5;
    float s = 0.f;
    #pragma unroll
    for (int i = 0; i < 64; ++i) {
      int k = seg*64 + i;
      s += bm0b[k]*Wg1[k*32 + j];
    }
    red[seg*32 + j] = s;
    __syncthreads();
    if (t < 32) {
      float a = 0.f;
      #pragma unroll
      for (int q = 0; q < 16; ++q) a += red[q*32 + t];
      ws[WS_B01 + t] = a;
    }
  } else {
    // P0b/c0b (34) and P1b/c1b (35)
    const float* Wb = (blk2 == 34) ? Wm0b : Wm1b;
    const float* bb = (blk2 == 34) ? bm0b : bm1b;
    size_t dstP = (blk2 == 34) ? WS_P0B : WS_P1B;
    size_t dstC = (blk2 == 34) ? WS_C0B : WS_C1B;
    float* h2mL = SM;        // 32
    float* f2vL = SM + 32;   // 32
    if (t < 32) { float s = 0.f; for (int r = 0; r < 32; ++r) s += H2w[r*32+t]; h2mL[t] = s*(1.f/32.f); }
    __syncthreads();
    if (t < 32) { float s = 0.f; for (int r = 0; r < 32; ++r) s += F2w[r*32+t]*h2mL[r]; f2vL[t] = s; }
    __syncthreads();
    if (t < 256) {
      #pragma unroll
      for (int q = 0; q < 4; ++q) {
        int e = t*4 + q;
        int k = e >> 5, c = e & 31;
        float s = 0.f;
        #pragma unroll
        for (int kp = 0; kp < 32; ++kp) s += Wb[k*1024 + c*32 + kp]*f2vL[kp];
        ws[dstP + e] = s;
      }
    }
    if (t < 32) {
      float s = 0.f;
      #pragma unroll
      for (int kp = 0; kp < 32; ++kp) s += bb[t*32+kp]*f2vL[kp];
      ws[dstC+t] = s;
    }
  }
}

// ---------------------------------------------------------------------------
// kPI: PI conv + relu reduced by g0v/g2v. Thread-per-(jp,kp): 20 PI taps
// hoisted to registers per position, 32-channel loop reuses them.
// ---------------------------------------------------------------------------
__global__ __launch_bounds__(256, 4) void kPI(
    const float* __restrict__ PI1, const float* __restrict__ PI2,
    const float* __restrict__ Kc, const float* __restrict__ bc,
    const float* __restrict__ G0w, const float* __restrict__ G2w,
    const float* __restrict__ H0w, const float* __restrict__ H2w,
    float* __restrict__ ws)
{
  int g = blockIdx.x, br = g >> 6, b = g & 63;
  const float* pig = (br ? PI2 : PI1) + (size_t)b*CF_*P_*P_;
  __shared__ float PIt[CF_*P_*P_];   // 50KB
  __shared__ float KcL[H_*CF_*4];    // 2.5KB
  __shared__ float bcL[H_], g0L[H_], g2L[PO], h2L[H_], hhL[H_];
  __shared__ float scr[640];         // 625 partials
  int t = threadIdx.x;
  for (int i = t; i < CF_*P_*P_; i += 256) PIt[i] = pig[i];
  for (int i = t; i < H_*CF_*4; i += 256) KcL[i] = Kc[i];
  // hhL[p] = mean_q H0w[q*64 + 32 + p]   (32 outs x 8 segments)
  {
    int p = t >> 3, s = t & 7;
    float v = 0.f;
    #pragma unroll
    for (int q = 0; q < 8; ++q) v += H0w[(s + q*8)*64 + 32 + p];
    #pragma unroll
    for (int d = 4; d > 0; d >>= 1) v += __shfl_down(v, d, 8);
    if (s == 0) hhL[p] = v * (1.f/64.f);
  }
  // h2L[r] = mean_rr H2w[rr*32 + r]      (32 outs x 8 segments of 4)
  {
    int r = t >> 3, s = t & 7;
    float v = 0.f;
    #pragma unroll
    for (int q = 0; q < 4; ++q) v += H2w[(s + q*8)*32 + r];
    #pragma unroll
    for (int d = 4; d > 0; d >>= 1) v += __shfl_down(v, d, 8);
    if (s == 0) h2L[r] = v * (1.f/32.f);
  }
  if (t < 32) bcL[t] = bc[t];
  __syncthreads();
  if (t < 32) { float s = 0.f; for (int p = 0; p < 32; ++p) s += G0w[p*32+t]*hhL[p]; g0L[t] = s; }
  if (t >= 64 && t < 64+PO) {
    int kp = t - 64;
    float s = 0.f;
    for (int r = 0; r < 32; ++r) s += G2w[r*25+kp]*h2L[r];
    g2L[kp] = s;
  }
  __syncthreads();
  for (int pos = t; pos < PO*PO; pos += 256) {
    int jp = pos / PO, kp = pos - jp*PO;
    float p00[CF_], p01[CF_], p10[CF_], p11[CF_];
    #pragma unroll
    for (int c = 0; c < CF_; ++c) {
      const float* q = &PIt[c*2500 + (2*jp)*50 + 2*kp];
      p00[c] = q[0]; p01[c] = q[1]; p10[c] = q[50]; p11[c] = q[51];
    }
    float acc = 0.f;
    for (int i = 0; i < H_; ++i) {
      float v = bcL[i];
      const float* kcp = &KcL[i*20];
      #pragma unroll
      for (int c = 0; c < CF_; ++c)
        v += p00[c]*kcp[c*4+0] + p01[c]*kcp[c*4+1] + p10[c]*kcp[c*4+2] + p11[c]*kcp[c*4+3];
      acc += fmaxf(v, 0.f) * g0L[i];
    }
    scr[pos] = acc * g2L[kp];
  }
  __syncthreads();
  if (t < PO) {
    float s = 0.f;
    #pragma unroll
    for (int k = 0; k < PO; ++k) s += scr[t*PO + k];
    ws[WS_PPI + (size_t)g*32 + t] = s;
  }
}

// ---------------------------------------------------------------------------
// kBS: per-graph count -> scan -> scatter(LDS) -> score(LDS gather) ->
// radix top-512 (wave0 suffix-scan, 3 barriers/pass) -> compact -> packed CSR.
// ---------------------------------------------------------------------------
__global__ __launch_bounds__(1024, 4) void kBS(
    const int* __restrict__ ei1, const int* __restrict__ ei2,
    const float* __restrict__ bsc, float* __restrict__ ws)
{
  int g = blockIdx.x, br = g >> 6, b = g & 63;
  const int* ei  = (br ? ei2 : ei1) + (size_t)b*2*E_;
  const int* src = ei;
  const int* dst = ei + E_;
  int* onodeg = (int*)ws + WS_ONODE + (size_t)g*K_;
  uint16_t* vdegg = (uint16_t*)(ws + WS_VDEG) + (size_t)g*K_;
  int* ceoffg = (int*)ws + WS_EOFF + (size_t)g*K_;
  float* dinvg = ws + WS_DINV + (size_t)g*K_;
  uint16_t* csrc = (uint16_t*)(ws + WS_SRCS) + (size_t)g*E_;

  __shared__ uint16_t srcL[E_];    // 64KB
  __shared__ float DscL[N_*5];     // 20KB
  __shared__ float dinvF[N_];      // 4KB
  __shared__ int fbL[N_];          // 4KB
  __shared__ int fillL[N_];        // 4KB
  __shared__ int nidxL[N_];        // 4KB
  __shared__ int seoffL[K_];       // 2KB
  __shared__ int vdegL[K_];        // 2KB
  __shared__ int ceoffL[K_];       // 2KB
  __shared__ int hist[256], hsum[256];
  __shared__ int wtot[16], wbase[16], wsum[16];
  __shared__ int remL, dstarL;

  int t = threadIdx.x;
  { const float* Dg = ws + WS_DSC + (size_t)g*N_*5;
    for (int i = t; i < N_*5; i += 1024) DscL[i] = Dg[i]; }
  fillL[t] = 0;
  if (t < 256) hist[t] = 0;
  if (t == 0) remL = K_;
  __syncthreads();

  // A: count
  for (int i = 0; i < E_/1024; ++i) {
    int d = dst[t + i*1024];
    atomicAdd(&fillL[d], 1);
  }
  __syncthreads();

  // B: exclusive scan of counts
  int c = fillL[t];
  int lane = t & 63, w = t >> 6;
  int x = c;
  #pragma unroll
  for (int s = 1; s < 64; s <<= 1) {
    int v = __shfl_up(x, s);
    if (lane >= s) x += v;
  }
  if (lane == 63) wsum[w] = x;
  __syncthreads();
  if (w == 0 && lane < 16) {
    int y = wsum[lane];
    #pragma unroll
    for (int s = 1; s < 16; s <<= 1) {
      int v = __shfl_up(y, s, 16);
      if (lane >= s) y += v;
    }
    wsum[lane] = y;
  }
  __syncthreads();
  int off0 = ((w == 0) ? 0 : wsum[w-1]) + x - c;
  int off1 = off0 + c;
  fbL[t] = off0;
  dinvF[t] = rsqrtf((float)c + 1.0f);
  fillL[t] = 0;
  __syncthreads();

  // C: scatter into LDS
  for (int i = 0; i < E_/1024; ++i) {
    int e = t + i*1024;
    int d = dst[e], s = src[e];
    int pos = fbL[d] + atomicAdd(&fillL[d], 1);
    srcL[pos] = (uint16_t)s;
  }
  __syncthreads();

  // D: score gather from LDS
  uint32_t key;
  {
    float agg[5] = {};
    for (int e = off0; e < off1; ++e) {
      int s = srcL[e];
      float dvs = dinvF[s];
      const float* hr = &DscL[s*5];
      #pragma unroll
      for (int j = 0; j < 5; ++j) agg[j] += hr[j]*dvs;
    }
    float dv = dinvF[t];
    const float* hn = &DscL[t*5];
    float sc = 0.f;
    #pragma unroll
    for (int j = 0; j < 5; ++j)
      sc += fabsf(dv*(agg[j] + dv*hn[j]) + (bsc[2*j+1] - bsc[2*j]));
    key = __float_as_uint(sc);   // sc >= 0 -> uint order == float order
  }
  __syncthreads();

  // E: 4-pass radix select; wave0 does the 256-bin suffix scan via shfl.
  uint32_t pref = 0, prefMask = 0;
  #pragma unroll
  for (int pass = 0; pass < 4; ++pass) {
    int shift = 24 - 8*pass;
    bool cand = (key & prefMask) == pref;
    if (cand) atomicAdd(&hist[(key >> shift) & 255], 1);
    __syncthreads();                          // B1: hist complete
    if (w == 0) {
      int base = lane*4;
      int h0 = hist[base+0], h1 = hist[base+1], h2 = hist[base+2], h3 = hist[base+3];
      int suf = h0 + h1 + h2 + h3;
      #pragma unroll
      for (int sh = 1; sh < 64; sh <<= 1) {
        int v = __shfl_down(suf, sh);
        if (lane + sh < 64) suf += v;
      }
      hsum[base+0] = suf;
      hsum[base+1] = suf - h0;
      hsum[base+2] = suf - h0 - h1;
      hsum[base+3] = suf - h0 - h1 - h2;
    }
    __syncthreads();                          // B2: hsum visible
    int rem = remL;
    if (t < 256) {
      int above = (t == 255) ? 0 : hsum[t+1];
      if (hsum[t] >= rem && above < rem) dstarL = t;
      hist[t] = 0;                            // zero for next pass
    }
    __syncthreads();                          // B3: dstar + zero done
    int ds = dstarL;
    if (t == 0) remL = rem - ((ds == 255) ? 0 : hsum[ds+1]);
    pref |= (uint32_t)ds << shift;
    prefMask |= 0xFFu << shift;
  }
  __syncthreads();
  uint32_t T = pref;
  int r = remL;

  // ties (key == T) rank by idx asc; select key>T plus first r ties
  bool eq = (key == T);
  uint64_t mEq = __ballot(eq);
  int lpEq = (int)__popcll(mEq & ((1ull << lane) - 1));
  if (lane == 0) wtot[w] = (int)__popcll(mEq);
  __syncthreads();
  if (t == 0) { int a = 0; for (int q = 0; q < 16; ++q) { wbase[q] = a; a += wtot[q]; } }
  __syncthreads();
  bool sel = (key > T) || (eq && (wbase[w] + lpEq) < r);
  __syncthreads();
  uint64_t mS = __ballot(sel);
  int lpS = (int)__popcll(mS & ((1ull << lane) - 1));
  if (lane == 0) wtot[w] = (int)__popcll(mS);
  __syncthreads();
  if (t == 0) { int a = 0; for (int q = 0; q < 16; ++q) { wbase[q] = a; a += wtot[q]; } }
  __syncthreads();
  int rank = wbase[w] + lpS;
  nidxL[t] = sel ? rank : -1;
  if (sel) onodeg[rank] = t;
  __syncthreads();

  // F: compact own segment in place (remap to ranks)
  if (sel) {
    int c2 = 0;
    for (int e = off0; e < off1; ++e) {
      int m = nidxL[srcL[e]];
      if (m >= 0) srcL[off0 + (c2++)] = (uint16_t)m;
    }
    vdegL[rank] = c2;
    seoffL[rank] = off0;
  }
  __syncthreads();

  // G: scan vdeg over 512 ranks -> packed offsets
  int vv = 0, xx = 0, w2 = t >> 6;
  if (t < K_) {
    vv = vdegL[t]; xx = vv;
    int l2 = t & 63;
    #pragma unroll
    for (int s = 1; s < 64; s <<= 1) {
      int v = __shfl_up(xx, s);
      if (l2 >= s) xx += v;
    }
    if (l2 == 63) wsum[w2] = xx;
  }
  __syncthreads();
  if (t == 0) { int run = 0; for (int q = 0; q < 8; ++q) { int tm = wsum[q]; wsum[q] = run; run += tm; } }
  __syncthreads();
  if (t < K_) {
    int ce = wsum[w2] + xx - vv;
    ceoffL[t] = ce;
    ceoffg[t] = ce;
    vdegg[t] = (uint16_t)vv;
    dinvg[t] = rsqrtf((float)vv + 1.0f);
  }
  __syncthreads();

  // H: write packed edge list
  if (t < K_) {
    int s0 = seoffL[t], n = vdegL[t], d0 = ceoffL[t];
    for (int i = 0; i < n; ++i) csrc[d0 + i] = srcL[s0 + i];
  }
}

// ---------------------------------------------------------------------------
// 256x32 @ 32x32 matmul core on swizzled LDS; W padded [32][36].
// ---------------------------------------------------------------------------
static __device__ __forceinline__ void mmA(
    const float* __restrict__ S, const float* __restrict__ Wp,
    float (&acc)[4][4], int it, int jt)
{
  const int i0 = it*4, swa = it & 7;
  #pragma unroll
  for (int kv = 0; kv < 8; ++kv) {
    float4 w0 = *(const float4*)&Wp[(kv*4+0)*36 + jt*4];
    float4 w1 = *(const float4*)&Wp[(kv*4+1)*36 + jt*4];
    float4 w2 = *(const float4*)&Wp[(kv*4+2)*36 + jt*4];
    float4 w3 = *(const float4*)&Wp[(kv*4+3)*36 + jt*4];
    #pragma unroll
    for (int d = 0; d < 4; ++d) {
      float4 a = *(const float4*)&S[(i0+d)*32 + ((kv ^ swa) << 2)];
      acc[d][0] += a.x*w0.x + a.y*w1.x + a.z*w2.x + a.w*w3.x;
      acc[d][1] += a.x*w0.y + a.y*w1.y + a.z*w2.y + a.w*w3.y;
      acc[d][2] += a.x*w0.z + a.y*w1.z + a.z*w2.z + a.w*w3.z;
      acc[d][3] += a.x*w0.w + a.y*w1.w + a.z*w2.w + a.w*w3.w;
    }
  }
}

// ---------------------------------------------------------------------------
// kG1: gA[g][dd] = dinv[dd] * (x[onode[dd]] @ Wg0).  grid (G,2) x 512.
// ---------------------------------------------------------------------------
__global__ __launch_bounds__(512, 4) void kG1(
    const float* __restrict__ x1, const float* __restrict__ x2,
    const float* __restrict__ Wg0, float* __restrict__ ws)
{
  int g = blockIdx.x, half = blockIdx.y, br = g >> 6, b = g & 63;
  const float* xg = (br ? x2 : x1) + (size_t)b*N_*F_;
  const int* onodeg = (const int*)ws + WS_ONODE + (size_t)g*K_ + half*256;
  const float* dinvg = ws + WS_DINV + (size_t)g*K_ + half*256;
  float* gAg = ws + WS_GA + (size_t)g*K_*H_ + (size_t)half*256*H_;

  __shared__ float wbuf[F_*36];
  __shared__ int   onodeL[256];
  __shared__ float dinvL[256];

  int t = threadIdx.x;
  for (int i = t; i < F_*H_; i += 512) wbuf[(i >> 5)*36 + (i & 31)] = Wg0[i];
  if (t < 256) { onodeL[t] = onodeg[t]; dinvL[t] = dinvg[t]; }
  __syncthreads();

  const int it = t >> 3, jt = t & 7;
  const int i0 = it*4;
  const float* xr0 = xg + (size_t)onodeL[i0+0]*F_;
  const float* xr1 = xg + (size_t)onodeL[i0+1]*F_;
  const float* xr2 = xg + (size_t)onodeL[i0+2]*F_;
  const float* xr3 = xg + (size_t)onodeL[i0+3]*F_;
  float acc[4][4] = {};
  for (int k4 = 0; k4 < 32; ++k4) {
    float4 w0 = *(const float4*)&wbuf[(k4*4+0)*36 + jt*4];
    float4 w1 = *(const float4*)&wbuf[(k4*4+1)*36 + jt*4];
    float4 w2 = *(const float4*)&wbuf[(k4*4+2)*36 + jt*4];
    float4 w3 = *(const float4*)&wbuf[(k4*4+3)*36 + jt*4];
    float4 a;
    a = *(const float4*)(xr0 + k4*4);
    acc[0][0]+=a.x*w0.x+a.y*w1.x+a.z*w2.x+a.w*w3.x; acc[0][1]+=a.x*w0.y+a.y*w1.y+a.z*w2.y+a.w*w3.y;
    acc[0][2]+=a.x*w0.z+a.y*w1.z+a.z*w2.z+a.w*w3.z; acc[0][3]+=a.x*w0.w+a.y*w1.w+a.z*w2.w+a.w*w3.w;
    a = *(const float4*)(xr1 + k4*4);
    acc[1][0]+=a.x*w0.x+a.y*w1.x+a.z*w2.x+a.w*w3.x; acc[1][1]+=a.x*w0.y+a.y*w1.y+a.z*w2.y+a.w*w3.y;
    acc[1][2]+=a.x*w0.z+a.y*w1.z+a.z*w2.z+a.w*w3.z; acc[1][3]+=a.x*w0.w+a.y*w1.w+a.z*w2.w+a.w*w3.w;
    a = *(const float4*)(xr2 + k4*4);
    acc[2][0]+=a.x*w0.x+a.y*w1.x+a.z*w2.x+a.w*w3.x; acc[2][1]+=a.x*w0.y+a.y*w1.y+a.z*w2.y+a.w*w3.y;
    acc[2][2]+=a.x*w0.z+a.y*w1.z+a.z*w2.z+a.w*w3.z; acc[2][3]+=a.x*w0.w+a.y*w1.w+a.z*w2.w+a.w*w3.w;
    a = *(const float4*)(xr3 + k4*4);
    acc[3][0]+=a.x*w0.x+a.y*w1.x+a.z*w2.x+a.w*w3.x; acc[3][1]+=a.x*w0.y+a.y*w1.y+a.z*w2.y+a.w*w3.y;
    acc[3][2]+=a.x*w0.z+a.y*w1.z+a.z*w2.z+a.w*w3.z; acc[3][3]+=a.x*w0.w+a.y*w1.w+a.z*w2.w+a.w*w3.w;
  }
  #pragma unroll
  for (int d = 0; d < 4; ++d) {
    int row = i0 + d;
    float rs = dinvL[row];
    float4 o; o.x=acc[d][0]*rs; o.y=acc[d][1]*rs; o.z=acc[d][2]*rs; o.w=acc[d][3]*rs;
    *(float4*)&gAg[row*32 + jt*4] = o;
  }
}

// ---------------------------------------------------------------------------
// conv gather (packed CSR) from global feature buffer into swizzled LDS.
// ---------------------------------------------------------------------------
static __device__ __forceinline__ void convG(
    const float* __restrict__ gS, float* __restrict__ cbuf,
    const float* __restrict__ bias, const float* __restrict__ dinvL,
    const int* __restrict__ eoffL, const int* __restrict__ vcntL,
    const uint16_t* __restrict__ srcS, int half, int t)
{
  int ddl = t & 255, hc = t >> 8;
  int dd = half*256 + ddl;
  int lo = eoffL[ddl], n = vcntL[ddl];
  int c0 = hc*16;
  float4 a0 = {0,0,0,0}, a1 = a0, a2 = a0, a3 = a0;
  for (int i = 0; i < n; ++i) {
    int ss = srcS[lo + i];
    const float* r = gS + ss*32 + c0;
    float4 v;
    v = *(const float4*)(r+0);  a0.x+=v.x; a0.y+=v.y; a0.z+=v.z; a0.w+=v.w;
    v = *(const float4*)(r+4);  a1.x+=v.x; a1.y+=v.y; a1.z+=v.z; a1.w+=v.w;
    v = *(const float4*)(r+8);  a2.x+=v.x; a2.y+=v.y; a2.z+=v.z; a2.w+=v.w;
    v = *(const float4*)(r+12); a3.x+=v.x; a3.y+=v.y; a3.z+=v.z; a3.w+=v.w;
  }
  { const float* r = gS + dd*32 + c0;
    float4 v;
    v = *(const float4*)(r+0);  a0.x+=v.x; a0.y+=v.y; a0.z+=v.z; a0.w+=v.w;
    v = *(const float4*)(r+4);  a1.x+=v.x; a1.y+=v.y; a1.z+=v.z; a1.w+=v.w;
    v = *(const float4*)(r+8);  a2.x+=v.x; a2.y+=v.y; a2.z+=v.z; a2.w+=v.w;
    v = *(const float4*)(r+12); a3.x+=v.x; a3.y+=v.y; a3.z+=v.z; a3.w+=v.w; }
  float dvd = dinvL[ddl];
  float4 r0, r1, r2, r3;
  r0.x = dvd*a0.x + bias[c0+0];  r0.y = dvd*a0.y + bias[c0+1];
  r0.z = dvd*a0.z + bias[c0+2];  r0.w = dvd*a0.w + bias[c0+3];
  r1.x = dvd*a1.x + bias[c0+4];  r1.y = dvd*a1.y + bias[c0+5];
  r1.z = dvd*a1.z + bias[c0+6];  r1.w = dvd*a1.w + bias[c0+7];
  r2.x = dvd*a2.x + bias[c0+8];  r2.y = dvd*a2.y + bias[c0+9];
  r2.z = dvd*a2.z + bias[c0+10]; r2.w = dvd*a2.w + bias[c0+11];
  r3.x = dvd*a3.x + bias[c0+12]; r3.y = dvd*a3.y + bias[c0+13];
  r3.z = dvd*a3.z + bias[c0+14]; r3.w = dvd*a3.w + bias[c0+15];
  int g4 = hc*4;
  *(float4*)&cbuf[swzf4(ddl, g4+0)] = r0;
  *(float4*)&cbuf[swzf4(ddl, g4+1)] = r1;
  *(float4*)&cbuf[swzf4(ddl, g4+2)] = r2;
  *(float4*)&cbuf[swzf4(ddl, g4+3)] = r3;
}

// ---------------------------------------------------------------------------
// kG2: conv0 -> r0=relu(.@Wm0a+b) -> {column partials, gC=(r0@W01+b01)*dinv}
// ---------------------------------------------------------------------------
__global__ __launch_bounds__(512, 4) void kG2(
    const float* __restrict__ bg0,
    const float* __restrict__ Wm0a, const float* __restrict__ bm0a,
    float* __restrict__ ws)
{
  int g = blockIdx.x, half = blockIdx.y;
  const float* gAg = ws + WS_GA + (size_t)g*K_*H_;
  float* gCg = ws + WS_GC + (size_t)g*K_*H_;
  const uint16_t* srcS = (const uint16_t*)(ws + WS_SRCS) + (size_t)g*E_;
  const int* eoffg = (const int*)ws + WS_EOFF + (size_t)g*K_ + half*256;
  const uint16_t* vdegg = (const uint16_t*)(ws + WS_VDEG) + (size_t)g*K_ + half*256;
  const float* dinvg = ws + WS_DINV + (size_t)g*K_ + half*256;

  __shared__ float cbufA[256*32];
  __shared__ float cbufB[256*32];
  __shared__ float wA[32*36];
  __shared__ float wB[32*36];
  __shared__ float scrP[64*33];
  __shared__ int   eoffL[256];
  __shared__ int   vcntL[256];
  __shared__ float dinvL[256];

  int t = threadIdx.x;
  for (int i = t; i < 1024; i += 512) {
    int k = i >> 5, j = i & 31;
    wA[k*36+j] = Wm0a[i];
    wB[k*36+j] = ws[WS_W01 + i];
  }
  if (t < 256) { eoffL[t] = eoffg[t]; vcntL[t] = vdegg[t]; dinvL[t] = dinvg[t]; }
  __syncthreads();

  convG(gAg, cbufA, bg0, dinvL, eoffL, vcntL, srcS, half, t);
  __syncthreads();

  const int it = t >> 3, jt = t & 7;
  float acc[4][4] = {};
  mmA(cbufA, wA, acc, it, jt);
  {
    float b0 = bm0a[jt*4+0], b1 = bm0a[jt*4+1], b2 = bm0a[jt*4+2], b3 = bm0a[jt*4+3];
    float cp0=0.f, cp1=0.f, cp2=0.f, cp3=0.f;
    #pragma unroll
    for (int d = 0; d < 4; ++d) {
      float v0=fmaxf(acc[d][0]+b0,0.f), v1=fmaxf(acc[d][1]+b1,0.f);
      float v2=fmaxf(acc[d][2]+b2,0.f), v3=fmaxf(acc[d][3]+b3,0.f);
      cp0+=v0; cp1+=v1; cp2+=v2; cp3+=v3;
      float4 o; o.x=v0; o.y=v1; o.z=v2; o.w=v3;
      *(float4*)&cbufB[swzf4(it*4+d, jt)] = o;
    }
    scrP[it*33 + jt*4+0] = cp0; scrP[it*33 + jt*4+1] = cp1;
    scrP[it*33 + jt*4+2] = cp2; scrP[it*33 + jt*4+3] = cp3;
  }
  __syncthreads();

  if (t < 32) {
    float s = 0.f;
    #pragma unroll
    for (int q = 0; q < 64; ++q) s += scrP[q*33 + t];
    ws[WS_PM0 + (size_t)g*64 + half*32 + t] = s;
  }

  float acc2[4][4] = {};
  mmA(cbufB, wB, acc2, it, jt);
  {
    float b0 = ws[WS_B01+jt*4+0], b1 = ws[WS_B01+jt*4+1];
    float b2 = ws[WS_B01+jt*4+2], b3 = ws[WS_B01+jt*4+3];
    #pragma unroll
    for (int d = 0; d < 4; ++d) {
      int row = it*4 + d;
      float rs = dinvL[row];
      float4 o;
      o.x=(acc2[d][0]+b0)*rs; o.y=(acc2[d][1]+b1)*rs;
      o.z=(acc2[d][2]+b2)*rs; o.w=(acc2[d][3]+b3)*rs;
      *(float4*)&gCg[(half*256+row)*32 + jt*4] = o;
    }
  }
}

// ---------------------------------------------------------------------------
// kG4: conv1 -> r1=relu(.@Wm1a+b) -> column partials.
// ---------------------------------------------------------------------------
__global__ __launch_bounds__(512, 4) void kG4(
    const float* __restrict__ bg1,
    const float* __restrict__ Wm1a, const float* __restrict__ bm1a,
    float* __restrict__ ws)
{
  int g = blockIdx.x, half = blockIdx.y;
  const float* gCg = ws + WS_GC + (size_t)g*K_*H_;
  const uint16_t* srcS = (const uint16_t*)(ws + WS_SRCS) + (size_t)g*E_;
  const int* eoffg = (const int*)ws + WS_EOFF + (size_t)g*K_ + half*256;
  const uint16_t* vdegg = (const uint16_t*)(ws + WS_VDEG) + (size_t)g*K_ + half*256;
  const float* dinvg = ws + WS_DINV + (size_t)g*K_ + half*256;

  __shared__ float cbufA[256*32];
  __shared__ float wA[32*36];
  __shared__ float scrP[64*33];
  __shared__ int   eoffL[256];
  __shared__ int   vcntL[256];
  __shared__ float dinvL[256];

  int t = threadIdx.x;
  for (int i = t; i < 1024; i += 512) wA[(i>>5)*36 + (i&31)] = Wm1a[i];
  if (t < 256) { eoffL[t] = eoffg[t]; vcntL[t] = vdegg[t]; dinvL[t] = dinvg[t]; }
  __syncthreads();

  convG(gCg, cbufA, bg1, dinvL, eoffL, vcntL, srcS, half, t);
  __syncthreads();

  const int it = t >> 3, jt = t & 7;
  float acc[4][4] = {};
  mmA(cbufA, wA, acc, it, jt);
  {
    float b0 = bm1a[jt*4+0], b1 = bm1a[jt*4+1], b2 = bm1a[jt*4+2], b3 = bm1a[jt*4+3];
    float cp0=0.f, cp1=0.f, cp2=0.f, cp3=0.f;
    #pragma unroll
    for (int d = 0; d < 4; ++d) {
      cp0 += fmaxf(acc[d][0]+b0,0.f); cp1 += fmaxf(acc[d][1]+b1,0.f);
      cp2 += fmaxf(acc[d][2]+b2,0.f); cp3 += fmaxf(acc[d][3]+b3,0.f);
    }
    scrP[it*33 + jt*4+0] = cp0; scrP[it*33 + jt*4+1] = cp1;
    scrP[it*33 + jt*4+2] = cp2; scrP[it*33 + jt*4+3] = cp3;
  }
  __syncthreads();

  if (t < 32) {
    float s = 0.f;
    #pragma unroll
    for (int q = 0; q < 64; ++q) s += scrP[q*33 + t];
    ws[WS_PM1 + (size_t)g*64 + half*32 + t] = s;
  }
}

// ---------------------------------------------------------------------------
// k5: per-graph tail via folded P0b/P1b. grid G x 64.
// ---------------------------------------------------------------------------
__global__ __launch_bounds__(64) void k5_final(
    const float* __restrict__ F1w, const float* __restrict__ G1w,
    const float* __restrict__ H1w, const float* __restrict__ Wo1,
    const float* __restrict__ bo1, const float* __restrict__ Wo2,
    const float* __restrict__ bo2, const float* __restrict__ ws,
    float* __restrict__ out)
{
  int g = blockIdx.x, t = threadIdx.x;
  __shared__ float mr0[32], mr1[32], AL[32], TL[32], pl[32], zl[32], ppiL[PO];
  if (t < 32) {
    mr0[t] = (ws[WS_PM0 + (size_t)g*64 + t] + ws[WS_PM0 + (size_t)g*64 + 32 + t]) * (1.f/512.f);
    mr1[t] = (ws[WS_PM1 + (size_t)g*64 + t] + ws[WS_PM1 + (size_t)g*64 + 32 + t]) * (1.f/512.f);
  }
  if (t >= 32 && t < 32+PO) ppiL[t-32] = ws[WS_PPI + (size_t)g*32 + (t-32)];
  __syncthreads();
  float f00 = ws[WS_F0V], f01 = ws[WS_F0V+1];
  if (t < 32) {
    float s0 = ws[WS_C0B + t], s1 = ws[WS_C1B + t];
    for (int k = 0; k < 32; ++k) {
      s0 += mr0[k]*ws[WS_P0B + k*32 + t];
      s1 += mr1[k]*ws[WS_P1B + k*32 + t];
    }
    AL[t] = f00*s0 + f01*s1;
  }
  __syncthreads();
  if (t < 32) {
    float s = 0.f;
    for (int jp = 0; jp < 32; ++jp) s += F1w[t*32+jp]*AL[jp];
    for (int jp = 0; jp < PO; ++jp) s += G1w[t*25+jp]*ppiL[jp];
    TL[t] = s;
  }
  __syncthreads();
  if (t < 32) {
    float s = 0.f;
    for (int j = 0; j < 32; ++j) s += H1w[t*32+j]*TL[j];
    pl[t] = s;
  }
  __syncthreads();
  if (t < 32) {
    float s = bo1[t];
    for (int j = 0; j < 32; ++j) s += pl[j]*Wo1[j*32+t];
    zl[t] = fmaxf(s, 0.f);
  }
  __syncthreads();
  if (t < 2) {
    float s = bo2[t];
    for (int q = 0; q < 32; ++q) s += zl[q]*Wo2[q*2+t];
    int br = g >> 6, b = g & 63;
    out[br*(B_*2) + b*2 + t] = s;
  }
}

// ---------------------------------------------------------------------------
extern "C" void kernel_launch(void* const* d_in, const int* in_sizes, int n_in,
                              void* d_out, int out_size, void* d_ws, size_t ws_size,
                              hipStream_t stream) {
  (void)in_sizes; (void)n_in; (void)out_size; (void)ws_size;
  const float* x1      = (const float*)d_in[0];
  const int*   ei1     = (const int*)  d_in[1];
  const float* PI1     = (const float*)d_in[2];
  const float* x2      = (const float*)d_in[3];
  const int*   ei2     = (const int*)  d_in[4];
  const float* PI2     = (const float*)d_in[5];
  const float* W_score = (const float*)d_in[6];
  const float* b_score = (const float*)d_in[7];
  const float* W_gcn0  = (const float*)d_in[8];
  const float* b_gcn0  = (const float*)d_in[9];
  const float* Wm0a    = (const float*)d_in[10];
  const float* bm0a    = (const float*)d_in[11];
  const float* Wm0b    = (const float*)d_in[12];
  const float* bm0b    = (const float*)d_in[13];
  const float* W_gcn1  = (const float*)d_in[14];
  const float* b_gcn1  = (const float*)d_in[15];
  const float* Wm1a    = (const float*)d_in[16];
  const float* bm1a    = (const float*)d_in[17];
  const float* Wm1b    = (const float*)d_in[18];
  const float* bm1b    = (const float*)d_in[19];
  const float* F0w     = (const float*)d_in[20];
  const float* F1w     = (const float*)d_in[21];
  const float* F2w     = (const float*)d_in[22];
  const float* Kc      = (const float*)d_in[23];
  const float* bc      = (const float*)d_in[24];
  const float* G0w     = (const float*)d_in[25];
  const float* G1w     = (const float*)d_in[26];
  const float* G2w     = (const float*)d_in[27];
  const float* H0w     = (const float*)d_in[28];
  const float* H1w     = (const float*)d_in[29];
  const float* H2w     = (const float*)d_in[30];
  const float* Wo1     = (const float*)d_in[31];
  const float* bo1     = (const float*)d_in[32];
  const float* Wo2     = (const float*)d_in[33];
  const float* bo2     = (const float*)d_in[34];
  float* ws  = (float*)d_ws;
  float* out = (float*)d_out;

  kA_pre<<<8*G_ + 36, 512, 0, stream>>>(x1, x2, W_score,
                                        F0w, F2w, H0w, H2w,
                                        Wm0b, bm0b, Wm1b, bm1b, W_gcn1, ws);
  kPI<<<G_, 256, 0, stream>>>(PI1, PI2, Kc, bc, G0w, G2w, H0w, H2w, ws);
  kBS<<<G_, 1024, 0, stream>>>(ei1, ei2, b_score, ws);
  kG1<<<dim3(G_, 2), 512, 0, stream>>>(x1, x2, W_gcn0, ws);
  kG2<<<dim3(G_, 2), 512, 0, stream>>>(b_gcn0, Wm0a, bm0a, ws);
  kG4<<<dim3(G_, 2), 512, 0, stream>>>(b_gcn1, Wm1a, bm1a, ws);
  k5_final<<<G_, 64, 0, stream>>>(F1w, G1w, H1w, Wo1, bo1, Wo2, bo2, ws, out);
}

// Round 13
// 169.436 us; speedup vs baseline: 1.2991x; 1.0276x over previous
//
#include <hip/hip_runtime.h>
#include <cstdint>

// ---------------------------------------------------------------------------
// TenGCN fused forward. 128 graphs (2 branches x 64 batches).
// R13: kBS edge list register-cached (single global read), packed-CSR write
// coalesced via binary search. Radix select as R12 (wave0 suffix-scan).
// 7 launches: kA (Dsc+setup) -> kPI -> kBS -> kG1 -> kG2 -> kG4 -> k5.
// ---------------------------------------------------------------------------

constexpr int B_ = 64, N_ = 1024, E_ = 32768, F_ = 128, H_ = 32;
constexpr int CF_ = 5, P_ = 50, K_ = 512, G_ = 128, PO = 25;

// workspace offsets (4-byte units)
constexpr size_t WS_SRCS  = 0;                                // G*E u16 (packed)
constexpr size_t WS_ONODE = WS_SRCS + (size_t)G_*(E_/2);      // G*512 int
constexpr size_t WS_VDEG  = WS_ONODE + (size_t)G_*K_;         // G*512 u16
constexpr size_t WS_EOFF  = WS_VDEG + (size_t)G_*(K_/2);      // G*512 int (packed ceoff)
constexpr size_t WS_DINV  = WS_EOFF + (size_t)G_*K_;          // G*512 f32 (valid dinv)
constexpr size_t WS_GA    = WS_DINV + (size_t)G_*K_;          // G*512*32 f32
constexpr size_t WS_GC    = WS_GA + (size_t)G_*K_*H_;         // G*512*32 f32
constexpr size_t WS_PM0   = WS_GC + (size_t)G_*K_*H_;         // G*2*32
constexpr size_t WS_PM1   = WS_PM0 + (size_t)G_*64;           // G*2*32
constexpr size_t WS_PPI   = WS_PM1 + (size_t)G_*64;           // G*32
constexpr size_t WS_F0V   = WS_PPI + (size_t)G_*32;           // 2 (pad 32)
constexpr size_t WS_B01   = WS_F0V + 32;                      // 32
constexpr size_t WS_C0B   = WS_B01 + 32;                      // 32
constexpr size_t WS_C1B   = WS_C0B + 32;                      // 32
constexpr size_t WS_W01   = WS_C1B + 32;                      // 1024
constexpr size_t WS_P0B   = WS_W01 + 1024;                    // 1024
constexpr size_t WS_P1B   = WS_P0B + 1024;                    // 1024

// Dsc lives in the (dead until kG2) GC region
constexpr size_t WS_DSC   = WS_GC;                            // G*N*5 f32

static __device__ __forceinline__ int swzf4(int row, int c4) {
  return row*32 + (((c4) ^ ((row >> 2) & 7)) << 2);
}

// ---------------------------------------------------------------------------
// kA: blocks [0,8G): Dsc[g][n][5] = x[n] @ Wdiff (quad-per-row, coalesced).
//     blk2 = blk-8G: 0: F0V; 1..32: W01 rows; 33: B01; 34/35: P0b/P1b.
// ---------------------------------------------------------------------------
__global__ __launch_bounds__(512, 4) void kA_pre(
    const float* __restrict__ x1, const float* __restrict__ x2,
    const float* __restrict__ Wsc,
    const float* __restrict__ F0w, const float* __restrict__ F2w,
    const float* __restrict__ H0w, const float* __restrict__ H2w,
    const float* __restrict__ Wm0b, const float* __restrict__ bm0b,
    const float* __restrict__ Wm1b, const float* __restrict__ bm1b,
    const float* __restrict__ Wg1, float* __restrict__ ws)
{
  __shared__ float SM[640];   // 2.56KB union
  int blk = blockIdx.x, t = threadIdx.x;

  if (blk < 8*G_) {
    // ---- Dsc: 8 blocks/graph, 4 threads/row, 64B-coalesced reads ----
    int g = blk >> 3, sub = blk & 7, br = g >> 6, b = g & 63;
    const float* xg = (br ? x2 : x1) + (size_t)b*N_*F_;
    float* WdL = SM;  // 640
    if (t < F_) {
      #pragma unroll
      for (int j = 0; j < 5; ++j) WdL[t*5+j] = Wsc[t*10+2*j+1] - Wsc[t*10+2*j];
    }
    __syncthreads();
    int row = sub*128 + (t >> 2), q = t & 3;
    const float4* xr = (const float4*)(xg + (size_t)row*F_);
    float acc[5] = {};
    #pragma unroll
    for (int i = 0; i < 8; ++i) {
      int k4 = q + 4*i;
      float4 v = xr[k4];
      const float* w = &WdL[k4*20];
      #pragma unroll
      for (int j = 0; j < 5; ++j)
        acc[j] += v.x*w[j] + v.y*w[5+j] + v.z*w[10+j] + v.w*w[15+j];
    }
    #pragma unroll
    for (int j = 0; j < 5; ++j) {
      acc[j] += __shfl_xor(acc[j], 1, 4);
      acc[j] += __shfl_xor(acc[j], 2, 4);
    }
    if (q == 0) {
      float* o = ws + WS_DSC + ((size_t)g*N_ + row)*5;
      #pragma unroll
      for (int j = 0; j < 5; ++j) o[j] = acc[j];
    }
    return;
  }

  int blk2 = blk - 8*G_;
  if (blk2 == 0) {
    // F0V
    float* h0mS = SM;
    if (t < 32) { float s = 0.f; for (int qq = 0; qq < 64; ++qq) s += H0w[qq*64+t]; h0mS[t] = s*(1.f/64.f); }
    __syncthreads();
    if (t < 2) { float s = 0.f; for (int p = 0; p < 32; ++p) s += F0w[p*2+t]*h0mS[p]; ws[WS_F0V+t] = s; }
  } else if (blk2 <= 32) {
    // W01 row kk: 512 thr = 32 cols x 16 k-segments of 64.
    int kk = blk2 - 1;
    int ol = t >> 4, seg = t & 15;
    const float4* ar = (const float4*)(Wm0b + (size_t)kk*1024 + seg*64);
    float s = 0.f;
    #pragma unroll
    for (int i = 0; i < 16; ++i) {
      float4 a = ar[i];
      int tt = seg*64 + i*4;
      s += a.x*Wg1[(tt+0)*32 + ol] + a.y*Wg1[(tt+1)*32 + ol]
         + a.z*Wg1[(tt+2)*32 + ol] + a.w*Wg1[(tt+3)*32 + ol];
    }
    s += __shfl_xor(s, 1, 16);
    s += __shfl_xor(s, 2, 16);
    s += __shfl_xor(s, 4, 16);
    s += __shfl_xor(s, 8, 16);
    if (seg == 0) ws[WS_W01 + kk*32 + ol] = s;
  } else if (blk2 == 33) {
    // B01: 32 cols x 16 segments of 64 + LDS reduce.
    float* red = SM;   // 512
    int j = t & 31, seg = t >> 5;
    float s = 0.f;
    #pragma unroll
    for (int i = 0; i < 64; ++i) {
      int k = seg*64 + i;
      s += bm0b[k]*Wg1[k*32 + j];
    }
    red[seg*32 + j] = s;
    __syncthreads();
    if (t < 32) {
      float a = 0.f;
      #pragma unroll
      for (int q = 0; q < 16; ++q) a += red[q*32 + t];
      ws[WS_B01 + t] = a;
    }
  } else {
    // P0b/c0b (34) and P1b/c1b (35)
    const float* Wb = (blk2 == 34) ? Wm0b : Wm1b;
    const float* bb = (blk2 == 34) ? bm0b : bm1b;
    size_t dstP = (blk2 == 34) ? WS_P0B : WS_P1B;
    size_t dstC = (blk2 == 34) ? WS_C0B : WS_C1B;
    float* h2mL = SM;        // 32
    float* f2vL = SM + 32;   // 32
    if (t < 32) { float s = 0.f; for (int r = 0; r < 32; ++r) s += H2w[r*32+t]; h2mL[t] = s*(1.f/32.f); }
    __syncthreads();
    if (t < 32) { float s = 0.f; for (int r = 0; r < 32; ++r) s += F2w[r*32+t]*h2mL[r]; f2vL[t] = s; }
    __syncthreads();
    if (t < 256) {
      #pragma unroll
      for (int q = 0; q < 4; ++q) {
        int e = t*4 + q;
        int k = e >> 5, c = e & 31;
        float s = 0.f;
        #pragma unroll
        for (int kp = 0; kp < 32; ++kp) s += Wb[k*1024 + c*32 + kp]*f2vL[kp];
        ws[dstP + e] = s;
      }
    }
    if (t < 32) {
      float s = 0.f;
      #pragma unroll
      for (int kp = 0; kp < 32; ++kp) s += bb[t*32+kp]*f2vL[kp];
      ws[dstC+t] = s;
    }
  }
}

// ---------------------------------------------------------------------------
// kPI: PI conv + relu reduced by g0v/g2v. Thread-per-(jp,kp).
// ---------------------------------------------------------------------------
__global__ __launch_bounds__(256, 4) void kPI(
    const float* __restrict__ PI1, const float* __restrict__ PI2,
    const float* __restrict__ Kc, const float* __restrict__ bc,
    const float* __restrict__ G0w, const float* __restrict__ G2w,
    const float* __restrict__ H0w, const float* __restrict__ H2w,
    float* __restrict__ ws)
{
  int g = blockIdx.x, br = g >> 6, b = g & 63;
  const float* pig = (br ? PI2 : PI1) + (size_t)b*CF_*P_*P_;
  __shared__ float PIt[CF_*P_*P_];   // 50KB
  __shared__ float KcL[H_*CF_*4];    // 2.5KB
  __shared__ float bcL[H_], g0L[H_], g2L[PO], h2L[H_], hhL[H_];
  __shared__ float scr[640];         // 625 partials
  int t = threadIdx.x;
  for (int i = t; i < CF_*P_*P_; i += 256) PIt[i] = pig[i];
  for (int i = t; i < H_*CF_*4; i += 256) KcL[i] = Kc[i];
  {
    int p = t >> 3, s = t & 7;
    float v = 0.f;
    #pragma unroll
    for (int q = 0; q < 8; ++q) v += H0w[(s + q*8)*64 + 32 + p];
    #pragma unroll
    for (int d = 4; d > 0; d >>= 1) v += __shfl_down(v, d, 8);
    if (s == 0) hhL[p] = v * (1.f/64.f);
  }
  {
    int r = t >> 3, s = t & 7;
    float v = 0.f;
    #pragma unroll
    for (int q = 0; q < 4; ++q) v += H2w[(s + q*8)*32 + r];
    #pragma unroll
    for (int d = 4; d > 0; d >>= 1) v += __shfl_down(v, d, 8);
    if (s == 0) h2L[r] = v * (1.f/32.f);
  }
  if (t < 32) bcL[t] = bc[t];
  __syncthreads();
  if (t < 32) { float s = 0.f; for (int p = 0; p < 32; ++p) s += G0w[p*32+t]*hhL[p]; g0L[t] = s; }
  if (t >= 64 && t < 64+PO) {
    int kp = t - 64;
    float s = 0.f;
    for (int r = 0; r < 32; ++r) s += G2w[r*25+kp]*h2L[r];
    g2L[kp] = s;
  }
  __syncthreads();
  for (int pos = t; pos < PO*PO; pos += 256) {
    int jp = pos / PO, kp = pos - jp*PO;
    float p00[CF_], p01[CF_], p10[CF_], p11[CF_];
    #pragma unroll
    for (int c = 0; c < CF_; ++c) {
      const float* q = &PIt[c*2500 + (2*jp)*50 + 2*kp];
      p00[c] = q[0]; p01[c] = q[1]; p10[c] = q[50]; p11[c] = q[51];
    }
    float acc = 0.f;
    for (int i = 0; i < H_; ++i) {
      float v = bcL[i];
      const float* kcp = &KcL[i*20];
      #pragma unroll
      for (int c = 0; c < CF_; ++c)
        v += p00[c]*kcp[c*4+0] + p01[c]*kcp[c*4+1] + p10[c]*kcp[c*4+2] + p11[c]*kcp[c*4+3];
      acc += fmaxf(v, 0.f) * g0L[i];
    }
    scr[pos] = acc * g2L[kp];
  }
  __syncthreads();
  if (t < PO) {
    float s = 0.f;
    #pragma unroll
    for (int k = 0; k < PO; ++k) s += scr[t*PO + k];
    ws[WS_PPI + (size_t)g*32 + t] = s;
  }
}

// ---------------------------------------------------------------------------
// kBS: per-graph single-pass edge load (registers) -> count -> scan ->
// scatter(LDS, from regs) -> score(LDS gather) -> radix top-512 -> compact
// -> coalesced packed CSR out (binary search).
// ---------------------------------------------------------------------------
__global__ __launch_bounds__(1024, 4) void kBS(
    const int* __restrict__ ei1, const int* __restrict__ ei2,
    const float* __restrict__ bsc, float* __restrict__ ws)
{
  int g = blockIdx.x, br = g >> 6, b = g & 63;
  const int* ei  = (br ? ei2 : ei1) + (size_t)b*2*E_;
  const int* src = ei;
  const int* dst = ei + E_;
  int* onodeg = (int*)ws + WS_ONODE + (size_t)g*K_;
  uint16_t* vdegg = (uint16_t*)(ws + WS_VDEG) + (size_t)g*K_;
  int* ceoffg = (int*)ws + WS_EOFF + (size_t)g*K_;
  float* dinvg = ws + WS_DINV + (size_t)g*K_;
  uint16_t* csrc = (uint16_t*)(ws + WS_SRCS) + (size_t)g*E_;

  __shared__ uint16_t srcL[E_];    // 64KB
  __shared__ float DscL[N_*5];     // 20KB
  __shared__ float dinvF[N_];      // 4KB
  __shared__ int fbL[N_];          // 4KB
  __shared__ int fillL[N_];        // 4KB
  __shared__ int nidxL[N_];        // 4KB
  __shared__ int seoffL[K_];       // 2KB
  __shared__ int vdegL[K_];        // 2KB
  __shared__ int ceoffL[K_];       // 2KB
  __shared__ int hist[256], hsum[256];
  __shared__ int wtot[16], wbase[16], wsum[16];
  __shared__ int remL, dstarL;

  int t = threadIdx.x;
  { const float* Dg = ws + WS_DSC + (size_t)g*N_*5;
    for (int i = t; i < N_*5; i += 1024) DscL[i] = Dg[i]; }
  fillL[t] = 0;
  if (t < 256) hist[t] = 0;
  if (t == 0) remL = K_;
  __syncthreads();

  // A: single global read of edges into registers + count
  uint32_t ep[32];
  #pragma unroll
  for (int i = 0; i < 32; ++i) {
    int e = t + i*1024;
    int s = src[e], d = dst[e];
    ep[i] = (uint32_t)s | ((uint32_t)d << 16);
    atomicAdd(&fillL[d], 1);
  }
  __syncthreads();

  // B: exclusive scan of counts
  int c = fillL[t];
  int lane = t & 63, w = t >> 6;
  int x = c;
  #pragma unroll
  for (int s = 1; s < 64; s <<= 1) {
    int v = __shfl_up(x, s);
    if (lane >= s) x += v;
  }
  if (lane == 63) wsum[w] = x;
  __syncthreads();
  if (w == 0 && lane < 16) {
    int y = wsum[lane];
    #pragma unroll
    for (int s = 1; s < 16; s <<= 1) {
      int v = __shfl_up(y, s, 16);
      if (lane >= s) y += v;
    }
    wsum[lane] = y;
  }
  __syncthreads();
  int off0 = ((w == 0) ? 0 : wsum[w-1]) + x - c;
  int off1 = off0 + c;
  fbL[t] = off0;
  dinvF[t] = rsqrtf((float)c + 1.0f);
  fillL[t] = 0;
  __syncthreads();

  // C: scatter into LDS from registers
  #pragma unroll
  for (int i = 0; i < 32; ++i) {
    int d = (int)(ep[i] >> 16), s = (int)(ep[i] & 0xffffu);
    int pos = fbL[d] + atomicAdd(&fillL[d], 1);
    srcL[pos] = (uint16_t)s;
  }
  __syncthreads();

  // D: score gather from LDS
  uint32_t key;
  {
    float agg[5] = {};
    for (int e = off0; e < off1; ++e) {
      int s = srcL[e];
      float dvs = dinvF[s];
      const float* hr = &DscL[s*5];
      #pragma unroll
      for (int j = 0; j < 5; ++j) agg[j] += hr[j]*dvs;
    }
    float dv = dinvF[t];
    const float* hn = &DscL[t*5];
    float sc = 0.f;
    #pragma unroll
    for (int j = 0; j < 5; ++j)
      sc += fabsf(dv*(agg[j] + dv*hn[j]) + (bsc[2*j+1] - bsc[2*j]));
    key = __float_as_uint(sc);   // sc >= 0 -> uint order == float order
  }
  __syncthreads();

  // E: 4-pass radix select; wave0 does the 256-bin suffix scan via shfl.
  uint32_t pref = 0, prefMask = 0;
  #pragma unroll
  for (int pass = 0; pass < 4; ++pass) {
    int shift = 24 - 8*pass;
    bool cand = (key & prefMask) == pref;
    if (cand) atomicAdd(&hist[(key >> shift) & 255], 1);
    __syncthreads();                          // B1: hist complete
    if (w == 0) {
      int base = lane*4;
      int h0 = hist[base+0], h1 = hist[base+1], h2 = hist[base+2], h3 = hist[base+3];
      int suf = h0 + h1 + h2 + h3;
      #pragma unroll
      for (int sh = 1; sh < 64; sh <<= 1) {
        int v = __shfl_down(suf, sh);
        if (lane + sh < 64) suf += v;
      }
      hsum[base+0] = suf;
      hsum[base+1] = suf - h0;
      hsum[base+2] = suf - h0 - h1;
      hsum[base+3] = suf - h0 - h1 - h2;
    }
    __syncthreads();                          // B2: hsum visible
    int rem = remL;
    if (t < 256) {
      int above = (t == 255) ? 0 : hsum[t+1];
      if (hsum[t] >= rem && above < rem) dstarL = t;
      hist[t] = 0;                            // zero for next pass
    }
    __syncthreads();                          // B3: dstar + zero done
    int ds = dstarL;
    if (t == 0) remL = rem - ((ds == 255) ? 0 : hsum[ds+1]);
    pref |= (uint32_t)ds << shift;
    prefMask |= 0xFFu << shift;
  }
  __syncthreads();
  uint32_t T = pref;
  int r = remL;

  // ties (key == T) rank by idx asc; select key>T plus first r ties
  bool eq = (key == T);
  uint64_t mEq = __ballot(eq);
  int lpEq = (int)__popcll(mEq & ((1ull << lane) - 1));
  if (lane == 0) wtot[w] = (int)__popcll(mEq);
  __syncthreads();
  if (t == 0) { int a = 0; for (int q = 0; q < 16; ++q) { wbase[q] = a; a += wtot[q]; } }
  __syncthreads();
  bool sel = (key > T) || (eq && (wbase[w] + lpEq) < r);
  __syncthreads();
  uint64_t mS = __ballot(sel);
  int lpS = (int)__popcll(mS & ((1ull << lane) - 1));
  if (lane == 0) wtot[w] = (int)__popcll(mS);
  __syncthreads();
  if (t == 0) { int a = 0; for (int q = 0; q < 16; ++q) { wbase[q] = a; a += wtot[q]; } }
  __syncthreads();
  int rank = wbase[w] + lpS;
  nidxL[t] = sel ? rank : -1;
  if (sel) onodeg[rank] = t;
  __syncthreads();

  // F: compact own segment in place (remap to ranks)
  if (sel) {
    int c2 = 0;
    for (int e = off0; e < off1; ++e) {
      int m = nidxL[srcL[e]];
      if (m >= 0) srcL[off0 + (c2++)] = (uint16_t)m;
    }
    vdegL[rank] = c2;
    seoffL[rank] = off0;
  }
  __syncthreads();

  // G: scan vdeg over 512 ranks -> packed offsets
  int vv = 0, xx = 0, w2 = t >> 6;
  if (t < K_) {
    vv = vdegL[t]; xx = vv;
    int l2 = t & 63;
    #pragma unroll
    for (int s = 1; s < 64; s <<= 1) {
      int v = __shfl_up(xx, s);
      if (l2 >= s) xx += v;
    }
    if (l2 == 63) wsum[w2] = xx;
  }
  __syncthreads();
  if (t == 0) { int run = 0; for (int q = 0; q < 8; ++q) { int tm = wsum[q]; wsum[q] = run; run += tm; } }
  __syncthreads();
  if (t < K_) {
    int ce = wsum[w2] + xx - vv;
    ceoffL[t] = ce;
    ceoffg[t] = ce;
    vdegg[t] = (uint16_t)vv;
    dinvg[t] = rsqrtf((float)vv + 1.0f);
  }
  __syncthreads();

  // H: coalesced packed edge-list write; owning rank via binary search
  // (containing segment = largest r with ceoffL[r] <= p).
  int tot = ceoffL[K_-1] + vdegL[K_-1];
  for (int p = t; p < tot; p += 1024) {
    int lo2 = 0, hi2 = K_ - 1;
    while (lo2 < hi2) {
      int mid = (lo2 + hi2 + 1) >> 1;
      if (ceoffL[mid] <= p) lo2 = mid; else hi2 = mid - 1;
    }
    csrc[p] = srcL[seoffL[lo2] + (p - ceoffL[lo2])];
  }
}

// ---------------------------------------------------------------------------
// 256x32 @ 32x32 matmul core on swizzled LDS; W padded [32][36].
// ---------------------------------------------------------------------------
static __device__ __forceinline__ void mmA(
    const float* __restrict__ S, const float* __restrict__ Wp,
    float (&acc)[4][4], int it, int jt)
{
  const int i0 = it*4, swa = it & 7;
  #pragma unroll
  for (int kv = 0; kv < 8; ++kv) {
    float4 w0 = *(const float4*)&Wp[(kv*4+0)*36 + jt*4];
    float4 w1 = *(const float4*)&Wp[(kv*4+1)*36 + jt*4];
    float4 w2 = *(const float4*)&Wp[(kv*4+2)*36 + jt*4];
    float4 w3 = *(const float4*)&Wp[(kv*4+3)*36 + jt*4];
    #pragma unroll
    for (int d = 0; d < 4; ++d) {
      float4 a = *(const float4*)&S[(i0+d)*32 + ((kv ^ swa) << 2)];
      acc[d][0] += a.x*w0.x + a.y*w1.x + a.z*w2.x + a.w*w3.x;
      acc[d][1] += a.x*w0.y + a.y*w1.y + a.z*w2.y + a.w*w3.y;
      acc[d][2] += a.x*w0.z + a.y*w1.z + a.z*w2.z + a.w*w3.z;
      acc[d][3] += a.x*w0.w + a.y*w1.w + a.z*w2.w + a.w*w3.w;
    }
  }
}

// ---------------------------------------------------------------------------
// kG1: gA[g][dd] = dinv[dd] * (x[onode[dd]] @ Wg0).  grid (G,2) x 512.
// ---------------------------------------------------------------------------
__global__ __launch_bounds__(512, 4) void kG1(
    const float* __restrict__ x1, const float* __restrict__ x2,
    const float* __restrict__ Wg0, float* __restrict__ ws)
{
  int g = blockIdx.x, half = blockIdx.y, br = g >> 6, b = g & 63;
  const float* xg = (br ? x2 : x1) + (size_t)b*N_*F_;
  const int* onodeg = (const int*)ws + WS_ONODE + (size_t)g*K_ + half*256;
  const float* dinvg = ws + WS_DINV + (size_t)g*K_ + half*256;
  float* gAg = ws + WS_GA + (size_t)g*K_*H_ + (size_t)half*256*H_;

  __shared__ float wbuf[F_*36];
  __shared__ int   onodeL[256];
  __shared__ float dinvL[256];

  int t = threadIdx.x;
  for (int i = t; i < F_*H_; i += 512) wbuf[(i >> 5)*36 + (i & 31)] = Wg0[i];
  if (t < 256) { onodeL[t] = onodeg[t]; dinvL[t] = dinvg[t]; }
  __syncthreads();

  const int it = t >> 3, jt = t & 7;
  const int i0 = it*4;
  const float* xr0 = xg + (size_t)onodeL[i0+0]*F_;
  const float* xr1 = xg + (size_t)onodeL[i0+1]*F_;
  const float* xr2 = xg + (size_t)onodeL[i0+2]*F_;
  const float* xr3 = xg + (size_t)onodeL[i0+3]*F_;
  float acc[4][4] = {};
  for (int k4 = 0; k4 < 32; ++k4) {
    float4 w0 = *(const float4*)&wbuf[(k4*4+0)*36 + jt*4];
    float4 w1 = *(const float4*)&wbuf[(k4*4+1)*36 + jt*4];
    float4 w2 = *(const float4*)&wbuf[(k4*4+2)*36 + jt*4];
    float4 w3 = *(const float4*)&wbuf[(k4*4+3)*36 + jt*4];
    float4 a;
    a = *(const float4*)(xr0 + k4*4);
    acc[0][0]+=a.x*w0.x+a.y*w1.x+a.z*w2.x+a.w*w3.x; acc[0][1]+=a.x*w0.y+a.y*w1.y+a.z*w2.y+a.w*w3.y;
    acc[0][2]+=a.x*w0.z+a.y*w1.z+a.z*w2.z+a.w*w3.z; acc[0][3]+=a.x*w0.w+a.y*w1.w+a.z*w2.w+a.w*w3.w;
    a = *(const float4*)(xr1 + k4*4);
    acc[1][0]+=a.x*w0.x+a.y*w1.x+a.z*w2.x+a.w*w3.x; acc[1][1]+=a.x*w0.y+a.y*w1.y+a.z*w2.y+a.w*w3.y;
    acc[1][2]+=a.x*w0.z+a.y*w1.z+a.z*w2.z+a.w*w3.z; acc[1][3]+=a.x*w0.w+a.y*w1.w+a.z*w2.w+a.w*w3.w;
    a = *(const float4*)(xr2 + k4*4);
    acc[2][0]+=a.x*w0.x+a.y*w1.x+a.z*w2.x+a.w*w3.x; acc[2][1]+=a.x*w0.y+a.y*w1.y+a.z*w2.y+a.w*w3.y;
    acc[2][2]+=a.x*w0.z+a.y*w1.z+a.z*w2.z+a.w*w3.z; acc[2][3]+=a.x*w0.w+a.y*w1.w+a.z*w2.w+a.w*w3.w;
    a = *(const float4*)(xr3 + k4*4);
    acc[3][0]+=a.x*w0.x+a.y*w1.x+a.z*w2.x+a.w*w3.x; acc[3][1]+=a.x*w0.y+a.y*w1.y+a.z*w2.y+a.w*w3.y;
    acc[3][2]+=a.x*w0.z+a.y*w1.z+a.z*w2.z+a.w*w3.z; acc[3][3]+=a.x*w0.w+a.y*w1.w+a.z*w2.w+a.w*w3.w;
  }
  #pragma unroll
  for (int d = 0; d < 4; ++d) {
    int row = i0 + d;
    float rs = dinvL[row];
    float4 o; o.x=acc[d][0]*rs; o.y=acc[d][1]*rs; o.z=acc[d][2]*rs; o.w=acc[d][3]*rs;
    *(float4*)&gAg[row*32 + jt*4] = o;
  }
}

// ---------------------------------------------------------------------------
// conv gather (packed CSR) from global feature buffer into swizzled LDS.
// ---------------------------------------------------------------------------
static __device__ __forceinline__ void convG(
    const float* __restrict__ gS, float* __restrict__ cbuf,
    const float* __restrict__ bias, const float* __restrict__ dinvL,
    const int* __restrict__ eoffL, const int* __restrict__ vcntL,
    const uint16_t* __restrict__ srcS, int half, int t)
{
  int ddl = t & 255, hc = t >> 8;
  int dd = half*256 + ddl;
  int lo = eoffL[ddl], n = vcntL[ddl];
  int c0 = hc*16;
  float4 a0 = {0,0,0,0}, a1 = a0, a2 = a0, a3 = a0;
  for (int i = 0; i < n; ++i) {
    int ss = srcS[lo + i];
    const float* r = gS + ss*32 + c0;
    float4 v;
    v = *(const float4*)(r+0);  a0.x+=v.x; a0.y+=v.y; a0.z+=v.z; a0.w+=v.w;
    v = *(const float4*)(r+4);  a1.x+=v.x; a1.y+=v.y; a1.z+=v.z; a1.w+=v.w;
    v = *(const float4*)(r+8);  a2.x+=v.x; a2.y+=v.y; a2.z+=v.z; a2.w+=v.w;
    v = *(const float4*)(r+12); a3.x+=v.x; a3.y+=v.y; a3.z+=v.z; a3.w+=v.w;
  }
  { const float* r = gS + dd*32 + c0;
    float4 v;
    v = *(const float4*)(r+0);  a0.x+=v.x; a0.y+=v.y; a0.z+=v.z; a0.w+=v.w;
    v = *(const float4*)(r+4);  a1.x+=v.x; a1.y+=v.y; a1.z+=v.z; a1.w+=v.w;
    v = *(const float4*)(r+8);  a2.x+=v.x; a2.y+=v.y; a2.z+=v.z; a2.w+=v.w;
    v = *(const float4*)(r+12); a3.x+=v.x; a3.y+=v.y; a3.z+=v.z; a3.w+=v.w; }
  float dvd = dinvL[ddl];
  float4 r0, r1, r2, r3;
  r0.x = dvd*a0.x + bias[c0+0];  r0.y = dvd*a0.y + bias[c0+1];
  r0.z = dvd*a0.z + bias[c0+2];  r0.w = dvd*a0.w + bias[c0+3];
  r1.x = dvd*a1.x + bias[c0+4];  r1.y = dvd*a1.y + bias[c0+5];
  r1.z = dvd*a1.z + bias[c0+6];  r1.w = dvd*a1.w + bias[c0+7];
  r2.x = dvd*a2.x + bias[c0+8];  r2.y = dvd*a2.y + bias[c0+9];
  r2.z = dvd*a2.z + bias[c0+10]; r2.w = dvd*a2.w + bias[c0+11];
  r3.x = dvd*a3.x + bias[c0+12]; r3.y = dvd*a3.y + bias[c0+13];
  r3.z = dvd*a3.z + bias[c0+14]; r3.w = dvd*a3.w + bias[c0+15];
  int g4 = hc*4;
  *(float4*)&cbuf[swzf4(ddl, g4+0)] = r0;
  *(float4*)&cbuf[swzf4(ddl, g4+1)] = r1;
  *(float4*)&cbuf[swzf4(ddl, g4+2)] = r2;
  *(float4*)&cbuf[swzf4(ddl, g4+3)] = r3;
}

// ---------------------------------------------------------------------------
// kG2: conv0 -> r0=relu(.@Wm0a+b) -> {column partials, gC=(r0@W01+b01)*dinv}
// ---------------------------------------------------------------------------
__global__ __launch_bounds__(512, 4) void kG2(
    const float* __restrict__ bg0,
    const float* __restrict__ Wm0a, const float* __restrict__ bm0a,
    float* __restrict__ ws)
{
  int g = blockIdx.x, half = blockIdx.y;
  const float* gAg = ws + WS_GA + (size_t)g*K_*H_;
  float* gCg = ws + WS_GC + (size_t)g*K_*H_;
  const uint16_t* srcS = (const uint16_t*)(ws + WS_SRCS) + (size_t)g*E_;
  const int* eoffg = (const int*)ws + WS_EOFF + (size_t)g*K_ + half*256;
  const uint16_t* vdegg = (const uint16_t*)(ws + WS_VDEG) + (size_t)g*K_ + half*256;
  const float* dinvg = ws + WS_DINV + (size_t)g*K_ + half*256;

  __shared__ float cbufA[256*32];
  __shared__ float cbufB[256*32];
  __shared__ float wA[32*36];
  __shared__ float wB[32*36];
  __shared__ float scrP[64*33];
  __shared__ int   eoffL[256];
  __shared__ int   vcntL[256];
  __shared__ float dinvL[256];

  int t = threadIdx.x;
  for (int i = t; i < 1024; i += 512) {
    int k = i >> 5, j = i & 31;
    wA[k*36+j] = Wm0a[i];
    wB[k*36+j] = ws[WS_W01 + i];
  }
  if (t < 256) { eoffL[t] = eoffg[t]; vcntL[t] = vdegg[t]; dinvL[t] = dinvg[t]; }
  __syncthreads();

  convG(gAg, cbufA, bg0, dinvL, eoffL, vcntL, srcS, half, t);
  __syncthreads();

  const int it = t >> 3, jt = t & 7;
  float acc[4][4] = {};
  mmA(cbufA, wA, acc, it, jt);
  {
    float b0 = bm0a[jt*4+0], b1 = bm0a[jt*4+1], b2 = bm0a[jt*4+2], b3 = bm0a[jt*4+3];
    float cp0=0.f, cp1=0.f, cp2=0.f, cp3=0.f;
    #pragma unroll
    for (int d = 0; d < 4; ++d) {
      float v0=fmaxf(acc[d][0]+b0,0.f), v1=fmaxf(acc[d][1]+b1,0.f);
      float v2=fmaxf(acc[d][2]+b2,0.f), v3=fmaxf(acc[d][3]+b3,0.f);
      cp0+=v0; cp1+=v1; cp2+=v2; cp3+=v3;
      float4 o; o.x=v0; o.y=v1; o.z=v2; o.w=v3;
      *(float4*)&cbufB[swzf4(it*4+d, jt)] = o;
    }
    scrP[it*33 + jt*4+0] = cp0; scrP[it*33 + jt*4+1] = cp1;
    scrP[it*33 + jt*4+2] = cp2; scrP[it*33 + jt*4+3] = cp3;
  }
  __syncthreads();

  if (t < 32) {
    float s = 0.f;
    #pragma unroll
    for (int q = 0; q < 64; ++q) s += scrP[q*33 + t];
    ws[WS_PM0 + (size_t)g*64 + half*32 + t] = s;
  }

  float acc2[4][4] = {};
  mmA(cbufB, wB, acc2, it, jt);
  {
    float b0 = ws[WS_B01+jt*4+0], b1 = ws[WS_B01+jt*4+1];
    float b2 = ws[WS_B01+jt*4+2], b3 = ws[WS_B01+jt*4+3];
    #pragma unroll
    for (int d = 0; d < 4; ++d) {
      int row = it*4 + d;
      float rs = dinvL[row];
      float4 o;
      o.x=(acc2[d][0]+b0)*rs; o.y=(acc2[d][1]+b1)*rs;
      o.z=(acc2[d][2]+b2)*rs; o.w=(acc2[d][3]+b3)*rs;
      *(float4*)&gCg[(half*256+row)*32 + jt*4] = o;
    }
  }
}

// ---------------------------------------------------------------------------
// kG4: conv1 -> r1=relu(.@Wm1a+b) -> column partials.
// ---------------------------------------------------------------------------
__global__ __launch_bounds__(512, 4) void kG4(
    const float* __restrict__ bg1,
    const float* __restrict__ Wm1a, const float* __restrict__ bm1a,
    float* __restrict__ ws)
{
  int g = blockIdx.x, half = blockIdx.y;
  const float* gCg = ws + WS_GC + (size_t)g*K_*H_;
  const uint16_t* srcS = (const uint16_t*)(ws + WS_SRCS) + (size_t)g*E_;
  const int* eoffg = (const int*)ws + WS_EOFF + (size_t)g*K_ + half*256;
  const uint16_t* vdegg = (const uint16_t*)(ws + WS_VDEG) + (size_t)g*K_ + half*256;
  const float* dinvg = ws + WS_DINV + (size_t)g*K_ + half*256;

  __shared__ float cbufA[256*32];
  __shared__ float wA[32*36];
  __shared__ float scrP[64*33];
  __shared__ int   eoffL[256];
  __shared__ int   vcntL[256];
  __shared__ float dinvL[256];

  int t = threadIdx.x;
  for (int i = t; i < 1024; i += 512) wA[(i>>5)*36 + (i&31)] = Wm1a[i];
  if (t < 256) { eoffL[t] = eoffg[t]; vcntL[t] = vdegg[t]; dinvL[t] = dinvg[t]; }
  __syncthreads();

  convG(gCg, cbufA, bg1, dinvL, eoffL, vcntL, srcS, half, t);
  __syncthreads();

  const int it = t >> 3, jt = t & 7;
  float acc[4][4] = {};
  mmA(cbufA, wA, acc, it, jt);
  {
    float b0 = bm1a[jt*4+0], b1 = bm1a[jt*4+1], b2 = bm1a[jt*4+2], b3 = bm1a[jt*4+3];
    float cp0=0.f, cp1=0.f, cp2=0.f, cp3=0.f;
    #pragma unroll
    for (int d = 0; d < 4; ++d) {
      cp0 += fmaxf(acc[d][0]+b0,0.f); cp1 += fmaxf(acc[d][1]+b1,0.f);
      cp2 += fmaxf(acc[d][2]+b2,0.f); cp3 += fmaxf(acc[d][3]+b3,0.f);
    }
    scrP[it*33 + jt*4+0] = cp0; scrP[it*33 + jt*4+1] = cp1;
    scrP[it*33 + jt*4+2] = cp2; scrP[it*33 + jt*4+3] = cp3;
  }
  __syncthreads();

  if (t < 32) {
    float s = 0.f;
    #pragma unroll
    for (int q = 0; q < 64; ++q) s += scrP[q*33 + t];
    ws[WS_PM1 + (size_t)g*64 + half*32 + t] = s;
  }
}

// ---------------------------------------------------------------------------
// k5: per-graph tail via folded P0b/P1b. grid G x 64.
// ---------------------------------------------------------------------------
__global__ __launch_bounds__(64) void k5_final(
    const float* __restrict__ F1w, const float* __restrict__ G1w,
    const float* __restrict__ H1w, const float* __restrict__ Wo1,
    const float* __restrict__ bo1, const float* __restrict__ Wo2,
    const float* __restrict__ bo2, const float* __restrict__ ws,
    float* __restrict__ out)
{
  int g = blockIdx.x, t = threadIdx.x;
  __shared__ float mr0[32], mr1[32], AL[32], TL[32], pl[32], zl[32], ppiL[PO];
  if (t < 32) {
    mr0[t] = (ws[WS_PM0 + (size_t)g*64 + t] + ws[WS_PM0 + (size_t)g*64 + 32 + t]) * (1.f/512.f);
    mr1[t] = (ws[WS_PM1 + (size_t)g*64 + t] + ws[WS_PM1 + (size_t)g*64 + 32 + t]) * (1.f/512.f);
  }
  if (t >= 32 && t < 32+PO) ppiL[t-32] = ws[WS_PPI + (size_t)g*32 + (t-32)];
  __syncthreads();
  float f00 = ws[WS_F0V], f01 = ws[WS_F0V+1];
  if (t < 32) {
    float s0 = ws[WS_C0B + t], s1 = ws[WS_C1B + t];
    for (int k = 0; k < 32; ++k) {
      s0 += mr0[k]*ws[WS_P0B + k*32 + t];
      s1 += mr1[k]*ws[WS_P1B + k*32 + t];
    }
    AL[t] = f00*s0 + f01*s1;
  }
  __syncthreads();
  if (t < 32) {
    float s = 0.f;
    for (int jp = 0; jp < 32; ++jp) s += F1w[t*32+jp]*AL[jp];
    for (int jp = 0; jp < PO; ++jp) s += G1w[t*25+jp]*ppiL[jp];
    TL[t] = s;
  }
  __syncthreads();
  if (t < 32) {
    float s = 0.f;
    for (int j = 0; j < 32; ++j) s += H1w[t*32+j]*TL[j];
    pl[t] = s;
  }
  __syncthreads();
  if (t < 32) {
    float s = bo1[t];
    for (int j = 0; j < 32; ++j) s += pl[j]*Wo1[j*32+t];
    zl[t] = fmaxf(s, 0.f);
  }
  __syncthreads();
  if (t < 2) {
    float s = bo2[t];
    for (int q = 0; q < 32; ++q) s += zl[q]*Wo2[q*2+t];
    int br = g >> 6, b = g & 63;
    out[br*(B_*2) + b*2 + t] = s;
  }
}

// ---------------------------------------------------------------------------
extern "C" void kernel_launch(void* const* d_in, const int* in_sizes, int n_in,
                              void* d_out, int out_size, void* d_ws, size_t ws_size,
                              hipStream_t stream) {
  (void)in_sizes; (void)n_in; (void)out_size; (void)ws_size;
  const float* x1      = (const float*)d_in[0];
  const int*   ei1     = (const int*)  d_in[1];
  const float* PI1     = (const float*)d_in[2];
  const float* x2      = (const float*)d_in[3];
  const int*   ei2     = (const int*)  d_in[4];
  const float* PI2     = (const float*)d_in[5];
  const float* W_score = (const float*)d_in[6];
  const float* b_score = (const float*)d_in[7];
  const float* W_gcn0  = (const float*)d_in[8];
  const float* b_gcn0  = (const float*)d_in[9];
  const float* Wm0a    = (const float*)d_in[10];
  const float* bm0a    = (const float*)d_in[11];
  const float* Wm0b    = (const float*)d_in[12];
  const float* bm0b    = (const float*)d_in[13];
  const float* W_gcn1  = (const float*)d_in[14];
  const float* b_gcn1  = (const float*)d_in[15];
  const float* Wm1a    = (const float*)d_in[16];
  const float* bm1a    = (const float*)d_in[17];
  const float* Wm1b    = (const float*)d_in[18];
  const float* bm1b    = (const float*)d_in[19];
  const float* F0w     = (const float*)d_in[20];
  const float* F1w     = (const float*)d_in[21];
  const float* F2w     = (const float*)d_in[22];
  const float* Kc      = (const float*)d_in[23];
  const float* bc      = (const float*)d_in[24];
  const float* G0w     = (const float*)d_in[25];
  const float* G1w     = (const float*)d_in[26];
  const float* G2w     = (const float*)d_in[27];
  const float* H0w     = (const float*)d_in[28];
  const float* H1w     = (const float*)d_in[29];
  const float* H2w     = (const float*)d_in[30];
  const float* Wo1     = (const float*)d_in[31];
  const float* bo1     = (const float*)d_in[32];
  const float* Wo2     = (const float*)d_in[33];
  const float* bo2     = (const float*)d_in[34];
  float* ws  = (float*)d_ws;
  float* out = (float*)d_out;

  kA_pre<<<8*G_ + 36, 512, 0, stream>>>(x1, x2, W_score,
                                        F0w, F2w, H0w, H2w,
                                        Wm0b, bm0b, Wm1b, bm1b, W_gcn1, ws);
  kPI<<<G_, 256, 0, stream>>>(PI1, PI2, Kc, bc, G0w, G2w, H0w, H2w, ws);
  kBS<<<G_, 1024, 0, stream>>>(ei1, ei2, b_score, ws);
  kG1<<<dim3(G_, 2), 512, 0, stream>>>(x1, x2, W_gcn0, ws);
  kG2<<<dim3(G_, 2), 512, 0, stream>>>(b_gcn0, Wm0a, bm0a, ws);
  kG4<<<dim3(G_, 2), 512, 0, stream>>>(b_gcn1, Wm1a, bm1a, ws);
  k5_final<<<G_, 64, 0, stream>>>(F1w, G1w, H1w, Wo1, bo1, Wo2, bo2, ws, out);
}

// Round 14
// 154.768 us; speedup vs baseline: 1.4223x; 1.0948x over previous
//
#include <hip/hip_runtime.h>
#include <cstdint>

// ---------------------------------------------------------------------------
// TenGCN fused forward. 128 graphs (2 branches x 64 batches).
// R14: kPI merged into kBS's grid (blocks [G,2G) -- fills the 128 idle CUs);
// kBS scatter de-atomized via slot capture in the count pass
// (src:10|dst:10|slot:12 packed edge registers).
// 6 launches: kA (Dsc+setup) -> kBSP (BS+PI) -> kG1 -> kG2 -> kG4 -> k5.
// ---------------------------------------------------------------------------

constexpr int B_ = 64, N_ = 1024, E_ = 32768, F_ = 128, H_ = 32;
constexpr int CF_ = 5, P_ = 50, K_ = 512, G_ = 128, PO = 25;

// workspace offsets (4-byte units)
constexpr size_t WS_SRCS  = 0;                                // G*E u16 (packed)
constexpr size_t WS_ONODE = WS_SRCS + (size_t)G_*(E_/2);      // G*512 int
constexpr size_t WS_VDEG  = WS_ONODE + (size_t)G_*K_;         // G*512 u16
constexpr size_t WS_EOFF  = WS_VDEG + (size_t)G_*(K_/2);      // G*512 int (packed ceoff)
constexpr size_t WS_DINV  = WS_EOFF + (size_t)G_*K_;          // G*512 f32 (valid dinv)
constexpr size_t WS_GA    = WS_DINV + (size_t)G_*K_;          // G*512*32 f32
constexpr size_t WS_GC    = WS_GA + (size_t)G_*K_*H_;         // G*512*32 f32
constexpr size_t WS_PM0   = WS_GC + (size_t)G_*K_*H_;         // G*2*32
constexpr size_t WS_PM1   = WS_PM0 + (size_t)G_*64;           // G*2*32
constexpr size_t WS_PPI   = WS_PM1 + (size_t)G_*64;           // G*32
constexpr size_t WS_F0V   = WS_PPI + (size_t)G_*32;           // 2 (pad 32)
constexpr size_t WS_B01   = WS_F0V + 32;                      // 32
constexpr size_t WS_C0B   = WS_B01 + 32;                      // 32
constexpr size_t WS_C1B   = WS_C0B + 32;                      // 32
constexpr size_t WS_W01   = WS_C1B + 32;                      // 1024
constexpr size_t WS_P0B   = WS_W01 + 1024;                    // 1024
constexpr size_t WS_P1B   = WS_P0B + 1024;                    // 1024

// Dsc lives in the (dead until kG2) GC region
constexpr size_t WS_DSC   = WS_GC;                            // G*N*5 f32

static __device__ __forceinline__ int swzf4(int row, int c4) {
  return row*32 + (((c4) ^ ((row >> 2) & 7)) << 2);
}

// ---------------------------------------------------------------------------
// kA: blocks [0,8G): Dsc[g][n][5] = x[n] @ Wdiff (quad-per-row, coalesced).
//     blk2 = blk-8G: 0: F0V; 1..32: W01 rows; 33: B01; 34/35: P0b/P1b.
// ---------------------------------------------------------------------------
__global__ __launch_bounds__(512, 4) void kA_pre(
    const float* __restrict__ x1, const float* __restrict__ x2,
    const float* __restrict__ Wsc,
    const float* __restrict__ F0w, const float* __restrict__ F2w,
    const float* __restrict__ H0w, const float* __restrict__ H2w,
    const float* __restrict__ Wm0b, const float* __restrict__ bm0b,
    const float* __restrict__ Wm1b, const float* __restrict__ bm1b,
    const float* __restrict__ Wg1, float* __restrict__ ws)
{
  __shared__ float SM[640];   // 2.56KB union
  int blk = blockIdx.x, t = threadIdx.x;

  if (blk < 8*G_) {
    // ---- Dsc: 8 blocks/graph, 4 threads/row, 64B-coalesced reads ----
    int g = blk >> 3, sub = blk & 7, br = g >> 6, b = g & 63;
    const float* xg = (br ? x2 : x1) + (size_t)b*N_*F_;
    float* WdL = SM;  // 640
    if (t < F_) {
      #pragma unroll
      for (int j = 0; j < 5; ++j) WdL[t*5+j] = Wsc[t*10+2*j+1] - Wsc[t*10+2*j];
    }
    __syncthreads();
    int row = sub*128 + (t >> 2), q = t & 3;
    const float4* xr = (const float4*)(xg + (size_t)row*F_);
    float acc[5] = {};
    #pragma unroll
    for (int i = 0; i < 8; ++i) {
      int k4 = q + 4*i;
      float4 v = xr[k4];
      const float* w = &WdL[k4*20];
      #pragma unroll
      for (int j = 0; j < 5; ++j)
        acc[j] += v.x*w[j] + v.y*w[5+j] + v.z*w[10+j] + v.w*w[15+j];
    }
    #pragma unroll
    for (int j = 0; j < 5; ++j) {
      acc[j] += __shfl_xor(acc[j], 1, 4);
      acc[j] += __shfl_xor(acc[j], 2, 4);
    }
    if (q == 0) {
      float* o = ws + WS_DSC + ((size_t)g*N_ + row)*5;
      #pragma unroll
      for (int j = 0; j < 5; ++j) o[j] = acc[j];
    }
    return;
  }

  int blk2 = blk - 8*G_;
  if (blk2 == 0) {
    // F0V
    float* h0mS = SM;
    if (t < 32) { float s = 0.f; for (int qq = 0; qq < 64; ++qq) s += H0w[qq*64+t]; h0mS[t] = s*(1.f/64.f); }
    __syncthreads();
    if (t < 2) { float s = 0.f; for (int p = 0; p < 32; ++p) s += F0w[p*2+t]*h0mS[p]; ws[WS_F0V+t] = s; }
  } else if (blk2 <= 32) {
    // W01 row kk: 512 thr = 32 cols x 16 k-segments of 64.
    int kk = blk2 - 1;
    int ol = t >> 4, seg = t & 15;
    const float4* ar = (const float4*)(Wm0b + (size_t)kk*1024 + seg*64);
    float s = 0.f;
    #pragma unroll
    for (int i = 0; i < 16; ++i) {
      float4 a = ar[i];
      int tt = seg*64 + i*4;
      s += a.x*Wg1[(tt+0)*32 + ol] + a.y*Wg1[(tt+1)*32 + ol]
         + a.z*Wg1[(tt+2)*32 + ol] + a.w*Wg1[(tt+3)*32 + ol];
    }
    s += __shfl_xor(s, 1, 16);
    s += __shfl_xor(s, 2, 16);
    s += __shfl_xor(s, 4, 16);
    s += __shfl_xor(s, 8, 16);
    if (seg == 0) ws[WS_W01 + kk*32 + ol] = s;
  } else if (blk2 == 33) {
    // B01: 32 cols x 16 segments of 64 + LDS reduce.
    float* red = SM;   // 512
    int j = t & 31, seg = t >> 5;
    float s = 0.f;
    #pragma unroll
    for (int i = 0; i < 64; ++i) {
      int k = seg*64 + i;
      s += bm0b[k]*Wg1[k*32 + j];
    }
    red[seg*32 + j] = s;
    __syncthreads();
    if (t < 32) {
      float a = 0.f;
      #pragma unroll
      for (int q = 0; q < 16; ++q) a += red[q*32 + t];
      ws[WS_B01 + t] = a;
    }
  } else {
    // P0b/c0b (34) and P1b/c1b (35)
    const float* Wb = (blk2 == 34) ? Wm0b : Wm1b;
    const float* bb = (blk2 == 34) ? bm0b : bm1b;
    size_t dstP = (blk2 == 34) ? WS_P0B : WS_P1B;
    size_t dstC = (blk2 == 34) ? WS_C0B : WS_C1B;
    float* h2mL = SM;        // 32
    float* f2vL = SM + 32;   // 32
    if (t < 32) { float s = 0.f; for (int r = 0; r < 32; ++r) s += H2w[r*32+t]; h2mL[t] = s*(1.f/32.f); }
    __syncthreads();
    if (t < 32) { float s = 0.f; for (int r = 0; r < 32; ++r) s += F2w[r*32+t]*h2mL[r]; f2vL[t] = s; }
    __syncthreads();
    if (t < 256) {
      #pragma unroll
      for (int q = 0; q < 4; ++q) {
        int e = t*4 + q;
        int k = e >> 5, c = e & 31;
        float s = 0.f;
        #pragma unroll
        for (int kp = 0; kp < 32; ++kp) s += Wb[k*1024 + c*32 + kp]*f2vL[kp];
        ws[dstP + e] = s;
      }
    }
    if (t < 32) {
      float s = 0.f;
      #pragma unroll
      for (int kp = 0; kp < 32; ++kp) s += bb[t*32+kp]*f2vL[kp];
      ws[dstC+t] = s;
    }
  }
}

// ---------------------------------------------------------------------------
// kBSP: blocks [0,G): per-graph CSR+score+select+compact (kBS).
//       blocks [G,2G): PI conv reduced by g0v/g2v (kPI, LDS aliased).
// ---------------------------------------------------------------------------
__global__ __launch_bounds__(1024, 4) void kBSP(
    const int* __restrict__ ei1, const int* __restrict__ ei2,
    const float* __restrict__ bsc,
    const float* __restrict__ PI1, const float* __restrict__ PI2,
    const float* __restrict__ Kc, const float* __restrict__ bc,
    const float* __restrict__ G0w, const float* __restrict__ G2w,
    const float* __restrict__ H0w, const float* __restrict__ H2w,
    float* __restrict__ ws)
{
  __shared__ uint16_t srcL[E_];    // 64KB
  __shared__ float DscL[N_*5];     // 20KB
  __shared__ float dinvF[N_];      // 4KB
  __shared__ int fbL[N_];          // 4KB
  __shared__ int fillL[N_];        // 4KB
  __shared__ int nidxL[N_];        // 4KB
  __shared__ int seoffL[K_];       // 2KB
  __shared__ int vdegL[K_];        // 2KB
  __shared__ int ceoffL[K_];       // 2KB
  __shared__ int hist[256], hsum[256];
  __shared__ int wtot[16], wbase[16], wsum[16];
  __shared__ int remL, dstarL;

  int blk = blockIdx.x, t = threadIdx.x;

  if (blk >= G_) {
    // =================== kPI branch (1024 threads) ===================
    int g = blk - G_, br = g >> 6, b = g & 63;
    const float* pig = (br ? PI2 : PI1) + (size_t)b*CF_*P_*P_;
    float* PIt = (float*)srcL;      // 12500 floats within 16384
    float* KcL = DscL;              // 640 within 5120
    float* bcL = dinvF;             // 32
    float* g0L = dinvF + 32;        // 32
    float* g2L = dinvF + 64;        // 25
    float* h2L = dinvF + 96;        // 32
    float* hhL = dinvF + 128;       // 32
    float* scr = (float*)fbL;       // 625 within 1024

    for (int i = t; i < CF_*P_*P_; i += 1024) PIt[i] = pig[i];
    if (t < H_*CF_*4) KcL[t] = Kc[t];
    if (t < 256) {
      int p = t >> 3, s = t & 7;
      float v = 0.f;
      #pragma unroll
      for (int q = 0; q < 8; ++q) v += H0w[(s + q*8)*64 + 32 + p];
      #pragma unroll
      for (int d = 4; d > 0; d >>= 1) v += __shfl_down(v, d, 8);
      if (s == 0) hhL[p] = v * (1.f/64.f);
    }
    if (t >= 256 && t < 512) {
      int tt = t - 256;
      int r = tt >> 3, s = tt & 7;
      float v = 0.f;
      #pragma unroll
      for (int q = 0; q < 4; ++q) v += H2w[(s + q*8)*32 + r];
      #pragma unroll
      for (int d = 4; d > 0; d >>= 1) v += __shfl_down(v, d, 8);
      if (s == 0) h2L[r] = v * (1.f/32.f);
    }
    if (t >= 512 && t < 544) bcL[t - 512] = bc[t - 512];
    __syncthreads();
    if (t < 32) { float s = 0.f; for (int p = 0; p < 32; ++p) s += G0w[p*32+t]*hhL[p]; g0L[t] = s; }
    if (t >= 64 && t < 64+PO) {
      int kp = t - 64;
      float s = 0.f;
      for (int r = 0; r < 32; ++r) s += G2w[r*25+kp]*h2L[r];
      g2L[kp] = s;
    }
    __syncthreads();
    if (t < PO*PO) {
      int jp = t / PO, kp = t - jp*PO;
      float p00[CF_], p01[CF_], p10[CF_], p11[CF_];
      #pragma unroll
      for (int c = 0; c < CF_; ++c) {
        const float* q = &PIt[c*2500 + (2*jp)*50 + 2*kp];
        p00[c] = q[0]; p01[c] = q[1]; p10[c] = q[50]; p11[c] = q[51];
      }
      float acc = 0.f;
      for (int i = 0; i < H_; ++i) {
        float v = bcL[i];
        const float* kcp = &KcL[i*20];
        #pragma unroll
        for (int c = 0; c < CF_; ++c)
          v += p00[c]*kcp[c*4+0] + p01[c]*kcp[c*4+1] + p10[c]*kcp[c*4+2] + p11[c]*kcp[c*4+3];
        acc += fmaxf(v, 0.f) * g0L[i];
      }
      scr[t] = acc * g2L[kp];
    }
    __syncthreads();
    if (t < PO) {
      float s = 0.f;
      #pragma unroll
      for (int k = 0; k < PO; ++k) s += scr[t*PO + k];
      ws[WS_PPI + (size_t)g*32 + t] = s;
    }
    return;
  }

  // =================== kBS branch ===================
  int g = blk, br = g >> 6, b = g & 63;
  const int* ei  = (br ? ei2 : ei1) + (size_t)b*2*E_;
  const int* src = ei;
  const int* dst = ei + E_;
  int* onodeg = (int*)ws + WS_ONODE + (size_t)g*K_;
  uint16_t* vdegg = (uint16_t*)(ws + WS_VDEG) + (size_t)g*K_;
  int* ceoffg = (int*)ws + WS_EOFF + (size_t)g*K_;
  float* dinvg = ws + WS_DINV + (size_t)g*K_;
  uint16_t* csrc = (uint16_t*)(ws + WS_SRCS) + (size_t)g*E_;

  { const float* Dg = ws + WS_DSC + (size_t)g*N_*5;
    for (int i = t; i < N_*5; i += 1024) DscL[i] = Dg[i]; }
  fillL[t] = 0;
  if (t < 256) hist[t] = 0;
  if (t == 0) remL = K_;
  __syncthreads();

  // A: single global read of edges; count atomics ALSO yield slot indices.
  // pack: src:10 | dst:10 | slot:12  (uniform-random degrees << 4096)
  uint32_t ep[32];
  #pragma unroll
  for (int i = 0; i < 32; ++i) {
    int e = t + i*1024;
    int s = src[e], d = dst[e];
    int slot = atomicAdd(&fillL[d], 1);
    ep[i] = (uint32_t)s | ((uint32_t)d << 10) | ((uint32_t)slot << 20);
  }
  __syncthreads();

  // B: exclusive scan of counts
  int c = fillL[t];
  int lane = t & 63, w = t >> 6;
  int x = c;
  #pragma unroll
  for (int s = 1; s < 64; s <<= 1) {
    int v = __shfl_up(x, s);
    if (lane >= s) x += v;
  }
  if (lane == 63) wsum[w] = x;
  __syncthreads();
  if (w == 0 && lane < 16) {
    int y = wsum[lane];
    #pragma unroll
    for (int s = 1; s < 16; s <<= 1) {
      int v = __shfl_up(y, s, 16);
      if (lane >= s) y += v;
    }
    wsum[lane] = y;
  }
  __syncthreads();
  int off0 = ((w == 0) ? 0 : wsum[w-1]) + x - c;
  int off1 = off0 + c;
  fbL[t] = off0;
  dinvF[t] = rsqrtf((float)c + 1.0f);
  __syncthreads();

  // C: scatter into LDS from registers -- no atomics (slots pre-assigned)
  #pragma unroll
  for (int i = 0; i < 32; ++i) {
    uint32_t e = ep[i];
    int s = (int)(e & 0x3FFu), d = (int)((e >> 10) & 0x3FFu), slot = (int)(e >> 20);
    srcL[fbL[d] + slot] = (uint16_t)s;
  }
  __syncthreads();

  // D: score gather from LDS
  uint32_t key;
  {
    float agg[5] = {};
    for (int e = off0; e < off1; ++e) {
      int s = srcL[e];
      float dvs = dinvF[s];
      const float* hr = &DscL[s*5];
      #pragma unroll
      for (int j = 0; j < 5; ++j) agg[j] += hr[j]*dvs;
    }
    float dv = dinvF[t];
    const float* hn = &DscL[t*5];
    float sc = 0.f;
    #pragma unroll
    for (int j = 0; j < 5; ++j)
      sc += fabsf(dv*(agg[j] + dv*hn[j]) + (bsc[2*j+1] - bsc[2*j]));
    key = __float_as_uint(sc);   // sc >= 0 -> uint order == float order
  }
  __syncthreads();

  // E: 4-pass radix select; wave0 does the 256-bin suffix scan via shfl.
  uint32_t pref = 0, prefMask = 0;
  #pragma unroll
  for (int pass = 0; pass < 4; ++pass) {
    int shift = 24 - 8*pass;
    bool cand = (key & prefMask) == pref;
    if (cand) atomicAdd(&hist[(key >> shift) & 255], 1);
    __syncthreads();                          // B1: hist complete
    if (w == 0) {
      int base = lane*4;
      int h0 = hist[base+0], h1 = hist[base+1], h2 = hist[base+2], h3 = hist[base+3];
      int suf = h0 + h1 + h2 + h3;
      #pragma unroll
      for (int sh = 1; sh < 64; sh <<= 1) {
        int v = __shfl_down(suf, sh);
        if (lane + sh < 64) suf += v;
      }
      hsum[base+0] = suf;
      hsum[base+1] = suf - h0;
      hsum[base+2] = suf - h0 - h1;
      hsum[base+3] = suf - h0 - h1 - h2;
    }
    __syncthreads();                          // B2: hsum visible
    int rem = remL;
    if (t < 256) {
      int above = (t == 255) ? 0 : hsum[t+1];
      if (hsum[t] >= rem && above < rem) dstarL = t;
      hist[t] = 0;                            // zero for next pass
    }
    __syncthreads();                          // B3: dstar + zero done
    int ds = dstarL;
    if (t == 0) remL = rem - ((ds == 255) ? 0 : hsum[ds+1]);
    pref |= (uint32_t)ds << shift;
    prefMask |= 0xFFu << shift;
  }
  __syncthreads();
  uint32_t T = pref;
  int r = remL;

  // ties (key == T) rank by idx asc; select key>T plus first r ties
  bool eq = (key == T);
  uint64_t mEq = __ballot(eq);
  int lpEq = (int)__popcll(mEq & ((1ull << lane) - 1));
  if (lane == 0) wtot[w] = (int)__popcll(mEq);
  __syncthreads();
  if (t == 0) { int a = 0; for (int q = 0; q < 16; ++q) { wbase[q] = a; a += wtot[q]; } }
  __syncthreads();
  bool sel = (key > T) || (eq && (wbase[w] + lpEq) < r);
  __syncthreads();
  uint64_t mS = __ballot(sel);
  int lpS = (int)__popcll(mS & ((1ull << lane) - 1));
  if (lane == 0) wtot[w] = (int)__popcll(mS);
  __syncthreads();
  if (t == 0) { int a = 0; for (int q = 0; q < 16; ++q) { wbase[q] = a; a += wtot[q]; } }
  __syncthreads();
  int rank = wbase[w] + lpS;
  nidxL[t] = sel ? rank : -1;
  if (sel) onodeg[rank] = t;
  __syncthreads();

  // F: compact own segment in place (remap to ranks)
  if (sel) {
    int c2 = 0;
    for (int e = off0; e < off1; ++e) {
      int m = nidxL[srcL[e]];
      if (m >= 0) srcL[off0 + (c2++)] = (uint16_t)m;
    }
    vdegL[rank] = c2;
    seoffL[rank] = off0;
  }
  __syncthreads();

  // G: scan vdeg over 512 ranks -> packed offsets
  int vv = 0, xx = 0, w2 = t >> 6;
  if (t < K_) {
    vv = vdegL[t]; xx = vv;
    int l2 = t & 63;
    #pragma unroll
    for (int s = 1; s < 64; s <<= 1) {
      int v = __shfl_up(xx, s);
      if (l2 >= s) xx += v;
    }
    if (l2 == 63) wsum[w2] = xx;
  }
  __syncthreads();
  if (t == 0) { int run = 0; for (int q = 0; q < 8; ++q) { int tm = wsum[q]; wsum[q] = run; run += tm; } }
  __syncthreads();
  if (t < K_) {
    int ce = wsum[w2] + xx - vv;
    ceoffL[t] = ce;
    ceoffg[t] = ce;
    vdegg[t] = (uint16_t)vv;
    dinvg[t] = rsqrtf((float)vv + 1.0f);
  }
  __syncthreads();

  // H: coalesced packed edge-list write; owning rank via binary search
  int tot = ceoffL[K_-1] + vdegL[K_-1];
  for (int p = t; p < tot; p += 1024) {
    int lo2 = 0, hi2 = K_ - 1;
    while (lo2 < hi2) {
      int mid = (lo2 + hi2 + 1) >> 1;
      if (ceoffL[mid] <= p) lo2 = mid; else hi2 = mid - 1;
    }
    csrc[p] = srcL[seoffL[lo2] + (p - ceoffL[lo2])];
  }
}

// ---------------------------------------------------------------------------
// 256x32 @ 32x32 matmul core on swizzled LDS; W padded [32][36].
// ---------------------------------------------------------------------------
static __device__ __forceinline__ void mmA(
    const float* __restrict__ S, const float* __restrict__ Wp,
    float (&acc)[4][4], int it, int jt)
{
  const int i0 = it*4, swa = it & 7;
  #pragma unroll
  for (int kv = 0; kv < 8; ++kv) {
    float4 w0 = *(const float4*)&Wp[(kv*4+0)*36 + jt*4];
    float4 w1 = *(const float4*)&Wp[(kv*4+1)*36 + jt*4];
    float4 w2 = *(const float4*)&Wp[(kv*4+2)*36 + jt*4];
    float4 w3 = *(const float4*)&Wp[(kv*4+3)*36 + jt*4];
    #pragma unroll
    for (int d = 0; d < 4; ++d) {
      float4 a = *(const float4*)&S[(i0+d)*32 + ((kv ^ swa) << 2)];
      acc[d][0] += a.x*w0.x + a.y*w1.x + a.z*w2.x + a.w*w3.x;
      acc[d][1] += a.x*w0.y + a.y*w1.y + a.z*w2.y + a.w*w3.y;
      acc[d][2] += a.x*w0.z + a.y*w1.z + a.z*w2.z + a.w*w3.z;
      acc[d][3] += a.x*w0.w + a.y*w1.w + a.z*w2.w + a.w*w3.w;
    }
  }
}

// ---------------------------------------------------------------------------
// kG1: gA[g][dd] = dinv[dd] * (x[onode[dd]] @ Wg0).  grid (G,2) x 512.
// ---------------------------------------------------------------------------
__global__ __launch_bounds__(512, 4) void kG1(
    const float* __restrict__ x1, const float* __restrict__ x2,
    const float* __restrict__ Wg0, float* __restrict__ ws)
{
  int g = blockIdx.x, half = blockIdx.y, br = g >> 6, b = g & 63;
  const float* xg = (br ? x2 : x1) + (size_t)b*N_*F_;
  const int* onodeg = (const int*)ws + WS_ONODE + (size_t)g*K_ + half*256;
  const float* dinvg = ws + WS_DINV + (size_t)g*K_ + half*256;
  float* gAg = ws + WS_GA + (size_t)g*K_*H_ + (size_t)half*256*H_;

  __shared__ float wbuf[F_*36];
  __shared__ int   onodeL[256];
  __shared__ float dinvL[256];

  int t = threadIdx.x;
  for (int i = t; i < F_*H_; i += 512) wbuf[(i >> 5)*36 + (i & 31)] = Wg0[i];
  if (t < 256) { onodeL[t] = onodeg[t]; dinvL[t] = dinvg[t]; }
  __syncthreads();

  const int it = t >> 3, jt = t & 7;
  const int i0 = it*4;
  const float* xr0 = xg + (size_t)onodeL[i0+0]*F_;
  const float* xr1 = xg + (size_t)onodeL[i0+1]*F_;
  const float* xr2 = xg + (size_t)onodeL[i0+2]*F_;
  const float* xr3 = xg + (size_t)onodeL[i0+3]*F_;
  float acc[4][4] = {};
  for (int k4 = 0; k4 < 32; ++k4) {
    float4 w0 = *(const float4*)&wbuf[(k4*4+0)*36 + jt*4];
    float4 w1 = *(const float4*)&wbuf[(k4*4+1)*36 + jt*4];
    float4 w2 = *(const float4*)&wbuf[(k4*4+2)*36 + jt*4];
    float4 w3 = *(const float4*)&wbuf[(k4*4+3)*36 + jt*4];
    float4 a;
    a = *(const float4*)(xr0 + k4*4);
    acc[0][0]+=a.x*w0.x+a.y*w1.x+a.z*w2.x+a.w*w3.x; acc[0][1]+=a.x*w0.y+a.y*w1.y+a.z*w2.y+a.w*w3.y;
    acc[0][2]+=a.x*w0.z+a.y*w1.z+a.z*w2.z+a.w*w3.z; acc[0][3]+=a.x*w0.w+a.y*w1.w+a.z*w2.w+a.w*w3.w;
    a = *(const float4*)(xr1 + k4*4);
    acc[1][0]+=a.x*w0.x+a.y*w1.x+a.z*w2.x+a.w*w3.x; acc[1][1]+=a.x*w0.y+a.y*w1.y+a.z*w2.y+a.w*w3.y;
    acc[1][2]+=a.x*w0.z+a.y*w1.z+a.z*w2.z+a.w*w3.z; acc[1][3]+=a.x*w0.w+a.y*w1.w+a.z*w2.w+a.w*w3.w;
    a = *(const float4*)(xr2 + k4*4);
    acc[2][0]+=a.x*w0.x+a.y*w1.x+a.z*w2.x+a.w*w3.x; acc[2][1]+=a.x*w0.y+a.y*w1.y+a.z*w2.y+a.w*w3.y;
    acc[2][2]+=a.x*w0.z+a.y*w1.z+a.z*w2.z+a.w*w3.z; acc[2][3]+=a.x*w0.w+a.y*w1.w+a.z*w2.w+a.w*w3.w;
    a = *(const float4*)(xr3 + k4*4);
    acc[3][0]+=a.x*w0.x+a.y*w1.x+a.z*w2.x+a.w*w3.x; acc[3][1]+=a.x*w0.y+a.y*w1.y+a.z*w2.y+a.w*w3.y;
    acc[3][2]+=a.x*w0.z+a.y*w1.z+a.z*w2.z+a.w*w3.z; acc[3][3]+=a.x*w0.w+a.y*w1.w+a.z*w2.w+a.w*w3.w;
  }
  #pragma unroll
  for (int d = 0; d < 4; ++d) {
    int row = i0 + d;
    float rs = dinvL[row];
    float4 o; o.x=acc[d][0]*rs; o.y=acc[d][1]*rs; o.z=acc[d][2]*rs; o.w=acc[d][3]*rs;
    *(float4*)&gAg[row*32 + jt*4] = o;
  }
}

// ---------------------------------------------------------------------------
// conv gather (packed CSR) from global feature buffer into swizzled LDS.
// ---------------------------------------------------------------------------
static __device__ __forceinline__ void convG(
    const float* __restrict__ gS, float* __restrict__ cbuf,
    const float* __restrict__ bias, const float* __restrict__ dinvL,
    const int* __restrict__ eoffL, const int* __restrict__ vcntL,
    const uint16_t* __restrict__ srcS, int half, int t)
{
  int ddl = t & 255, hc = t >> 8;
  int dd = half*256 + ddl;
  int lo = eoffL[ddl], n = vcntL[ddl];
  int c0 = hc*16;
  float4 a0 = {0,0,0,0}, a1 = a0, a2 = a0, a3 = a0;
  for (int i = 0; i < n; ++i) {
    int ss = srcS[lo + i];
    const float* r = gS + ss*32 + c0;
    float4 v;
    v = *(const float4*)(r+0);  a0.x+=v.x; a0.y+=v.y; a0.z+=v.z; a0.w+=v.w;
    v = *(const float4*)(r+4);  a1.x+=v.x; a1.y+=v.y; a1.z+=v.z; a1.w+=v.w;
    v = *(const float4*)(r+8);  a2.x+=v.x; a2.y+=v.y; a2.z+=v.z; a2.w+=v.w;
    v = *(const float4*)(r+12); a3.x+=v.x; a3.y+=v.y; a3.z+=v.z; a3.w+=v.w;
  }
  { const float* r = gS + dd*32 + c0;
    float4 v;
    v = *(const float4*)(r+0);  a0.x+=v.x; a0.y+=v.y; a0.z+=v.z; a0.w+=v.w;
    v = *(const float4*)(r+4);  a1.x+=v.x; a1.y+=v.y; a1.z+=v.z; a1.w+=v.w;
    v = *(const float4*)(r+8);  a2.x+=v.x; a2.y+=v.y; a2.z+=v.z; a2.w+=v.w;
    v = *(const float4*)(r+12); a3.x+=v.x; a3.y+=v.y; a3.z+=v.z; a3.w+=v.w; }
  float dvd = dinvL[ddl];
  float4 r0, r1, r2, r3;
  r0.x = dvd*a0.x + bias[c0+0];  r0.y = dvd*a0.y + bias[c0+1];
  r0.z = dvd*a0.z + bias[c0+2];  r0.w = dvd*a0.w + bias[c0+3];
  r1.x = dvd*a1.x + bias[c0+4];  r1.y = dvd*a1.y + bias[c0+5];
  r1.z = dvd*a1.z + bias[c0+6];  r1.w = dvd*a1.w + bias[c0+7];
  r2.x = dvd*a2.x + bias[c0+8];  r2.y = dvd*a2.y + bias[c0+9];
  r2.z = dvd*a2.z + bias[c0+10]; r2.w = dvd*a2.w + bias[c0+11];
  r3.x = dvd*a3.x + bias[c0+12]; r3.y = dvd*a3.y + bias[c0+13];
  r3.z = dvd*a3.z + bias[c0+14]; r3.w = dvd*a3.w + bias[c0+15];
  int g4 = hc*4;
  *(float4*)&cbuf[swzf4(ddl, g4+0)] = r0;
  *(float4*)&cbuf[swzf4(ddl, g4+1)] = r1;
  *(float4*)&cbuf[swzf4(ddl, g4+2)] = r2;
  *(float4*)&cbuf[swzf4(ddl, g4+3)] = r3;
}

// ---------------------------------------------------------------------------
// kG2: conv0 -> r0=relu(.@Wm0a+b) -> {column partials, gC=(r0@W01+b01)*dinv}
// ---------------------------------------------------------------------------
__global__ __launch_bounds__(512, 4) void kG2(
    const float* __restrict__ bg0,
    const float* __restrict__ Wm0a, const float* __restrict__ bm0a,
    float* __restrict__ ws)
{
  int g = blockIdx.x, half = blockIdx.y;
  const float* gAg = ws + WS_GA + (size_t)g*K_*H_;
  float* gCg = ws + WS_GC + (size_t)g*K_*H_;
  const uint16_t* srcS = (const uint16_t*)(ws + WS_SRCS) + (size_t)g*E_;
  const int* eoffg = (const int*)ws + WS_EOFF + (size_t)g*K_ + half*256;
  const uint16_t* vdegg = (const uint16_t*)(ws + WS_VDEG) + (size_t)g*K_ + half*256;
  const float* dinvg = ws + WS_DINV + (size_t)g*K_ + half*256;

  __shared__ float cbufA[256*32];
  __shared__ float cbufB[256*32];
  __shared__ float wA[32*36];
  __shared__ float wB[32*36];
  __shared__ float scrP[64*33];
  __shared__ int   eoffL[256];
  __shared__ int   vcntL[256];
  __shared__ float dinvL[256];

  int t = threadIdx.x;
  for (int i = t; i < 1024; i += 512) {
    int k = i >> 5, j = i & 31;
    wA[k*36+j] = Wm0a[i];
    wB[k*36+j] = ws[WS_W01 + i];
  }
  if (t < 256) { eoffL[t] = eoffg[t]; vcntL[t] = vdegg[t]; dinvL[t] = dinvg[t]; }
  __syncthreads();

  convG(gAg, cbufA, bg0, dinvL, eoffL, vcntL, srcS, half, t);
  __syncthreads();

  const int it = t >> 3, jt = t & 7;
  float acc[4][4] = {};
  mmA(cbufA, wA, acc, it, jt);
  {
    float b0 = bm0a[jt*4+0], b1 = bm0a[jt*4+1], b2 = bm0a[jt*4+2], b3 = bm0a[jt*4+3];
    float cp0=0.f, cp1=0.f, cp2=0.f, cp3=0.f;
    #pragma unroll
    for (int d = 0; d < 4; ++d) {
      float v0=fmaxf(acc[d][0]+b0,0.f), v1=fmaxf(acc[d][1]+b1,0.f);
      float v2=fmaxf(acc[d][2]+b2,0.f), v3=fmaxf(acc[d][3]+b3,0.f);
      cp0+=v0; cp1+=v1; cp2+=v2; cp3+=v3;
      float4 o; o.x=v0; o.y=v1; o.z=v2; o.w=v3;
      *(float4*)&cbufB[swzf4(it*4+d, jt)] = o;
    }
    scrP[it*33 + jt*4+0] = cp0; scrP[it*33 + jt*4+1] = cp1;
    scrP[it*33 + jt*4+2] = cp2; scrP[it*33 + jt*4+3] = cp3;
  }
  __syncthreads();

  if (t < 32) {
    float s = 0.f;
    #pragma unroll
    for (int q = 0; q < 64; ++q) s += scrP[q*33 + t];
    ws[WS_PM0 + (size_t)g*64 + half*32 + t] = s;
  }

  float acc2[4][4] = {};
  mmA(cbufB, wB, acc2, it, jt);
  {
    float b0 = ws[WS_B01+jt*4+0], b1 = ws[WS_B01+jt*4+1];
    float b2 = ws[WS_B01+jt*4+2], b3 = ws[WS_B01+jt*4+3];
    #pragma unroll
    for (int d = 0; d < 4; ++d) {
      int row = it*4 + d;
      float rs = dinvL[row];
      float4 o;
      o.x=(acc2[d][0]+b0)*rs; o.y=(acc2[d][1]+b1)*rs;
      o.z=(acc2[d][2]+b2)*rs; o.w=(acc2[d][3]+b3)*rs;
      *(float4*)&gCg[(half*256+row)*32 + jt*4] = o;
    }
  }
}

// ---------------------------------------------------------------------------
// kG4: conv1 -> r1=relu(.@Wm1a+b) -> column partials.
// ---------------------------------------------------------------------------
__global__ __launch_bounds__(512, 4) void kG4(
    const float* __restrict__ bg1,
    const float* __restrict__ Wm1a, const float* __restrict__ bm1a,
    float* __restrict__ ws)
{
  int g = blockIdx.x, half = blockIdx.y;
  const float* gCg = ws + WS_GC + (size_t)g*K_*H_;
  const uint16_t* srcS = (const uint16_t*)(ws + WS_SRCS) + (size_t)g*E_;
  const int* eoffg = (const int*)ws + WS_EOFF + (size_t)g*K_ + half*256;
  const uint16_t* vdegg = (const uint16_t*)(ws + WS_VDEG) + (size_t)g*K_ + half*256;
  const float* dinvg = ws + WS_DINV + (size_t)g*K_ + half*256;

  __shared__ float cbufA[256*32];
  __shared__ float wA[32*36];
  __shared__ float scrP[64*33];
  __shared__ int   eoffL[256];
  __shared__ int   vcntL[256];
  __shared__ float dinvL[256];

  int t = threadIdx.x;
  for (int i = t; i < 1024; i += 512) wA[(i>>5)*36 + (i&31)] = Wm1a[i];
  if (t < 256) { eoffL[t] = eoffg[t]; vcntL[t] = vdegg[t]; dinvL[t] = dinvg[t]; }
  __syncthreads();

  convG(gCg, cbufA, bg1, dinvL, eoffL, vcntL, srcS, half, t);
  __syncthreads();

  const int it = t >> 3, jt = t & 7;
  float acc[4][4] = {};
  mmA(cbufA, wA, acc, it, jt);
  {
    float b0 = bm1a[jt*4+0], b1 = bm1a[jt*4+1], b2 = bm1a[jt*4+2], b3 = bm1a[jt*4+3];
    float cp0=0.f, cp1=0.f, cp2=0.f, cp3=0.f;
    #pragma unroll
    for (int d = 0; d < 4; ++d) {
      cp0 += fmaxf(acc[d][0]+b0,0.f); cp1 += fmaxf(acc[d][1]+b1,0.f);
      cp2 += fmaxf(acc[d][2]+b2,0.f); cp3 += fmaxf(acc[d][3]+b3,0.f);
    }
    scrP[it*33 + jt*4+0] = cp0; scrP[it*33 + jt*4+1] = cp1;
    scrP[it*33 + jt*4+2] = cp2; scrP[it*33 + jt*4+3] = cp3;
  }
  __syncthreads();

  if (t < 32) {
    float s = 0.f;
    #pragma unroll
    for (int q = 0; q < 64; ++q) s += scrP[q*33 + t];
    ws[WS_PM1 + (size_t)g*64 + half*32 + t] = s;
  }
}

// ---------------------------------------------------------------------------
// k5: per-graph tail via folded P0b/P1b. grid G x 64.
// ---------------------------------------------------------------------------
__global__ __launch_bounds__(64) void k5_final(
    const float* __restrict__ F1w, const float* __restrict__ G1w,
    const float* __restrict__ H1w, const float* __restrict__ Wo1,
    const float* __restrict__ bo1, const float* __restrict__ Wo2,
    const float* __restrict__ bo2, const float* __restrict__ ws,
    float* __restrict__ out)
{
  int g = blockIdx.x, t = threadIdx.x;
  __shared__ float mr0[32], mr1[32], AL[32], TL[32], pl[32], zl[32], ppiL[PO];
  if (t < 32) {
    mr0[t] = (ws[WS_PM0 + (size_t)g*64 + t] + ws[WS_PM0 + (size_t)g*64 + 32 + t]) * (1.f/512.f);
    mr1[t] = (ws[WS_PM1 + (size_t)g*64 + t] + ws[WS_PM1 + (size_t)g*64 + 32 + t]) * (1.f/512.f);
  }
  if (t >= 32 && t < 32+PO) ppiL[t-32] = ws[WS_PPI + (size_t)g*32 + (t-32)];
  __syncthreads();
  float f00 = ws[WS_F0V], f01 = ws[WS_F0V+1];
  if (t < 32) {
    float s0 = ws[WS_C0B + t], s1 = ws[WS_C1B + t];
    for (int k = 0; k < 32; ++k) {
      s0 += mr0[k]*ws[WS_P0B + k*32 + t];
      s1 += mr1[k]*ws[WS_P1B + k*32 + t];
    }
    AL[t] = f00*s0 + f01*s1;
  }
  __syncthreads();
  if (t < 32) {
    float s = 0.f;
    for (int jp = 0; jp < 32; ++jp) s += F1w[t*32+jp]*AL[jp];
    for (int jp = 0; jp < PO; ++jp) s += G1w[t*25+jp]*ppiL[jp];
    TL[t] = s;
  }
  __syncthreads();
  if (t < 32) {
    float s = 0.f;
    for (int j = 0; j < 32; ++j) s += H1w[t*32+j]*TL[j];
    pl[t] = s;
  }
  __syncthreads();
  if (t < 32) {
    float s = bo1[t];
    for (int j = 0; j < 32; ++j) s += pl[j]*Wo1[j*32+t];
    zl[t] = fmaxf(s, 0.f);
  }
  __syncthreads();
  if (t < 2) {
    float s = bo2[t];
    for (int q = 0; q < 32; ++q) s += zl[q]*Wo2[q*2+t];
    int br = g >> 6, b = g & 63;
    out[br*(B_*2) + b*2 + t] = s;
  }
}

// ---------------------------------------------------------------------------
extern "C" void kernel_launch(void* const* d_in, const int* in_sizes, int n_in,
                              void* d_out, int out_size, void* d_ws, size_t ws_size,
                              hipStream_t stream) {
  (void)in_sizes; (void)n_in; (void)out_size; (void)ws_size;
  const float* x1      = (const float*)d_in[0];
  const int*   ei1     = (const int*)  d_in[1];
  const float* PI1     = (const float*)d_in[2];
  const float* x2      = (const float*)d_in[3];
  const int*   ei2     = (const int*)  d_in[4];
  const float* PI2     = (const float*)d_in[5];
  const float* W_score = (const float*)d_in[6];
  const float* b_score = (const float*)d_in[7];
  const float* W_gcn0  = (const float*)d_in[8];
  const float* b_gcn0  = (const float*)d_in[9];
  const float* Wm0a    = (const float*)d_in[10];
  const float* bm0a    = (const float*)d_in[11];
  const float* Wm0b    = (const float*)d_in[12];
  const float* bm0b    = (const float*)d_in[13];
  const float* W_gcn1  = (const float*)d_in[14];
  const float* b_gcn1  = (const float*)d_in[15];
  const float* Wm1a    = (const float*)d_in[16];
  const float* bm1a    = (const float*)d_in[17];
  const float* Wm1b    = (const float*)d_in[18];
  const float* bm1b    = (const float*)d_in[19];
  const float* F0w     = (const float*)d_in[20];
  const float* F1w     = (const float*)d_in[21];
  const float* F2w     = (const float*)d_in[22];
  const float* Kc      = (const float*)d_in[23];
  const float* bc      = (const float*)d_in[24];
  const float* G0w     = (const float*)d_in[25];
  const float* G1w     = (const float*)d_in[26];
  const float* G2w     = (const float*)d_in[27];
  const float* H0w     = (const float*)d_in[28];
  const float* H1w     = (const float*)d_in[29];
  const float* H2w     = (const float*)d_in[30];
  const float* Wo1     = (const float*)d_in[31];
  const float* bo1     = (const float*)d_in[32];
  const float* Wo2     = (const float*)d_in[33];
  const float* bo2     = (const float*)d_in[34];
  float* ws  = (float*)d_ws;
  float* out = (float*)d_out;

  kA_pre<<<8*G_ + 36, 512, 0, stream>>>(x1, x2, W_score,
                                        F0w, F2w, H0w, H2w,
                                        Wm0b, bm0b, Wm1b, bm1b, W_gcn1, ws);
  kBSP<<<2*G_, 1024, 0, stream>>>(ei1, ei2, b_score, PI1, PI2, Kc, bc,
                                  G0w, G2w, H0w, H2w, ws);
  kG1<<<dim3(G_, 2), 512, 0, stream>>>(x1, x2, W_gcn0, ws);
  kG2<<<dim3(G_, 2), 512, 0, stream>>>(b_gcn0, Wm0a, bm0a, ws);
  kG4<<<dim3(G_, 2), 512, 0, stream>>>(b_gcn1, Wm1a, bm1a, ws);
  k5_final<<<G_, 64, 0, stream>>>(F1w, G1w, H1w, Wo1, bo1, Wo2, bo2, ws, out);
}

// Round 15
// 154.735 us; speedup vs baseline: 1.4226x; 1.0002x over previous
//
#include <hip/hip_runtime.h>
#include <cstdint>

// ---------------------------------------------------------------------------
// TenGCN fused forward. 128 graphs (2 branches x 64 batches).
// R15: kBSP latency-chain fixes -- phase A split (loads fully pipelined,
// atomics second), DscL prescaled by dinv, score gather 4-way unrolled.
// 6 launches: kA (Dsc+setup) -> kBSP (BS+PI) -> kG1 -> kG2 -> kG4 -> k5.
// ---------------------------------------------------------------------------

constexpr int B_ = 64, N_ = 1024, E_ = 32768, F_ = 128, H_ = 32;
constexpr int CF_ = 5, P_ = 50, K_ = 512, G_ = 128, PO = 25;

// workspace offsets (4-byte units)
constexpr size_t WS_SRCS  = 0;                                // G*E u16 (packed)
constexpr size_t WS_ONODE = WS_SRCS + (size_t)G_*(E_/2);      // G*512 int
constexpr size_t WS_VDEG  = WS_ONODE + (size_t)G_*K_;         // G*512 u16
constexpr size_t WS_EOFF  = WS_VDEG + (size_t)G_*(K_/2);      // G*512 int (packed ceoff)
constexpr size_t WS_DINV  = WS_EOFF + (size_t)G_*K_;          // G*512 f32 (valid dinv)
constexpr size_t WS_GA    = WS_DINV + (size_t)G_*K_;          // G*512*32 f32
constexpr size_t WS_GC    = WS_GA + (size_t)G_*K_*H_;         // G*512*32 f32
constexpr size_t WS_PM0   = WS_GC + (size_t)G_*K_*H_;         // G*2*32
constexpr size_t WS_PM1   = WS_PM0 + (size_t)G_*64;           // G*2*32
constexpr size_t WS_PPI   = WS_PM1 + (size_t)G_*64;           // G*32
constexpr size_t WS_F0V   = WS_PPI + (size_t)G_*32;           // 2 (pad 32)
constexpr size_t WS_B01   = WS_F0V + 32;                      // 32
constexpr size_t WS_C0B   = WS_B01 + 32;                      // 32
constexpr size_t WS_C1B   = WS_C0B + 32;                      // 32
constexpr size_t WS_W01   = WS_C1B + 32;                      // 1024
constexpr size_t WS_P0B   = WS_W01 + 1024;                    // 1024
constexpr size_t WS_P1B   = WS_P0B + 1024;                    // 1024

// Dsc lives in the (dead until kG2) GC region
constexpr size_t WS_DSC   = WS_GC;                            // G*N*5 f32

static __device__ __forceinline__ int swzf4(int row, int c4) {
  return row*32 + (((c4) ^ ((row >> 2) & 7)) << 2);
}

// ---------------------------------------------------------------------------
// kA: blocks [0,8G): Dsc[g][n][5] = x[n] @ Wdiff (quad-per-row, coalesced).
//     blk2 = blk-8G: 0: F0V; 1..32: W01 rows; 33: B01; 34/35: P0b/P1b.
// ---------------------------------------------------------------------------
__global__ __launch_bounds__(512, 4) void kA_pre(
    const float* __restrict__ x1, const float* __restrict__ x2,
    const float* __restrict__ Wsc,
    const float* __restrict__ F0w, const float* __restrict__ F2w,
    const float* __restrict__ H0w, const float* __restrict__ H2w,
    const float* __restrict__ Wm0b, const float* __restrict__ bm0b,
    const float* __restrict__ Wm1b, const float* __restrict__ bm1b,
    const float* __restrict__ Wg1, float* __restrict__ ws)
{
  __shared__ float SM[640];   // 2.56KB union
  int blk = blockIdx.x, t = threadIdx.x;

  if (blk < 8*G_) {
    // ---- Dsc: 8 blocks/graph, 4 threads/row, 64B-coalesced reads ----
    int g = blk >> 3, sub = blk & 7, br = g >> 6, b = g & 63;
    const float* xg = (br ? x2 : x1) + (size_t)b*N_*F_;
    float* WdL = SM;  // 640
    if (t < F_) {
      #pragma unroll
      for (int j = 0; j < 5; ++j) WdL[t*5+j] = Wsc[t*10+2*j+1] - Wsc[t*10+2*j];
    }
    __syncthreads();
    int row = sub*128 + (t >> 2), q = t & 3;
    const float4* xr = (const float4*)(xg + (size_t)row*F_);
    float acc[5] = {};
    #pragma unroll
    for (int i = 0; i < 8; ++i) {
      int k4 = q + 4*i;
      float4 v = xr[k4];
      const float* w = &WdL[k4*20];
      #pragma unroll
      for (int j = 0; j < 5; ++j)
        acc[j] += v.x*w[j] + v.y*w[5+j] + v.z*w[10+j] + v.w*w[15+j];
    }
    #pragma unroll
    for (int j = 0; j < 5; ++j) {
      acc[j] += __shfl_xor(acc[j], 1, 4);
      acc[j] += __shfl_xor(acc[j], 2, 4);
    }
    if (q == 0) {
      float* o = ws + WS_DSC + ((size_t)g*N_ + row)*5;
      #pragma unroll
      for (int j = 0; j < 5; ++j) o[j] = acc[j];
    }
    return;
  }

  int blk2 = blk - 8*G_;
  if (blk2 == 0) {
    // F0V
    float* h0mS = SM;
    if (t < 32) { float s = 0.f; for (int qq = 0; qq < 64; ++qq) s += H0w[qq*64+t]; h0mS[t] = s*(1.f/64.f); }
    __syncthreads();
    if (t < 2) { float s = 0.f; for (int p = 0; p < 32; ++p) s += F0w[p*2+t]*h0mS[p]; ws[WS_F0V+t] = s; }
  } else if (blk2 <= 32) {
    // W01 row kk: 512 thr = 32 cols x 16 k-segments of 64.
    int kk = blk2 - 1;
    int ol = t >> 4, seg = t & 15;
    const float4* ar = (const float4*)(Wm0b + (size_t)kk*1024 + seg*64);
    float s = 0.f;
    #pragma unroll
    for (int i = 0; i < 16; ++i) {
      float4 a = ar[i];
      int tt = seg*64 + i*4;
      s += a.x*Wg1[(tt+0)*32 + ol] + a.y*Wg1[(tt+1)*32 + ol]
         + a.z*Wg1[(tt+2)*32 + ol] + a.w*Wg1[(tt+3)*32 + ol];
    }
    s += __shfl_xor(s, 1, 16);
    s += __shfl_xor(s, 2, 16);
    s += __shfl_xor(s, 4, 16);
    s += __shfl_xor(s, 8, 16);
    if (seg == 0) ws[WS_W01 + kk*32 + ol] = s;
  } else if (blk2 == 33) {
    // B01: 32 cols x 16 segments of 64 + LDS reduce.
    float* red = SM;   // 512
    int j = t & 31, seg = t >> 5;
    float s = 0.f;
    #pragma unroll
    for (int i = 0; i < 64; ++i) {
      int k = seg*64 + i;
      s += bm0b[k]*Wg1[k*32 + j];
    }
    red[seg*32 + j] = s;
    __syncthreads();
    if (t < 32) {
      float a = 0.f;
      #pragma unroll
      for (int q = 0; q < 16; ++q) a += red[q*32 + t];
      ws[WS_B01 + t] = a;
    }
  } else {
    // P0b/c0b (34) and P1b/c1b (35)
    const float* Wb = (blk2 == 34) ? Wm0b : Wm1b;
    const float* bb = (blk2 == 34) ? bm0b : bm1b;
    size_t dstP = (blk2 == 34) ? WS_P0B : WS_P1B;
    size_t dstC = (blk2 == 34) ? WS_C0B : WS_C1B;
    float* h2mL = SM;        // 32
    float* f2vL = SM + 32;   // 32
    if (t < 32) { float s = 0.f; for (int r = 0; r < 32; ++r) s += H2w[r*32+t]; h2mL[t] = s*(1.f/32.f); }
    __syncthreads();
    if (t < 32) { float s = 0.f; for (int r = 0; r < 32; ++r) s += F2w[r*32+t]*h2mL[r]; f2vL[t] = s; }
    __syncthreads();
    if (t < 256) {
      #pragma unroll
      for (int q = 0; q < 4; ++q) {
        int e = t*4 + q;
        int k = e >> 5, c = e & 31;
        float s = 0.f;
        #pragma unroll
        for (int kp = 0; kp < 32; ++kp) s += Wb[k*1024 + c*32 + kp]*f2vL[kp];
        ws[dstP + e] = s;
      }
    }
    if (t < 32) {
      float s = 0.f;
      #pragma unroll
      for (int kp = 0; kp < 32; ++kp) s += bb[t*32+kp]*f2vL[kp];
      ws[dstC+t] = s;
    }
  }
}

// ---------------------------------------------------------------------------
// kBSP: blocks [0,G): per-graph CSR+score+select+compact (kBS).
//       blocks [G,2G): PI conv reduced by g0v/g2v (kPI, LDS aliased).
// ---------------------------------------------------------------------------
__global__ __launch_bounds__(1024, 4) void kBSP(
    const int* __restrict__ ei1, const int* __restrict__ ei2,
    const float* __restrict__ bsc,
    const float* __restrict__ PI1, const float* __restrict__ PI2,
    const float* __restrict__ Kc, const float* __restrict__ bc,
    const float* __restrict__ G0w, const float* __restrict__ G2w,
    const float* __restrict__ H0w, const float* __restrict__ H2w,
    float* __restrict__ ws)
{
  __shared__ uint16_t srcL[E_];    // 64KB
  __shared__ float DscL[N_*5];     // 20KB
  __shared__ float dinvF[N_];      // 4KB
  __shared__ int fbL[N_];          // 4KB
  __shared__ int fillL[N_];        // 4KB
  __shared__ int nidxL[N_];        // 4KB
  __shared__ int seoffL[K_];       // 2KB
  __shared__ int vdegL[K_];        // 2KB
  __shared__ int ceoffL[K_];       // 2KB
  __shared__ int hist[256], hsum[256];
  __shared__ int wtot[16], wbase[16], wsum[16];
  __shared__ int remL, dstarL;

  int blk = blockIdx.x, t = threadIdx.x;

  if (blk >= G_) {
    // =================== kPI branch (1024 threads) ===================
    int g = blk - G_, br = g >> 6, b = g & 63;
    const float* pig = (br ? PI2 : PI1) + (size_t)b*CF_*P_*P_;
    float* PIt = (float*)srcL;      // 12500 floats within 16384
    float* KcL = DscL;              // 640 within 5120
    float* bcL = dinvF;             // 32
    float* g0L = dinvF + 32;        // 32
    float* g2L = dinvF + 64;        // 25
    float* h2L = dinvF + 96;        // 32
    float* hhL = dinvF + 128;       // 32
    float* scr = (float*)fbL;       // 625 within 1024

    for (int i = t; i < CF_*P_*P_; i += 1024) PIt[i] = pig[i];
    if (t < H_*CF_*4) KcL[t] = Kc[t];
    if (t < 256) {
      int p = t >> 3, s = t & 7;
      float v = 0.f;
      #pragma unroll
      for (int q = 0; q < 8; ++q) v += H0w[(s + q*8)*64 + 32 + p];
      #pragma unroll
      for (int d = 4; d > 0; d >>= 1) v += __shfl_down(v, d, 8);
      if (s == 0) hhL[p] = v * (1.f/64.f);
    }
    if (t >= 256 && t < 512) {
      int tt = t - 256;
      int r = tt >> 3, s = tt & 7;
      float v = 0.f;
      #pragma unroll
      for (int q = 0; q < 4; ++q) v += H2w[(s + q*8)*32 + r];
      #pragma unroll
      for (int d = 4; d > 0; d >>= 1) v += __shfl_down(v, d, 8);
      if (s == 0) h2L[r] = v * (1.f/32.f);
    }
    if (t >= 512 && t < 544) bcL[t - 512] = bc[t - 512];
    __syncthreads();
    if (t < 32) { float s = 0.f; for (int p = 0; p < 32; ++p) s += G0w[p*32+t]*hhL[p]; g0L[t] = s; }
    if (t >= 64 && t < 64+PO) {
      int kp = t - 64;
      float s = 0.f;
      for (int r = 0; r < 32; ++r) s += G2w[r*25+kp]*h2L[r];
      g2L[kp] = s;
    }
    __syncthreads();
    if (t < PO*PO) {
      int jp = t / PO, kp = t - jp*PO;
      float p00[CF_], p01[CF_], p10[CF_], p11[CF_];
      #pragma unroll
      for (int c = 0; c < CF_; ++c) {
        const float* q = &PIt[c*2500 + (2*jp)*50 + 2*kp];
        p00[c] = q[0]; p01[c] = q[1]; p10[c] = q[50]; p11[c] = q[51];
      }
      float acc = 0.f;
      for (int i = 0; i < H_; ++i) {
        float v = bcL[i];
        const float* kcp = &KcL[i*20];
        #pragma unroll
        for (int c = 0; c < CF_; ++c)
          v += p00[c]*kcp[c*4+0] + p01[c]*kcp[c*4+1] + p10[c]*kcp[c*4+2] + p11[c]*kcp[c*4+3];
        acc += fmaxf(v, 0.f) * g0L[i];
      }
      scr[t] = acc * g2L[kp];
    }
    __syncthreads();
    if (t < PO) {
      float s = 0.f;
      #pragma unroll
      for (int k = 0; k < PO; ++k) s += scr[t*PO + k];
      ws[WS_PPI + (size_t)g*32 + t] = s;
    }
    return;
  }

  // =================== kBS branch ===================
  int g = blk, br = g >> 6, b = g & 63;
  const int* ei  = (br ? ei2 : ei1) + (size_t)b*2*E_;
  const int* src = ei;
  const int* dst = ei + E_;
  int* onodeg = (int*)ws + WS_ONODE + (size_t)g*K_;
  uint16_t* vdegg = (uint16_t*)(ws + WS_VDEG) + (size_t)g*K_;
  int* ceoffg = (int*)ws + WS_EOFF + (size_t)g*K_;
  float* dinvg = ws + WS_DINV + (size_t)g*K_;
  uint16_t* csrc = (uint16_t*)(ws + WS_SRCS) + (size_t)g*E_;

  { const float* Dg = ws + WS_DSC + (size_t)g*N_*5;
    for (int i = t; i < N_*5; i += 1024) DscL[i] = Dg[i]; }
  fillL[t] = 0;
  if (t < 256) hist[t] = 0;
  if (t == 0) remL = K_;
  __syncthreads();

  // A1: pure edge loads into registers (no LDS dependency -- full MLP)
  uint32_t ep[32];
  #pragma unroll
  for (int i = 0; i < 32; ++i) {
    int e = t + i*1024;
    ep[i] = (uint32_t)src[e] | ((uint32_t)dst[e] << 10);
  }
  // A2: slot atomics from registers (pack src:10 | dst:10 | slot:12)
  #pragma unroll
  for (int i = 0; i < 32; ++i) {
    int d = (int)((ep[i] >> 10) & 0x3FFu);
    int slot = atomicAdd(&fillL[d], 1);
    ep[i] |= (uint32_t)slot << 20;
  }
  __syncthreads();

  // B: exclusive scan of counts
  int c = fillL[t];
  int lane = t & 63, w = t >> 6;
  int x = c;
  #pragma unroll
  for (int s = 1; s < 64; s <<= 1) {
    int v = __shfl_up(x, s);
    if (lane >= s) x += v;
  }
  if (lane == 63) wsum[w] = x;
  __syncthreads();
  if (w == 0 && lane < 16) {
    int y = wsum[lane];
    #pragma unroll
    for (int s = 1; s < 16; s <<= 1) {
      int v = __shfl_up(y, s, 16);
      if (lane >= s) y += v;
    }
    wsum[lane] = y;
  }
  __syncthreads();
  int off0 = ((w == 0) ? 0 : wsum[w-1]) + x - c;
  int off1 = off0 + c;
  fbL[t] = off0;
  float dvT = rsqrtf((float)c + 1.0f);
  dinvF[t] = dvT;
  __syncthreads();

  // prescale DscL by dinv (score = sum_j |dv*(aggS_j + DscS_t_j) + bd_j|)
  {
    #pragma unroll
    for (int j = 0; j < 5; ++j) DscL[t*5+j] *= dvT;
  }

  // C: scatter into LDS from registers -- no atomics (slots pre-assigned)
  #pragma unroll
  for (int i = 0; i < 32; ++i) {
    uint32_t e = ep[i];
    int s = (int)(e & 0x3FFu), d = (int)((e >> 10) & 0x3FFu), slot = (int)(e >> 20);
    srcL[fbL[d] + slot] = (uint16_t)s;
  }
  __syncthreads();

  // D: score gather from LDS -- 4-way unrolled (independent chains)
  uint32_t key;
  {
    float agg[5] = {};
    int e = off0;
    for (; e + 4 <= off1; e += 4) {
      int s0 = srcL[e+0], s1 = srcL[e+1], s2 = srcL[e+2], s3 = srcL[e+3];
      const float* h0 = &DscL[s0*5];
      const float* h1 = &DscL[s1*5];
      const float* h2 = &DscL[s2*5];
      const float* h3 = &DscL[s3*5];
      #pragma unroll
      for (int j = 0; j < 5; ++j) agg[j] += (h0[j] + h1[j]) + (h2[j] + h3[j]);
    }
    for (; e < off1; ++e) {
      const float* hr = &DscL[srcL[e]*5];
      #pragma unroll
      for (int j = 0; j < 5; ++j) agg[j] += hr[j];
    }
    const float* hn = &DscL[t*5];
    float sc = 0.f;
    #pragma unroll
    for (int j = 0; j < 5; ++j)
      sc += fabsf(dvT*(agg[j] + hn[j]) + (bsc[2*j+1] - bsc[2*j]));
    key = __float_as_uint(sc);   // sc >= 0 -> uint order == float order
  }
  __syncthreads();

  // E: 4-pass radix select; wave0 does the 256-bin suffix scan via shfl.
  uint32_t pref = 0, prefMask = 0;
  #pragma unroll
  for (int pass = 0; pass < 4; ++pass) {
    int shift = 24 - 8*pass;
    bool cand = (key & prefMask) == pref;
    if (cand) atomicAdd(&hist[(key >> shift) & 255], 1);
    __syncthreads();                          // B1: hist complete
    if (w == 0) {
      int base = lane*4;
      int h0 = hist[base+0], h1 = hist[base+1], h2 = hist[base+2], h3 = hist[base+3];
      int suf = h0 + h1 + h2 + h3;
      #pragma unroll
      for (int sh = 1; sh < 64; sh <<= 1) {
        int v = __shfl_down(suf, sh);
        if (lane + sh < 64) suf += v;
      }
      hsum[base+0] = suf;
      hsum[base+1] = suf - h0;
      hsum[base+2] = suf - h0 - h1;
      hsum[base+3] = suf - h0 - h1 - h2;
    }
    __syncthreads();                          // B2: hsum visible
    int rem = remL;
    if (t < 256) {
      int above = (t == 255) ? 0 : hsum[t+1];
      if (hsum[t] >= rem && above < rem) dstarL = t;
      hist[t] = 0;                            // zero for next pass
    }
    __syncthreads();                          // B3: dstar + zero done
    int ds = dstarL;
    if (t == 0) remL = rem - ((ds == 255) ? 0 : hsum[ds+1]);
    pref |= (uint32_t)ds << shift;
    prefMask |= 0xFFu << shift;
  }
  __syncthreads();
  uint32_t T = pref;
  int r = remL;

  // ties (key == T) rank by idx asc; select key>T plus first r ties
  bool eq = (key == T);
  uint64_t mEq = __ballot(eq);
  int lpEq = (int)__popcll(mEq & ((1ull << lane) - 1));
  if (lane == 0) wtot[w] = (int)__popcll(mEq);
  __syncthreads();
  if (t == 0) { int a = 0; for (int q = 0; q < 16; ++q) { wbase[q] = a; a += wtot[q]; } }
  __syncthreads();
  bool sel = (key > T) || (eq && (wbase[w] + lpEq) < r);
  __syncthreads();
  uint64_t mS = __ballot(sel);
  int lpS = (int)__popcll(mS & ((1ull << lane) - 1));
  if (lane == 0) wtot[w] = (int)__popcll(mS);
  __syncthreads();
  if (t == 0) { int a = 0; for (int q = 0; q < 16; ++q) { wbase[q] = a; a += wtot[q]; } }
  __syncthreads();
  int rank = wbase[w] + lpS;
  nidxL[t] = sel ? rank : -1;
  if (sel) onodeg[rank] = t;
  __syncthreads();

  // F: compact own segment in place (remap to ranks)
  if (sel) {
    int c2 = 0;
    for (int e = off0; e < off1; ++e) {
      int m = nidxL[srcL[e]];
      if (m >= 0) srcL[off0 + (c2++)] = (uint16_t)m;
    }
    vdegL[rank] = c2;
    seoffL[rank] = off0;
  }
  __syncthreads();

  // G: scan vdeg over 512 ranks -> packed offsets
  int vv = 0, xx = 0, w2 = t >> 6;
  if (t < K_) {
    vv = vdegL[t]; xx = vv;
    int l2 = t & 63;
    #pragma unroll
    for (int s = 1; s < 64; s <<= 1) {
      int v = __shfl_up(xx, s);
      if (l2 >= s) xx += v;
    }
    if (l2 == 63) wsum[w2] = xx;
  }
  __syncthreads();
  if (t == 0) { int run = 0; for (int q = 0; q < 8; ++q) { int tm = wsum[q]; wsum[q] = run; run += tm; } }
  __syncthreads();
  if (t < K_) {
    int ce = wsum[w2] + xx - vv;
    ceoffL[t] = ce;
    ceoffg[t] = ce;
    vdegg[t] = (uint16_t)vv;
    dinvg[t] = rsqrtf((float)vv + 1.0f);
  }
  __syncthreads();

  // H: coalesced packed edge-list write; owning rank via binary search
  int tot = ceoffL[K_-1] + vdegL[K_-1];
  for (int p = t; p < tot; p += 1024) {
    int lo2 = 0, hi2 = K_ - 1;
    while (lo2 < hi2) {
      int mid = (lo2 + hi2 + 1) >> 1;
      if (ceoffL[mid] <= p) lo2 = mid; else hi2 = mid - 1;
    }
    csrc[p] = srcL[seoffL[lo2] + (p - ceoffL[lo2])];
  }
}

// ---------------------------------------------------------------------------
// 256x32 @ 32x32 matmul core on swizzled LDS; W padded [32][36].
// ---------------------------------------------------------------------------
static __device__ __forceinline__ void mmA(
    const float* __restrict__ S, const float* __restrict__ Wp,
    float (&acc)[4][4], int it, int jt)
{
  const int i0 = it*4, swa = it & 7;
  #pragma unroll
  for (int kv = 0; kv < 8; ++kv) {
    float4 w0 = *(const float4*)&Wp[(kv*4+0)*36 + jt*4];
    float4 w1 = *(const float4*)&Wp[(kv*4+1)*36 + jt*4];
    float4 w2 = *(const float4*)&Wp[(kv*4+2)*36 + jt*4];
    float4 w3 = *(const float4*)&Wp[(kv*4+3)*36 + jt*4];
    #pragma unroll
    for (int d = 0; d < 4; ++d) {
      float4 a = *(const float4*)&S[(i0+d)*32 + ((kv ^ swa) << 2)];
      acc[d][0] += a.x*w0.x + a.y*w1.x + a.z*w2.x + a.w*w3.x;
      acc[d][1] += a.x*w0.y + a.y*w1.y + a.z*w2.y + a.w*w3.y;
      acc[d][2] += a.x*w0.z + a.y*w1.z + a.z*w2.z + a.w*w3.z;
      acc[d][3] += a.x*w0.w + a.y*w1.w + a.z*w2.w + a.w*w3.w;
    }
  }
}

// ---------------------------------------------------------------------------
// kG1: gA[g][dd] = dinv[dd] * (x[onode[dd]] @ Wg0).  grid (G,2) x 512.
// ---------------------------------------------------------------------------
__global__ __launch_bounds__(512, 4) void kG1(
    const float* __restrict__ x1, const float* __restrict__ x2,
    const float* __restrict__ Wg0, float* __restrict__ ws)
{
  int g = blockIdx.x, half = blockIdx.y, br = g >> 6, b = g & 63;
  const float* xg = (br ? x2 : x1) + (size_t)b*N_*F_;
  const int* onodeg = (const int*)ws + WS_ONODE + (size_t)g*K_ + half*256;
  const float* dinvg = ws + WS_DINV + (size_t)g*K_ + half*256;
  float* gAg = ws + WS_GA + (size_t)g*K_*H_ + (size_t)half*256*H_;

  __shared__ float wbuf[F_*36];
  __shared__ int   onodeL[256];
  __shared__ float dinvL[256];

  int t = threadIdx.x;
  for (int i = t; i < F_*H_; i += 512) wbuf[(i >> 5)*36 + (i & 31)] = Wg0[i];
  if (t < 256) { onodeL[t] = onodeg[t]; dinvL[t] = dinvg[t]; }
  __syncthreads();

  const int it = t >> 3, jt = t & 7;
  const int i0 = it*4;
  const float* xr0 = xg + (size_t)onodeL[i0+0]*F_;
  const float* xr1 = xg + (size_t)onodeL[i0+1]*F_;
  const float* xr2 = xg + (size_t)onodeL[i0+2]*F_;
  const float* xr3 = xg + (size_t)onodeL[i0+3]*F_;
  float acc[4][4] = {};
  for (int k4 = 0; k4 < 32; ++k4) {
    float4 w0 = *(const float4*)&wbuf[(k4*4+0)*36 + jt*4];
    float4 w1 = *(const float4*)&wbuf[(k4*4+1)*36 + jt*4];
    float4 w2 = *(const float4*)&wbuf[(k4*4+2)*36 + jt*4];
    float4 w3 = *(const float4*)&wbuf[(k4*4+3)*36 + jt*4];
    float4 a;
    a = *(const float4*)(xr0 + k4*4);
    acc[0][0]+=a.x*w0.x+a.y*w1.x+a.z*w2.x+a.w*w3.x; acc[0][1]+=a.x*w0.y+a.y*w1.y+a.z*w2.y+a.w*w3.y;
    acc[0][2]+=a.x*w0.z+a.y*w1.z+a.z*w2.z+a.w*w3.z; acc[0][3]+=a.x*w0.w+a.y*w1.w+a.z*w2.w+a.w*w3.w;
    a = *(const float4*)(xr1 + k4*4);
    acc[1][0]+=a.x*w0.x+a.y*w1.x+a.z*w2.x+a.w*w3.x; acc[1][1]+=a.x*w0.y+a.y*w1.y+a.z*w2.y+a.w*w3.y;
    acc[1][2]+=a.x*w0.z+a.y*w1.z+a.z*w2.z+a.w*w3.z; acc[1][3]+=a.x*w0.w+a.y*w1.w+a.z*w2.w+a.w*w3.w;
    a = *(const float4*)(xr2 + k4*4);
    acc[2][0]+=a.x*w0.x+a.y*w1.x+a.z*w2.x+a.w*w3.x; acc[2][1]+=a.x*w0.y+a.y*w1.y+a.z*w2.y+a.w*w3.y;
    acc[2][2]+=a.x*w0.z+a.y*w1.z+a.z*w2.z+a.w*w3.z; acc[2][3]+=a.x*w0.w+a.y*w1.w+a.z*w2.w+a.w*w3.w;
    a = *(const float4*)(xr3 + k4*4);
    acc[3][0]+=a.x*w0.x+a.y*w1.x+a.z*w2.x+a.w*w3.x; acc[3][1]+=a.x*w0.y+a.y*w1.y+a.z*w2.y+a.w*w3.y;
    acc[3][2]+=a.x*w0.z+a.y*w1.z+a.z*w2.z+a.w*w3.z; acc[3][3]+=a.x*w0.w+a.y*w1.w+a.z*w2.w+a.w*w3.w;
  }
  #pragma unroll
  for (int d = 0; d < 4; ++d) {
    int row = i0 + d;
    float rs = dinvL[row];
    float4 o; o.x=acc[d][0]*rs; o.y=acc[d][1]*rs; o.z=acc[d][2]*rs; o.w=acc[d][3]*rs;
    *(float4*)&gAg[row*32 + jt*4] = o;
  }
}

// ---------------------------------------------------------------------------
// conv gather (packed CSR) from global feature buffer into swizzled LDS.
// ---------------------------------------------------------------------------
static __device__ __forceinline__ void convG(
    const float* __restrict__ gS, float* __restrict__ cbuf,
    const float* __restrict__ bias, const float* __restrict__ dinvL,
    const int* __restrict__ eoffL, const int* __restrict__ vcntL,
    const uint16_t* __restrict__ srcS, int half, int t)
{
  int ddl = t & 255, hc = t >> 8;
  int dd = half*256 + ddl;
  int lo = eoffL[ddl], n = vcntL[ddl];
  int c0 = hc*16;
  float4 a0 = {0,0,0,0}, a1 = a0, a2 = a0, a3 = a0;
  for (int i = 0; i < n; ++i) {
    int ss = srcS[lo + i];
    const float* r = gS + ss*32 + c0;
    float4 v;
    v = *(const float4*)(r+0);  a0.x+=v.x; a0.y+=v.y; a0.z+=v.z; a0.w+=v.w;
    v = *(const float4*)(r+4);  a1.x+=v.x; a1.y+=v.y; a1.z+=v.z; a1.w+=v.w;
    v = *(const float4*)(r+8);  a2.x+=v.x; a2.y+=v.y; a2.z+=v.z; a2.w+=v.w;
    v = *(const float4*)(r+12); a3.x+=v.x; a3.y+=v.y; a3.z+=v.z; a3.w+=v.w;
  }
  { const float* r = gS + dd*32 + c0;
    float4 v;
    v = *(const float4*)(r+0);  a0.x+=v.x; a0.y+=v.y; a0.z+=v.z; a0.w+=v.w;
    v = *(const float4*)(r+4);  a1.x+=v.x; a1.y+=v.y; a1.z+=v.z; a1.w+=v.w;
    v = *(const float4*)(r+8);  a2.x+=v.x; a2.y+=v.y; a2.z+=v.z; a2.w+=v.w;
    v = *(const float4*)(r+12); a3.x+=v.x; a3.y+=v.y; a3.z+=v.z; a3.w+=v.w; }
  float dvd = dinvL[ddl];
  float4 r0, r1, r2, r3;
  r0.x = dvd*a0.x + bias[c0+0];  r0.y = dvd*a0.y + bias[c0+1];
  r0.z = dvd*a0.z + bias[c0+2];  r0.w = dvd*a0.w + bias[c0+3];
  r1.x = dvd*a1.x + bias[c0+4];  r1.y = dvd*a1.y + bias[c0+5];
  r1.z = dvd*a1.z + bias[c0+6];  r1.w = dvd*a1.w + bias[c0+7];
  r2.x = dvd*a2.x + bias[c0+8];  r2.y = dvd*a2.y + bias[c0+9];
  r2.z = dvd*a2.z + bias[c0+10]; r2.w = dvd*a2.w + bias[c0+11];
  r3.x = dvd*a3.x + bias[c0+12]; r3.y = dvd*a3.y + bias[c0+13];
  r3.z = dvd*a3.z + bias[c0+14]; r3.w = dvd*a3.w + bias[c0+15];
  int g4 = hc*4;
  *(float4*)&cbuf[swzf4(ddl, g4+0)] = r0;
  *(float4*)&cbuf[swzf4(ddl, g4+1)] = r1;
  *(float4*)&cbuf[swzf4(ddl, g4+2)] = r2;
  *(float4*)&cbuf[swzf4(ddl, g4+3)] = r3;
}

// ---------------------------------------------------------------------------
// kG2: conv0 -> r0=relu(.@Wm0a+b) -> {column partials, gC=(r0@W01+b01)*dinv}
// ---------------------------------------------------------------------------
__global__ __launch_bounds__(512, 4) void kG2(
    const float* __restrict__ bg0,
    const float* __restrict__ Wm0a, const float* __restrict__ bm0a,
    float* __restrict__ ws)
{
  int g = blockIdx.x, half = blockIdx.y;
  const float* gAg = ws + WS_GA + (size_t)g*K_*H_;
  float* gCg = ws + WS_GC + (size_t)g*K_*H_;
  const uint16_t* srcS = (const uint16_t*)(ws + WS_SRCS) + (size_t)g*E_;
  const int* eoffg = (const int*)ws + WS_EOFF + (size_t)g*K_ + half*256;
  const uint16_t* vdegg = (const uint16_t*)(ws + WS_VDEG) + (size_t)g*K_ + half*256;
  const float* dinvg = ws + WS_DINV + (size_t)g*K_ + half*256;

  __shared__ float cbufA[256*32];
  __shared__ float cbufB[256*32];
  __shared__ float wA[32*36];
  __shared__ float wB[32*36];
  __shared__ float scrP[64*33];
  __shared__ int   eoffL[256];
  __shared__ int   vcntL[256];
  __shared__ float dinvL[256];

  int t = threadIdx.x;
  for (int i = t; i < 1024; i += 512) {
    int k = i >> 5, j = i & 31;
    wA[k*36+j] = Wm0a[i];
    wB[k*36+j] = ws[WS_W01 + i];
  }
  if (t < 256) { eoffL[t] = eoffg[t]; vcntL[t] = vdegg[t]; dinvL[t] = dinvg[t]; }
  __syncthreads();

  convG(gAg, cbufA, bg0, dinvL, eoffL, vcntL, srcS, half, t);
  __syncthreads();

  const int it = t >> 3, jt = t & 7;
  float acc[4][4] = {};
  mmA(cbufA, wA, acc, it, jt);
  {
    float b0 = bm0a[jt*4+0], b1 = bm0a[jt*4+1], b2 = bm0a[jt*4+2], b3 = bm0a[jt*4+3];
    float cp0=0.f, cp1=0.f, cp2=0.f, cp3=0.f;
    #pragma unroll
    for (int d = 0; d < 4; ++d) {
      float v0=fmaxf(acc[d][0]+b0,0.f), v1=fmaxf(acc[d][1]+b1,0.f);
      float v2=fmaxf(acc[d][2]+b2,0.f), v3=fmaxf(acc[d][3]+b3,0.f);
      cp0+=v0; cp1+=v1; cp2+=v2; cp3+=v3;
      float4 o; o.x=v0; o.y=v1; o.z=v2; o.w=v3;
      *(float4*)&cbufB[swzf4(it*4+d, jt)] = o;
    }
    scrP[it*33 + jt*4+0] = cp0; scrP[it*33 + jt*4+1] = cp1;
    scrP[it*33 + jt*4+2] = cp2; scrP[it*33 + jt*4+3] = cp3;
  }
  __syncthreads();

  if (t < 32) {
    float s = 0.f;
    #pragma unroll
    for (int q = 0; q < 64; ++q) s += scrP[q*33 + t];
    ws[WS_PM0 + (size_t)g*64 + half*32 + t] = s;
  }

  float acc2[4][4] = {};
  mmA(cbufB, wB, acc2, it, jt);
  {
    float b0 = ws[WS_B01+jt*4+0], b1 = ws[WS_B01+jt*4+1];
    float b2 = ws[WS_B01+jt*4+2], b3 = ws[WS_B01+jt*4+3];
    #pragma unroll
    for (int d = 0; d < 4; ++d) {
      int row = it*4 + d;
      float rs = dinvL[row];
      float4 o;
      o.x=(acc2[d][0]+b0)*rs; o.y=(acc2[d][1]+b1)*rs;
      o.z=(acc2[d][2]+b2)*rs; o.w=(acc2[d][3]+b3)*rs;
      *(float4*)&gCg[(half*256+row)*32 + jt*4] = o;
    }
  }
}

// ---------------------------------------------------------------------------
// kG4: conv1 -> r1=relu(.@Wm1a+b) -> column partials.
// ---------------------------------------------------------------------------
__global__ __launch_bounds__(512, 4) void kG4(
    const float* __restrict__ bg1,
    const float* __restrict__ Wm1a, const float* __restrict__ bm1a,
    float* __restrict__ ws)
{
  int g = blockIdx.x, half = blockIdx.y;
  const float* gCg = ws + WS_GC + (size_t)g*K_*H_;
  const uint16_t* srcS = (const uint16_t*)(ws + WS_SRCS) + (size_t)g*E_;
  const int* eoffg = (const int*)ws + WS_EOFF + (size_t)g*K_ + half*256;
  const uint16_t* vdegg = (const uint16_t*)(ws + WS_VDEG) + (size_t)g*K_ + half*256;
  const float* dinvg = ws + WS_DINV + (size_t)g*K_ + half*256;

  __shared__ float cbufA[256*32];
  __shared__ float wA[32*36];
  __shared__ float scrP[64*33];
  __shared__ int   eoffL[256];
  __shared__ int   vcntL[256];
  __shared__ float dinvL[256];

  int t = threadIdx.x;
  for (int i = t; i < 1024; i += 512) wA[(i>>5)*36 + (i&31)] = Wm1a[i];
  if (t < 256) { eoffL[t] = eoffg[t]; vcntL[t] = vdegg[t]; dinvL[t] = dinvg[t]; }
  __syncthreads();

  convG(gCg, cbufA, bg1, dinvL, eoffL, vcntL, srcS, half, t);
  __syncthreads();

  const int it = t >> 3, jt = t & 7;
  float acc[4][4] = {};
  mmA(cbufA, wA, acc, it, jt);
  {
    float b0 = bm1a[jt*4+0], b1 = bm1a[jt*4+1], b2 = bm1a[jt*4+2], b3 = bm1a[jt*4+3];
    float cp0=0.f, cp1=0.f, cp2=0.f, cp3=0.f;
    #pragma unroll
    for (int d = 0; d < 4; ++d) {
      cp0 += fmaxf(acc[d][0]+b0,0.f); cp1 += fmaxf(acc[d][1]+b1,0.f);
      cp2 += fmaxf(acc[d][2]+b2,0.f); cp3 += fmaxf(acc[d][3]+b3,0.f);
    }
    scrP[it*33 + jt*4+0] = cp0; scrP[it*33 + jt*4+1] = cp1;
    scrP[it*33 + jt*4+2] = cp2; scrP[it*33 + jt*4+3] = cp3;
  }
  __syncthreads();

  if (t < 32) {
    float s = 0.f;
    #pragma unroll
    for (int q = 0; q < 64; ++q) s += scrP[q*33 + t];
    ws[WS_PM1 + (size_t)g*64 + half*32 + t] = s;
  }
}

// ---------------------------------------------------------------------------
// k5: per-graph tail via folded P0b/P1b. grid G x 64.
// ---------------------------------------------------------------------------
__global__ __launch_bounds__(64) void k5_final(
    const float* __restrict__ F1w, const float* __restrict__ G1w,
    const float* __restrict__ H1w, const float* __restrict__ Wo1,
    const float* __restrict__ bo1, const float* __restrict__ Wo2,
    const float* __restrict__ bo2, const float* __restrict__ ws,
    float* __restrict__ out)
{
  int g = blockIdx.x, t = threadIdx.x;
  __shared__ float mr0[32], mr1[32], AL[32], TL[32], pl[32], zl[32], ppiL[PO];
  if (t < 32) {
    mr0[t] = (ws[WS_PM0 + (size_t)g*64 + t] + ws[WS_PM0 + (size_t)g*64 + 32 + t]) * (1.f/512.f);
    mr1[t] = (ws[WS_PM1 + (size_t)g*64 + t] + ws[WS_PM1 + (size_t)g*64 + 32 + t]) * (1.f/512.f);
  }
  if (t >= 32 && t < 32+PO) ppiL[t-32] = ws[WS_PPI + (size_t)g*32 + (t-32)];
  __syncthreads();
  float f00 = ws[WS_F0V], f01 = ws[WS_F0V+1];
  if (t < 32) {
    float s0 = ws[WS_C0B + t], s1 = ws[WS_C1B + t];
    for (int k = 0; k < 32; ++k) {
      s0 += mr0[k]*ws[WS_P0B + k*32 + t];
      s1 += mr1[k]*ws[WS_P1B + k*32 + t];
    }
    AL[t] = f00*s0 + f01*s1;
  }
  __syncthreads();
  if (t < 32) {
    float s = 0.f;
    for (int jp = 0; jp < 32; ++jp) s += F1w[t*32+jp]*AL[jp];
    for (int jp = 0; jp < PO; ++jp) s += G1w[t*25+jp]*ppiL[jp];
    TL[t] = s;
  }
  __syncthreads();
  if (t < 32) {
    float s = 0.f;
    for (int j = 0; j < 32; ++j) s += H1w[t*32+j]*TL[j];
    pl[t] = s;
  }
  __syncthreads();
  if (t < 32) {
    float s = bo1[t];
    for (int j = 0; j < 32; ++j) s += pl[j]*Wo1[j*32+t];
    zl[t] = fmaxf(s, 0.f);
  }
  __syncthreads();
  if (t < 2) {
    float s = bo2[t];
    for (int q = 0; q < 32; ++q) s += zl[q]*Wo2[q*2+t];
    int br = g >> 6, b = g & 63;
    out[br*(B_*2) + b*2 + t] = s;
  }
}

// ---------------------------------------------------------------------------
extern "C" void kernel_launch(void* const* d_in, const int* in_sizes, int n_in,
                              void* d_out, int out_size, void* d_ws, size_t ws_size,
                              hipStream_t stream) {
  (void)in_sizes; (void)n_in; (void)out_size; (void)ws_size;
  const float* x1      = (const float*)d_in[0];
  const int*   ei1     = (const int*)  d_in[1];
  const float* PI1     = (const float*)d_in[2];
  const float* x2      = (const float*)d_in[3];
  const int*   ei2     = (const int*)  d_in[4];
  const float* PI2     = (const float*)d_in[5];
  const float* W_score = (const float*)d_in[6];
  const float* b_score = (const float*)d_in[7];
  const float* W_gcn0  = (const float*)d_in[8];
  const float* b_gcn0  = (const float*)d_in[9];
  const float* Wm0a    = (const float*)d_in[10];
  const float* bm0a    = (const float*)d_in[11];
  const float* Wm0b    = (const float*)d_in[12];
  const float* bm0b    = (const float*)d_in[13];
  const float* W_gcn1  = (const float*)d_in[14];
  const float* b_gcn1  = (const float*)d_in[15];
  const float* Wm1a    = (const float*)d_in[16];
  const float* bm1a    = (const float*)d_in[17];
  const float* Wm1b    = (const float*)d_in[18];
  const float* bm1b    = (const float*)d_in[19];
  const float* F0w     = (const float*)d_in[20];
  const float* F1w     = (const float*)d_in[21];
  const float* F2w     = (const float*)d_in[22];
  const float* Kc      = (const float*)d_in[23];
  const float* bc      = (const float*)d_in[24];
  const float* G0w     = (const float*)d_in[25];
  const float* G1w     = (const float*)d_in[26];
  const float* G2w     = (const float*)d_in[27];
  const float* H0w     = (const float*)d_in[28];
  const float* H1w     = (const float*)d_in[29];
  const float* H2w     = (const float*)d_in[30];
  const float* Wo1     = (const float*)d_in[31];
  const float* bo1     = (const float*)d_in[32];
  const float* Wo2     = (const float*)d_in[33];
  const float* bo2     = (const float*)d_in[34];
  float* ws  = (float*)d_ws;
  float* out = (float*)d_out;

  kA_pre<<<8*G_ + 36, 512, 0, stream>>>(x1, x2, W_score,
                                        F0w, F2w, H0w, H2w,
                                        Wm0b, bm0b, Wm1b, bm1b, W_gcn1, ws);
  kBSP<<<2*G_, 1024, 0, stream>>>(ei1, ei2, b_score, PI1, PI2, Kc, bc,
                                  G0w, G2w, H0w, H2w, ws);
  kG1<<<dim3(G_, 2), 512, 0, stream>>>(x1, x2, W_gcn0, ws);
  kG2<<<dim3(G_, 2), 512, 0, stream>>>(b_gcn0, Wm0a, bm0a, ws);
  kG4<<<dim3(G_, 2), 512, 0, stream>>>(b_gcn1, Wm1a, bm1a, ws);
  k5_final<<<G_, 64, 0, stream>>>(F1w, G1w, H1w, Wo1, bo1, Wo2, bo2, ws, out);
}